// Round 1
// 1789.436 us; speedup vs baseline: 1.0814x; 1.0814x over previous
//
#include <hip/hip_runtime.h>
#include <hip/hip_bf16.h>
#include <cmath>

// ---------------------------------------------------------------------------
// DAFNetBaseLayer — round 4: fp32 tiled attention (scores/softmax/PV GEMMs)
// replacing the latency-bound outer_attn_v2 / score_attn_v2 kernels.
// D=512, H=8, DK=64, HS=4, FF=2048, P=512, E=256
// ---------------------------------------------------------------------------

#define DD 512
#define FF 2048
#define PP 512
#define NEG_BIG (-1e30f)
#define LDT 68   // padded LDS stride for 64-wide fp32 tiles

typedef __attribute__((ext_vector_type(8))) short shortx8;   // 8 bf16 = 4 VGPR
typedef __attribute__((ext_vector_type(4))) float floatx4;

__device__ __forceinline__ unsigned short f2b(float f) {
    unsigned int u = __float_as_uint(f);
    unsigned int r = (u + 0x7fffu + ((u >> 16) & 1u)) >> 16;
    return (unsigned short)r;
}
__device__ __forceinline__ float b2f(unsigned short h) {
    return __uint_as_float(((unsigned int)h) << 16);
}

__device__ __forceinline__ void async_copy16(const void* g, void* l) {
    __builtin_amdgcn_global_load_lds(
        (const __attribute__((address_space(1))) unsigned int*)g,
        (__attribute__((address_space(3))) unsigned int*)l, 16, 0, 0);
}

// ---------------- bf16 MFMA GEMM:  C[M,N] = act(A[M,K] @ Bt[N,K]^T + bias) --
// 128x128 tile, BK=32, 256 threads = 4 waves (2x2 of 64x64), 16x16x32 MFMA.
// N % 128 == 0, K % 32 == 0. A,Bt bf16 row-major; bias fp32; C fp32 or bf16.
template<int OUT_BF16, int RELU>
__global__ __launch_bounds__(256) void gemm_bf16_kernel(
    const unsigned short* __restrict__ A, const unsigned short* __restrict__ Bt,
    const float* __restrict__ bias, void* __restrict__ C,
    int M, int N, int K)
{
    __shared__ unsigned short As[128 * 32];
    __shared__ unsigned short Bs[128 * 32];

    int t = threadIdx.x;
    int w = t >> 6, l = t & 63;
    int bm = blockIdx.x * 128, bn = blockIdx.y * 128;
    int wm = (w >> 1) * 64, wn = (w & 1) * 64;

    floatx4 acc[4][4];
#pragma unroll
    for (int i = 0; i < 4; ++i)
#pragma unroll
        for (int j = 0; j < 4; ++j)
#pragma unroll
            for (int r = 0; r < 4; ++r) acc[i][j][r] = 0.f;

    int s0 = t, s1 = 256 + t;
    int ar0 = s0 >> 2, ak0 = (s0 & 3) * 8;
    int ar1 = s1 >> 2, ak1 = (s1 & 3) * 8;
    int am0 = min(bm + ar0, M - 1);
    int am1 = min(bm + ar1, M - 1);
    const unsigned short* Ap0 = A + (size_t)am0 * K + ak0;
    const unsigned short* Ap1 = A + (size_t)am1 * K + ak1;
    const unsigned short* Bp0 = Bt + (size_t)(bn + ar0) * K + ak0;
    const unsigned short* Bp1 = Bt + (size_t)(bn + ar1) * K + ak1;

    unsigned short* AsB0 = As + (size_t)(w * 64) * 8;
    unsigned short* AsB1 = As + (size_t)(256 + w * 64) * 8;
    unsigned short* BsB0 = Bs + (size_t)(w * 64) * 8;
    unsigned short* BsB1 = Bs + (size_t)(256 + w * 64) * 8;

    int fr = l & 15, fq = l >> 4;
    int aoff = (wm + fr) * 32 + fq * 8;
    int boff = (wn + fr) * 32 + fq * 8;

    for (int k0 = 0; k0 < K; k0 += 32) {
        async_copy16(Ap0 + k0, AsB0);
        async_copy16(Ap1 + k0, AsB1);
        async_copy16(Bp0 + k0, BsB0);
        async_copy16(Bp1 + k0, BsB1);
        __syncthreads();

        shortx8 af[4], bf[4];
#pragma unroll
        for (int i = 0; i < 4; ++i) af[i] = *(const shortx8*)&As[aoff + i * 16 * 32];
#pragma unroll
        for (int j = 0; j < 4; ++j) bf[j] = *(const shortx8*)&Bs[boff + j * 16 * 32];
#pragma unroll
        for (int i = 0; i < 4; ++i)
#pragma unroll
            for (int j = 0; j < 4; ++j)
                acc[i][j] = __builtin_amdgcn_mfma_f32_16x16x32_bf16(af[i], bf[j], acc[i][j], 0, 0, 0);
        __syncthreads();
    }

#pragma unroll
    for (int j = 0; j < 4; ++j) {
        int col = bn + wn + j * 16 + fr;
        float bj = bias[col];
#pragma unroll
        for (int i = 0; i < 4; ++i) {
            int row0 = bm + wm + i * 16 + fq * 4;
#pragma unroll
            for (int r = 0; r < 4; ++r) {
                int row = row0 + r;
                if (row >= M) continue;
                float v = acc[i][j][r] + bj;
                if (RELU) v = fmaxf(v, 0.f);
                if (OUT_BF16) ((unsigned short*)C)[(size_t)row * N + col] = f2b(v);
                else          ((float*)C)[(size_t)row * N + col] = v;
            }
        }
    }
}

// ---------------- fp32 -> bf16 elementwise (n % 4 == 0) --------------------
__global__ void cvt_b16_kernel(const float* __restrict__ in, unsigned short* __restrict__ out, size_t n4)
{
    size_t i = (size_t)blockIdx.x * blockDim.x + threadIdx.x;
    if (i >= n4) return;
    float4 v = ((const float4*)in)[i];
    ushort4 o;
    o.x = f2b(v.x); o.y = f2b(v.y); o.z = f2b(v.z); o.w = f2b(v.w);
    ((ushort4*)out)[i] = o;
}

// ---------------- W[K,N] fp32 -> Wt[N,K] bf16 (K,N % 32 == 0) --------------
__global__ __launch_bounds__(256) void transpose_b16_kernel(
    const float* __restrict__ W, unsigned short* __restrict__ Wt, int Kd, int Nd)
{
    __shared__ float tile[32][33];
    int bx = blockIdx.x * 32;   // N
    int by = blockIdx.y * 32;   // K
    int tx = threadIdx.x & 31, ty = threadIdx.x >> 5;  // 32 x 8
#pragma unroll
    for (int i = 0; i < 32; i += 8)
        tile[ty + i][tx] = W[(size_t)(by + ty + i) * Nd + bx + tx];
    __syncthreads();
#pragma unroll
    for (int i = 0; i < 32; i += 8)
        Wt[(size_t)(bx + ty + i) * Kd + by + tx] = f2b(tile[tx][ty + i]);
}

// ---------------- bias concat for fused projection -------------------------
__global__ void bcat_kernel(const float* __restrict__ okb, const float* __restrict__ ovb,
                            const float* __restrict__ oqb, const float* __restrict__ skb,
                            const float* __restrict__ sqb, float* __restrict__ bcat)
{
    int i = blockIdx.x * 256 + threadIdx.x;  // 0..2047
    float v;
    if      (i < 512)  v = okb[i];
    else if (i < 1024) v = ovb[i - 512];
    else if (i < 1536) v = oqb[i - 1024];
    else if (i < 1792) v = skb[i - 1536];
    else               v = sqb[i - 1792];
    bcat[i] = v;
}

// ---------------- generic tiled fp32 GEMM (o-proj only) --------------------
__global__ __launch_bounds__(256) void gemm_kernel(
    const float* __restrict__ A, const float* __restrict__ W,
    const float* __restrict__ bias, float* __restrict__ C,
    int M, int N, int K, int relu)
{
    __shared__ float As[16][68];
    __shared__ float Ws[16][68];
    int t  = threadIdx.x;
    int tx = t & 15, ty = t >> 4;
    int bm = blockIdx.x * 64, bn = blockIdx.y * 64;
    float acc[4][4] = {};

    for (int k0 = 0; k0 < K; k0 += 16) {
#pragma unroll
        for (int e = 0; e < 4; ++e) {
            int idx = t + e * 256;
            int kk = idx & 15, m = idx >> 4;
            int row = bm + m;
            As[kk][m] = (row < M) ? A[(size_t)row * K + k0 + kk] : 0.f;
        }
#pragma unroll
        for (int e = 0; e < 4; ++e) {
            int idx = t + e * 256;
            int n = idx & 63, kk = idx >> 6;
            Ws[kk][n] = W[(size_t)(k0 + kk) * N + bn + n];
        }
        __syncthreads();
#pragma unroll
        for (int kk = 0; kk < 16; ++kk) {
            float4 a4 = *(const float4*)&As[kk][ty * 4];
            float4 b4 = *(const float4*)&Ws[kk][tx * 4];
            float av[4] = {a4.x, a4.y, a4.z, a4.w};
            float bv[4] = {b4.x, b4.y, b4.z, b4.w};
#pragma unroll
            for (int i = 0; i < 4; ++i)
#pragma unroll
                for (int j = 0; j < 4; ++j)
                    acc[i][j] += av[i] * bv[j];
        }
        __syncthreads();
    }

#pragma unroll
    for (int i = 0; i < 4; ++i) {
        int row = bm + ty * 4 + i;
        if (row >= M) continue;
        int col = bn + tx * 4;
        float4 bb = *(const float4*)&bias[col];
        float4 r;
        r.x = acc[i][0] + bb.x; r.y = acc[i][1] + bb.y;
        r.z = acc[i][2] + bb.z; r.w = acc[i][3] + bb.w;
        if (relu) {
            r.x = fmaxf(r.x, 0.f); r.y = fmaxf(r.y, 0.f);
            r.z = fmaxf(r.z, 0.f); r.w = fmaxf(r.w, 0.f);
        }
        *(float4*)&C[(size_t)row * N + col] = r;
    }
}

// ---------------- s = h2(bf16) @ t2w2 + t2b2 (one wave per row) ------------
__global__ __launch_bounds__(64) void rowdot512_b16_kernel(
    const unsigned short* __restrict__ A, const float* __restrict__ w,
    const float* __restrict__ bptr, float* __restrict__ out)
{
    int row = blockIdx.x;
    int lane = threadIdx.x;
    const unsigned short* a = A + (size_t)row * DD;
    float v = 0.f;
#pragma unroll
    for (int i = 0; i < 8; ++i) v += b2f(a[lane + 64 * i]) * w[lane + 64 * i];
#pragma unroll
    for (int d = 32; d > 0; d >>= 1) v += __shfl_down(v, d, 64);
    if (lane == 0) out[row] = v + bptr[0];
}

// ---------------- segment machinery ----------------------------------------
__global__ void seg_offsets_kernel(const int* __restrict__ lens, int* __restrict__ offs, int E)
{
    if (threadIdx.x == 0 && blockIdx.x == 0) {
        int acc = 0;
        for (int g = 0; g < E; ++g) { offs[g] = acc; acc += lens[g]; }
        offs[E] = acc;
    }
}

__global__ void fill_seg_kernel(const int* __restrict__ offs, int* __restrict__ seg)
{
    int g = blockIdx.x;
    int o = offs[g], e = offs[g + 1];
    for (int i = o + threadIdx.x; i < e; i += blockDim.x) seg[i] = g;
}

__global__ __launch_bounds__(384) void seg_softmax_kernel(
    const float* __restrict__ s, const int* __restrict__ offs, float* __restrict__ wgt)
{
    __shared__ float red[8];
    int g = blockIdx.x;
    int o = offs[g], len = offs[g + 1] - o;
    int t = threadIdx.x;
    int lane = t & 63, wid = t >> 6;

    float v = (t < len) ? s[o + t] : NEG_BIG;
    float m = v;
#pragma unroll
    for (int d = 32; d > 0; d >>= 1) m = fmaxf(m, __shfl_down(m, d, 64));
    if (lane == 0) red[wid] = m;
    __syncthreads();
    if (t == 0) {
        float mm = red[0];
        for (int i = 1; i < 6; ++i) mm = fmaxf(mm, red[i]);
        red[6] = mm;
    }
    __syncthreads();
    float M = red[6];

    float p = (t < len) ? expf(v - M) : 0.f;
    float sum = p;
#pragma unroll
    for (int d = 32; d > 0; d >>= 1) sum += __shfl_down(sum, d, 64);
    if (lane == 0) red[wid] = sum;
    __syncthreads();
    if (t == 0) {
        float ss = red[0];
        for (int i = 1; i < 6; ++i) ss += red[i];
        red[7] = ss;
    }
    __syncthreads();
    if (t < len) wgt[o + t] = p / red[7];
}

__global__ __launch_bounds__(256) void seg_wsum_kernel(
    const unsigned short* __restrict__ att_x, const float* __restrict__ wgt,
    const int* __restrict__ offs, float* __restrict__ rep)
{
    int g = blockIdx.x;
    int o = offs[g], e = offs[g + 1];
    int c = threadIdx.x;
    float a0 = 0.f, a1 = 0.f;
    for (int i = o; i < e; ++i) {
        float w = wgt[i];
        const unsigned short* r = att_x + (size_t)i * DD;
        a0 += b2f(r[c]) * w;
        a1 += b2f(r[c + 256]) * w;
    }
    rep[(size_t)g * DD + c] = a0;
    rep[(size_t)g * DD + c + 256] = a1;
}

// ---------------- block reduce helpers -------------------------------------
__device__ __forceinline__ float block_sum_256(float v, float* red)
{
    int lane = threadIdx.x & 63, wid = threadIdx.x >> 6;
#pragma unroll
    for (int d = 32; d > 0; d >>= 1) v += __shfl_down(v, d, 64);
    if (lane == 0) red[wid] = v;
    __syncthreads();
    float r = red[0] + red[1] + red[2] + red[3];
    __syncthreads();
    return r;
}

__device__ __forceinline__ float block_max_256(float v, float* red)
{
    int lane = threadIdx.x & 63, wid = threadIdx.x >> 6;
#pragma unroll
    for (int d = 32; d > 0; d >>= 1) v = fmaxf(v, __shfl_down(v, d, 64));
    if (lane == 0) red[wid] = v;
    __syncthreads();
    float r = fmaxf(fmaxf(red[0], red[1]), fmaxf(red[2], red[3]));
    __syncthreads();
    return r;
}

// ---------------- LN1: out = LN(x + att_x(bf16)*wgt[row]) ------------------
__global__ __launch_bounds__(256) void ln1_kernel(
    const float* __restrict__ x, const unsigned short* __restrict__ att_x,
    const float* __restrict__ wgt, const float* __restrict__ w,
    const float* __restrict__ b, float* __restrict__ out)
{
    __shared__ float red[4];
    size_t row = blockIdx.x;
    int c = threadIdx.x;
    float wr = wgt[row];
    const float* xr = x + row * DD;
    const unsigned short* ar = att_x + row * DD;
    float v0 = xr[c] + b2f(ar[c]) * wr;
    float v1 = xr[c + 256] + b2f(ar[c + 256]) * wr;
    float mean = block_sum_256(v0 + v1, red) * (1.f / 512.f);
    float d0 = v0 - mean, d1 = v1 - mean;
    float var = block_sum_256(d0 * d0 + d1 * d1, red) * (1.f / 512.f);
    float rstd = rsqrtf(var + 1e-5f);
    out[row * DD + c] = d0 * rstd * w[c] + b[c];
    out[row * DD + c + 256] = d1 * rstd * w[c + 256] + b[c + 256];
}

// ---------------- LN2 (in-place) + bf16 copy -------------------------------
__global__ __launch_bounds__(256) void ln2_kernel(
    float* __restrict__ xb, const float* __restrict__ o,
    const int* __restrict__ seg, const float* __restrict__ w,
    const float* __restrict__ b, unsigned short* __restrict__ xb16)
{
    __shared__ float red[4];
    size_t row = blockIdx.x;
    int c = threadIdx.x;
    int g = seg[row];
    const float* orow = o + (size_t)g * DD;
    float v0 = xb[row * DD + c] + orow[c];
    float v1 = xb[row * DD + c + 256] + orow[c + 256];
    float mean = block_sum_256(v0 + v1, red) * (1.f / 512.f);
    float d0 = v0 - mean, d1 = v1 - mean;
    float var = block_sum_256(d0 * d0 + d1 * d1, red) * (1.f / 512.f);
    float rstd = rsqrtf(var + 1e-5f);
    float y0 = d0 * rstd * w[c] + b[c];
    float y1 = d1 * rstd * w[c + 256] + b[c + 256];
    xb[row * DD + c] = y0;
    xb[row * DD + c + 256] = y1;
    xb16[row * DD + c] = f2b(y0);
    xb16[row * DD + c + 256] = f2b(y1);
}

// ---------------- LN3 + FiLM (ffn in bf16) ---------------------------------
__global__ __launch_bounds__(256) void ln3_film_kernel(
    const float* __restrict__ xb, const unsigned short* __restrict__ ffn,
    const int* __restrict__ mode, const float* __restrict__ w,
    const float* __restrict__ b, const float* __restrict__ msc,
    const float* __restrict__ msh, float* __restrict__ out)
{
    __shared__ float red[4];
    size_t row = blockIdx.x;
    int c = threadIdx.x;
    int md = mode[row];
    float v0 = xb[row * DD + c] + b2f(ffn[row * DD + c]);
    float v1 = xb[row * DD + c + 256] + b2f(ffn[row * DD + c + 256]);
    float mean = block_sum_256(v0 + v1, red) * (1.f / 512.f);
    float d0 = v0 - mean, d1 = v1 - mean;
    float var = block_sum_256(d0 * d0 + d1 * d1, red) * (1.f / 512.f);
    float rstd = rsqrtf(var + 1e-5f);
    float y0 = d0 * rstd * w[c] + b[c];
    float y1 = d1 * rstd * w[c + 256] + b[c + 256];
    float p0 = y0 * msc[(size_t)md * DD + c] + msh[(size_t)md * DD + c];
    float p1 = y1 * msc[(size_t)md * DD + c + 256] + msh[(size_t)md * DD + c + 256];
    out[row * DD + c] = fmaxf(p0, 0.f) + y0;
    out[row * DD + c + 256] = fmaxf(p1, 0.f) + y1;
}

// ---------------- new_rep = concat(past_rep, sample_rep) -------------------
__global__ void newrep_kernel(const float* __restrict__ past, const float* __restrict__ rep,
                              float* __restrict__ out, int total)
{
    int i = blockIdx.x * blockDim.x + threadIdx.x;
    if (i >= total) return;
    out[i] = (i < PP * DD) ? past[i] : rep[i - PP * DD];
}

// ---------------- attention scores: S[h][q][k] = (Q·K)/8 -------------------
// h 0..7: outer attn (Q cols 1024.., K cols 0..); h 8..11: score attn
// (Q cols 1792.., K cols 1536..). 64x64 tile, 4x4 register blocking,
// transposed LDS tiles ([d][q], [d][k], stride 68 -> conflict-free float4).
__global__ __launch_bounds__(256) void attn_scores_kernel(
    const float* __restrict__ proj, float* __restrict__ S, int pe)
{
    int q0 = blockIdx.x * 64;
    int k0 = blockIdx.y * 64;
    int h  = blockIdx.z;
    if (k0 > PP + q0 + 63) return;          // fully-masked causal tile

    int qcol = (h < 8) ? (1024 + h * 64) : (1792 + (h - 8) * 64);
    int kcol = (h < 8) ? (h * 64)        : (1536 + (h - 8) * 64);

    __shared__ float Qs[64][LDT];   // [d][q]
    __shared__ float Ks[64][LDT];   // [d][k]
    int t = threadIdx.x;
    int r = t >> 2, c4 = (t & 3) * 16;
    const float* qsrc = proj + (size_t)(PP + q0 + r) * 2048 + qcol + c4;
    const float* ksrc = proj + (size_t)(k0 + r) * 2048 + kcol + c4;
#pragma unroll
    for (int e = 0; e < 4; ++e) {
        float4 v = *(const float4*)(qsrc + e * 4);
        Qs[c4 + e * 4 + 0][r] = v.x; Qs[c4 + e * 4 + 1][r] = v.y;
        Qs[c4 + e * 4 + 2][r] = v.z; Qs[c4 + e * 4 + 3][r] = v.w;
        float4 u = *(const float4*)(ksrc + e * 4);
        Ks[c4 + e * 4 + 0][r] = u.x; Ks[c4 + e * 4 + 1][r] = u.y;
        Ks[c4 + e * 4 + 2][r] = u.z; Ks[c4 + e * 4 + 3][r] = u.w;
    }
    __syncthreads();

    int tx = t & 15, ty = t >> 4;           // tx -> 4 k cols, ty -> 4 q rows
    float acc[4][4] = {};
#pragma unroll 4
    for (int d = 0; d < 64; ++d) {
        float4 a = *(const float4*)&Qs[d][ty * 4];
        float4 b = *(const float4*)&Ks[d][tx * 4];
        float av[4] = {a.x, a.y, a.z, a.w};
        float bv[4] = {b.x, b.y, b.z, b.w};
#pragma unroll
        for (int i = 0; i < 4; ++i)
#pragma unroll
            for (int j = 0; j < 4; ++j)
                acc[i][j] += av[i] * bv[j];
    }

    float* Sh = S + ((size_t)h * 256 + q0) * pe + k0;
#pragma unroll
    for (int i = 0; i < 4; ++i) {
        float4 o;
        o.x = acc[i][0] * 0.125f; o.y = acc[i][1] * 0.125f;
        o.z = acc[i][2] * 0.125f; o.w = acc[i][3] * 0.125f;
        *(float4*)&Sh[(size_t)(ty * 4 + i) * pe + tx * 4] = o;
    }
}

// ---------------- attention softmax: P in place, diag u for score heads ----
// block per (q, h). Causal limit k <= PP+q; zero-pads P beyond limit so the
// PV GEMM can run unmasked over full tiles.
__global__ __launch_bounds__(256) void attn_softmax_kernel(
    float* __restrict__ S, float* __restrict__ u4, int pe)
{
    __shared__ float red[4];
    int q = blockIdx.x;
    int h = blockIdx.y;
    int limq = PP + q;                       // inclusive
    float* row = S + ((size_t)h * 256 + q) * pe;
    int t = threadIdx.x;

    float m = NEG_BIG;
    for (int k = t; k <= limq; k += 256) m = fmaxf(m, row[k]);
    float M = block_max_256(m, red);

    float s = 0.f;
    for (int k = t; k <= limq; k += 256) s += expf(row[k] - M);
    float SUM = block_sum_256(s, red);
    float inv = 1.f / SUM;

    if (h < 8) {
        for (int k = t; k < pe; k += 256)
            row[k] = (k <= limq) ? expf(row[k] - M) * inv : 0.f;
    } else {
        if (t == 0) u4[q * 4 + (h - 8)] = expf(row[limq] - M) * inv;
    }
}

// ---------------- attention PV: ob[q][h*64+d] = P[h][q][:] @ V[:][d] -------
// 32q x 64d tile, 2x4 register blocking; grid (E/32, 8).
__global__ __launch_bounds__(256) void attn_pv_kernel(
    const float* __restrict__ S, const float* __restrict__ proj,
    float* __restrict__ ob, int pe)
{
    __shared__ float Ps[64][36];    // [k][q] transposed, q-width 32
    __shared__ float Vs[64][LDT];   // [k][d]
    int q0 = blockIdx.x * 32;
    int h  = blockIdx.y;
    int ktiles = (PP + q0 + 31) / 64 + 1;    // covers all k <= PP+q0+31

    int t = threadIdx.x;
    int tx = t & 15, ty = t >> 4;            // tx -> 4 d cols, ty -> 2 q rows
    int rp = t >> 3, c8 = (t & 7) * 8;       // P staging: 32 rows x 8 cols
    int rv = t >> 2, c16 = (t & 3) * 16;     // V staging: 64 rows x 16 cols
    float acc[2][4] = {};

    for (int kt = 0; kt < ktiles; ++kt) {
        int k0 = kt * 64;
        const float* psrc = S + ((size_t)h * 256 + q0 + rp) * pe + k0 + c8;
        const float* vsrc = proj + (size_t)(k0 + rv) * 2048 + 512 + h * 64 + c16;
#pragma unroll
        for (int e = 0; e < 2; ++e) {
            float4 v = *(const float4*)(psrc + e * 4);
            Ps[c8 + e * 4 + 0][rp] = v.x; Ps[c8 + e * 4 + 1][rp] = v.y;
            Ps[c8 + e * 4 + 2][rp] = v.z; Ps[c8 + e * 4 + 3][rp] = v.w;
        }
#pragma unroll
        for (int e = 0; e < 4; ++e)
            *(float4*)&Vs[rv][c16 + e * 4] = *(const float4*)(vsrc + e * 4);
        __syncthreads();

#pragma unroll 8
        for (int kk = 0; kk < 64; ++kk) {
            float2 a = *(const float2*)&Ps[kk][ty * 2];
            float4 b = *(const float4*)&Vs[kk][tx * 4];
            float av[2] = {a.x, a.y};
            float bv[4] = {b.x, b.y, b.z, b.w};
#pragma unroll
            for (int i = 0; i < 2; ++i)
#pragma unroll
                for (int j = 0; j < 4; ++j)
                    acc[i][j] += av[i] * bv[j];
        }
        __syncthreads();
    }

#pragma unroll
    for (int i = 0; i < 2; ++i) {
        float4 o;
        o.x = acc[i][0]; o.y = acc[i][1]; o.z = acc[i][2]; o.w = acc[i][3];
        *(float4*)&ob[(size_t)(q0 + ty * 2 + i) * DD + h * 64 + tx * 4] = o;
    }
}

// ---------------- cumprod finalize (head-mean + reversed cumprod) ----------
__global__ void finalize_kernel(const float* __restrict__ u4, float* __restrict__ out_past,
                                float* __restrict__ out_us, int E)
{
    if (threadIdx.x == 0 && blockIdx.x == 0) {
        float uE = 0.25f * (u4[(E - 1) * 4] + u4[(E - 1) * 4 + 1] + u4[(E - 1) * 4 + 2] + u4[(E - 1) * 4 + 3]);
        out_us[E - 1] = uE;
        float pf = 1.f;
        for (int i = E - 1; i >= 0; --i) {
            float u = 0.25f * (u4[i * 4] + u4[i * 4 + 1] + u4[i * 4 + 2] + u4[i * 4 + 3]);
            if (i < E - 1) out_us[i] = u * pf;
            pf = (1.f - u) * pf;
        }
        out_past[0] = pf;
    }
}

// ---------------------------------------------------------------------------
extern "C" void kernel_launch(void* const* d_in, const int* in_sizes, int n_in,
                              void* d_out, int out_size, void* d_ws, size_t ws_size,
                              hipStream_t stream)
{
    const float* x    = (const float*)d_in[0];
    const float* past = (const float*)d_in[1];
    const int*   lens = (const int*)d_in[2];
    const int*   mode = (const int*)d_in[3];
    const float* t1w1 = (const float*)d_in[4];
    const float* t1b1 = (const float*)d_in[5];
    const float* t1w2 = (const float*)d_in[6];
    const float* t1b2 = (const float*)d_in[7];
    const float* t2w1 = (const float*)d_in[8];
    const float* t2b1 = (const float*)d_in[9];
    const float* t2w2 = (const float*)d_in[10];
    const float* t2b2 = (const float*)d_in[11];
    const float* oq_w = (const float*)d_in[12];
    const float* oq_b = (const float*)d_in[13];
    const float* ok_w = (const float*)d_in[14];
    const float* ok_b = (const float*)d_in[15];
    const float* ov_w = (const float*)d_in[16];
    const float* ov_b = (const float*)d_in[17];
    const float* oo_w = (const float*)d_in[18];
    const float* oo_b = (const float*)d_in[19];
    const float* sq_w = (const float*)d_in[20];
    const float* sq_b = (const float*)d_in[21];
    const float* sk_w = (const float*)d_in[22];
    const float* sk_b = (const float*)d_in[23];
    const float* f1w  = (const float*)d_in[24];
    const float* f1b  = (const float*)d_in[25];
    const float* f2w  = (const float*)d_in[26];
    const float* f2b_ = (const float*)d_in[27];
    const float* ln1w = (const float*)d_in[28];
    const float* ln1b = (const float*)d_in[29];
    const float* ln2w = (const float*)d_in[30];
    const float* ln2b = (const float*)d_in[31];
    const float* ln3w = (const float*)d_in[32];
    const float* ln3b = (const float*)d_in[33];
    const float* msc  = (const float*)d_in[34];
    const float* msh  = (const float*)d_in[35];

    int N  = in_sizes[0] / DD;
    int E  = in_sizes[2];
    int PE = PP + E;
    if (N <= 0) return;

    float* out        = (float*)d_out;
    float* out_x      = out;
    float* out_past   = out + (size_t)N * DD;
    float* out_us     = out_past + 1;
    float* out_newrep = out_us + E;

    // ---- workspace layout ----
    const int CH = 16384;                               // FFN row-chunk
    char* wp = (char*)d_ws;
    unsigned short* b16_a = (unsigned short*)wp;  wp += (size_t)N * DD * 2;
    unsigned short* b16_b = (unsigned short*)wp;  wp += (size_t)N * DD * 2;
    unsigned short* ffh   = (unsigned short*)wp;  wp += (size_t)CH * FF * 2;
    unsigned short* wt1   = (unsigned short*)wp;  wp += (size_t)DD * DD * 2;
    unsigned short* wt2   = (unsigned short*)wp;  wp += (size_t)DD * DD * 2;
    unsigned short* wt3   = (unsigned short*)wp;  wp += (size_t)DD * DD * 2;
    unsigned short* wtf1  = (unsigned short*)wp;  wp += (size_t)FF * DD * 2;
    unsigned short* wtf2  = (unsigned short*)wp;  wp += (size_t)DD * FF * 2;
    unsigned short* wtcat = (unsigned short*)wp;  wp += (size_t)2048 * DD * 2;  // [2048][512]
    unsigned short* nr16  = (unsigned short*)wp;  wp += (size_t)PE * DD * 2;
    float* bcat = (float*)wp;  wp += 2048 * 4;
    float* proj = (float*)wp;  wp += (size_t)PE * 2048 * 4;   // fused projections
    float* sbuf = (float*)wp;  wp += (size_t)N * 4;
    float* wgt  = (float*)wp;  wp += (size_t)N * 4;
    float* rep  = (float*)wp;  wp += (size_t)E * DD * 4;
    float* ob   = (float*)wp;  wp += (size_t)E * DD * 4;
    float* oprj = (float*)wp;  wp += (size_t)E * DD * 4;
    float* u4   = (float*)wp;  wp += (size_t)E * 4 * 4;
    int*   seg  = (int*)wp;    wp += (size_t)N * 4;
    int*   offs = (int*)wp;

    // S/P buffer [12][E][PE] fp32 aliases ffh (attention completes before FFN)
    float* S = (float*)ffh;

    int mg128 = (N + 127) / 128;

    // ---- weight prep: transposes to [N,K] bf16 + fused-projection concat ----
    transpose_b16_kernel<<<dim3(DD / 32, DD / 32), 256, 0, stream>>>(t1w1, wt1, DD, DD);
    transpose_b16_kernel<<<dim3(DD / 32, DD / 32), 256, 0, stream>>>(t1w2, wt2, DD, DD);
    transpose_b16_kernel<<<dim3(DD / 32, DD / 32), 256, 0, stream>>>(t2w1, wt3, DD, DD);
    transpose_b16_kernel<<<dim3(FF / 32, DD / 32), 256, 0, stream>>>(f1w, wtf1, DD, FF);
    transpose_b16_kernel<<<dim3(DD / 32, FF / 32), 256, 0, stream>>>(f2w, wtf2, FF, DD);
    transpose_b16_kernel<<<dim3(DD / 32, DD / 32), 256, 0, stream>>>(ok_w, wtcat,              DD, DD);
    transpose_b16_kernel<<<dim3(DD / 32, DD / 32), 256, 0, stream>>>(ov_w, wtcat + 512 * DD,  DD, DD);
    transpose_b16_kernel<<<dim3(DD / 32, DD / 32), 256, 0, stream>>>(oq_w, wtcat + 1024 * DD, DD, DD);
    transpose_b16_kernel<<<dim3(256 / 32, DD / 32), 256, 0, stream>>>(sk_w, wtcat + 1536 * DD, DD, 256);
    transpose_b16_kernel<<<dim3(256 / 32, DD / 32), 256, 0, stream>>>(sq_w, wtcat + 1792 * DD, DD, 256);
    bcat_kernel<<<8, 256, 0, stream>>>(ok_b, ov_b, oq_b, sk_b, sq_b, bcat);

    // ---- x -> bf16 ----
    size_t n4 = (size_t)N * DD / 4;
    cvt_b16_kernel<<<(int)((n4 + 255) / 256), 256, 0, stream>>>(x, b16_a, n4);

    // ---- inner attention MLPs (bf16 MFMA) ----
    gemm_bf16_kernel<1, 1><<<dim3(mg128, DD / 128), 256, 0, stream>>>(b16_a, wt1, t1b1, b16_b, N, DD, DD);
    gemm_bf16_kernel<1, 0><<<dim3(mg128, DD / 128), 256, 0, stream>>>(b16_b, wt2, t1b2, b16_a, N, DD, DD);
    gemm_bf16_kernel<1, 1><<<dim3(mg128, DD / 128), 256, 0, stream>>>(b16_a, wt3, t2b1, b16_b, N, DD, DD);
    rowdot512_b16_kernel<<<N, 64, 0, stream>>>(b16_b, t2w2, t2b2, sbuf);

    // ---- segment softmax + rep + LN1 ----
    seg_offsets_kernel<<<1, 64, 0, stream>>>(lens, offs, E);
    fill_seg_kernel<<<E, 256, 0, stream>>>(offs, seg);
    seg_softmax_kernel<<<E, 384, 0, stream>>>(sbuf, offs, wgt);
    seg_wsum_kernel<<<E, 256, 0, stream>>>(b16_a, wgt, offs, rep);
    ln1_kernel<<<N, 256, 0, stream>>>(x, b16_a, wgt, ln1w, ln1b, out_x);

    // ---- new_rep output + bf16 copy ----
    int nr_total = PE * DD;
    newrep_kernel<<<(nr_total + 255) / 256, 256, 0, stream>>>(past, rep, out_newrep, nr_total);
    cvt_b16_kernel<<<(nr_total / 4 + 255) / 256, 256, 0, stream>>>(out_newrep, nr16, nr_total / 4);

    // ---- fused K|V|Q|K2|Q2 projection (one MFMA GEMM, N=2048) ----
    gemm_bf16_kernel<0, 0><<<dim3(PE / 128, 2048 / 128), 256, 0, stream>>>(nr16, wtcat, bcat, proj, PE, 2048, DD);

    // ---- outer + score attention as fp32 tiled GEMMs ----
    attn_scores_kernel<<<dim3(E / 64, PE / 64, 12), 256, 0, stream>>>(proj, S, PE);
    attn_softmax_kernel<<<dim3(E, 12), 256, 0, stream>>>(S, u4, PE);
    attn_pv_kernel<<<dim3(E / 32, 8), 256, 0, stream>>>(S, proj, ob, PE);
    gemm_kernel<<<dim3(E / 64, DD / 64), 256, 0, stream>>>(ob, oo_w, oo_b, oprj, E, DD, DD, 0);
    ln2_kernel<<<N, 256, 0, stream>>>(out_x, oprj, seg, ln2w, ln2b, b16_b);
    finalize_kernel<<<1, 64, 0, stream>>>(u4, out_past, out_us, E);

    // ---- FFN (bf16 MFMA, chunked) ----
    for (int r0 = 0; r0 < N; r0 += CH) {
        int mr = N - r0; if (mr > CH) mr = CH;
        int mgc = (mr + 127) / 128;
        gemm_bf16_kernel<1, 1><<<dim3(mgc, FF / 128), 256, 0, stream>>>(
            b16_b + (size_t)r0 * DD, wtf1, f1b, ffh, mr, FF, DD);
        gemm_bf16_kernel<1, 0><<<dim3(mgc, DD / 128), 256, 0, stream>>>(
            ffh, wtf2, f2b_, b16_a + (size_t)r0 * DD, mr, DD, FF);
    }
    ln3_film_kernel<<<N, 256, 0, stream>>>(out_x, b16_a, mode, ln3w, ln3b, msc, msh, out_x);
}

// Round 3
// 1662.096 us; speedup vs baseline: 1.1643x; 1.0766x over previous
//
#include <hip/hip_runtime.h>
#include <hip/hip_bf16.h>
#include <cmath>

// ---------------------------------------------------------------------------
// DAFNetBaseLayer — round 6: pipelined bf16 MFMA GEMM, hazard-hardened.
// Double-buffered LDS with stage-before-compute; __syncthreads() phase
// boundaries (safe vmcnt+lgkmcnt drain — avoids pitfall: compiler sinking
// register-only MFMA past inline-asm waits); swapped-operand vectorized
// epilogue; XCD-bijective N-fast block remap. Attention kernels from r4.
// D=512, H=8, DK=64, HS=4, FF=2048, P=512, E=256
// ---------------------------------------------------------------------------

#define DD 512
#define FF 2048
#define PP 512
#define NEG_BIG (-1e30f)
#define LDT 68   // padded LDS stride for 64-wide fp32 tiles

typedef __attribute__((ext_vector_type(8))) short shortx8;   // 8 bf16 = 4 VGPR
typedef __attribute__((ext_vector_type(4))) float floatx4;

__device__ __forceinline__ unsigned short f2b(float f) {
    unsigned int u = __float_as_uint(f);
    unsigned int r = (u + 0x7fffu + ((u >> 16) & 1u)) >> 16;
    return (unsigned short)r;
}
__device__ __forceinline__ float b2f(unsigned short h) {
    return __uint_as_float(((unsigned int)h) << 16);
}

__device__ __forceinline__ void async_copy16(const void* g, void* l) {
    __builtin_amdgcn_global_load_lds(
        (const __attribute__((address_space(1))) unsigned int*)g,
        (__attribute__((address_space(3))) unsigned int*)l, 16, 0, 0);
}

// ---------------- bf16 MFMA GEMM:  C[M,N] = act(A[M,K] @ Bt[N,K]^T + bias) --
// 128x128 tile, BK=32, 256 threads = 4 waves (2x2 of 64x64), 16x16x32 MFMA.
// N % 128 == 0, K % 64 == 0. A,Bt bf16 row-major; bias fp32; C fp32 or bf16.
// Pipeline: 2x LDS buffers, stage(t+1) issued BEFORE compute(t); one
// __syncthreads (vmcnt+lgkmcnt drain) per K-step. Static buffer indices.
template<int OUT_BF16, int RELU>
__global__ __launch_bounds__(256) void gemm_bf16_kernel(
    const unsigned short* __restrict__ A, const unsigned short* __restrict__ Bt,
    const float* __restrict__ bias, void* __restrict__ C,
    int M, int N, int K)
{
    __shared__ unsigned short As[2][128 * 32];
    __shared__ unsigned short Bs[2][128 * 32];

    int t = threadIdx.x;
    int w = t >> 6, l = t & 63;

    // ---- block remap: XCD-contiguous chunks (bijective), N-tile fastest ----
    int nwg = gridDim.x * gridDim.y;
    int bid = blockIdx.x + blockIdx.y * gridDim.x;
    int qch = nwg >> 3, rch = nwg & 7;
    int xcd = bid & 7, lo = bid >> 3;
    int swz = (xcd < rch ? xcd * (qch + 1) : rch * (qch + 1) + (xcd - rch) * qch) + lo;
    int bm = (swz / gridDim.y) * 128;
    int bn = (swz % gridDim.y) * 128;

    int wm = (w >> 1) * 64, wn = (w & 1) * 64;

    // Swapped operands: mfma(bf, af) -> D transposed vs r4: lane&15 indexes
    // M rows, reg-dim indexes 4 consecutive N cols -> vectorized epilogue.
    floatx4 acc[4][4];
#pragma unroll
    for (int i = 0; i < 4; ++i)
#pragma unroll
        for (int j = 0; j < 4; ++j)
#pragma unroll
            for (int r = 0; r < 4; ++r) acc[i][j][r] = 0.f;

    int s0 = t, s1 = 256 + t;
    int ar0 = s0 >> 2, ak0 = (s0 & 3) * 8;
    int ar1 = s1 >> 2, ak1 = (s1 & 3) * 8;
    int am0 = min(bm + ar0, M - 1);
    int am1 = min(bm + ar1, M - 1);
    const unsigned short* Ap0 = A + (size_t)am0 * K + ak0;
    const unsigned short* Ap1 = A + (size_t)am1 * K + ak1;
    const unsigned short* Bp0 = Bt + (size_t)(bn + ar0) * K + ak0;
    const unsigned short* Bp1 = Bt + (size_t)(bn + ar1) * K + ak1;

    int o0 = (w * 64) * 8, o1 = (256 + w * 64) * 8;

    int fr = l & 15, fq = l >> 4;
    int aoff = (wm + fr) * 32 + fq * 8;
    int boff = (wn + fr) * 32 + fq * 8;

    int nt = K >> 5;   // even for all call sites (K % 64 == 0)

    // ---- prologue: stage tile 0 -> buf 0 ----
    async_copy16(Ap0, &As[0][o0]);
    async_copy16(Ap1, &As[0][o1]);
    async_copy16(Bp0, &Bs[0][o0]);
    async_copy16(Bp1, &Bs[0][o1]);
    __syncthreads();

    for (int tt = 0; tt < nt; tt += 2) {
        // ---- phase A: stage tile tt+1 -> buf1, then compute buf0 ----
        {
            int k1 = (tt + 1) << 5;
            async_copy16(Ap0 + k1, &As[1][o0]);
            async_copy16(Ap1 + k1, &As[1][o1]);
            async_copy16(Bp0 + k1, &Bs[1][o0]);
            async_copy16(Bp1 + k1, &Bs[1][o1]);
        }
        {
            shortx8 af[4], bf[4];
#pragma unroll
            for (int i = 0; i < 4; ++i) af[i] = *(const shortx8*)&As[0][aoff + i * 16 * 32];
#pragma unroll
            for (int j = 0; j < 4; ++j) bf[j] = *(const shortx8*)&Bs[0][boff + j * 16 * 32];
#pragma unroll
            for (int i = 0; i < 4; ++i)
#pragma unroll
                for (int j = 0; j < 4; ++j)
                    acc[i][j] = __builtin_amdgcn_mfma_f32_16x16x32_bf16(bf[j], af[i], acc[i][j], 0, 0, 0);
        }
        __syncthreads();

        // ---- phase B: stage tile tt+2 -> buf0, then compute buf1 ----
        if (tt + 2 < nt) {
            int k2 = (tt + 2) << 5;
            async_copy16(Ap0 + k2, &As[0][o0]);
            async_copy16(Ap1 + k2, &As[0][o1]);
            async_copy16(Bp0 + k2, &Bs[0][o0]);
            async_copy16(Bp1 + k2, &Bs[0][o1]);
        }
        {
            shortx8 af[4], bf[4];
#pragma unroll
            for (int i = 0; i < 4; ++i) af[i] = *(const shortx8*)&As[1][aoff + i * 16 * 32];
#pragma unroll
            for (int j = 0; j < 4; ++j) bf[j] = *(const shortx8*)&Bs[1][boff + j * 16 * 32];
#pragma unroll
            for (int i = 0; i < 4; ++i)
#pragma unroll
                for (int j = 0; j < 4; ++j)
                    acc[i][j] = __builtin_amdgcn_mfma_f32_16x16x32_bf16(bf[j], af[i], acc[i][j], 0, 0, 0);
        }
        __syncthreads();
    }

    // ---- epilogue: lane owns rows (i*16+fr), cols (j*16+fq*4 .. +3) ----
    float4 bb[4];
#pragma unroll
    for (int j = 0; j < 4; ++j)
        bb[j] = *(const float4*)&bias[bn + wn + j * 16 + fq * 4];

#pragma unroll
    for (int i = 0; i < 4; ++i) {
        int row = bm + wm + i * 16 + fr;
        if (row >= M) continue;
#pragma unroll
        for (int j = 0; j < 4; ++j) {
            int col = bn + wn + j * 16 + fq * 4;
            float v0 = acc[i][j][0] + bb[j].x;
            float v1 = acc[i][j][1] + bb[j].y;
            float v2 = acc[i][j][2] + bb[j].z;
            float v3 = acc[i][j][3] + bb[j].w;
            if (RELU) {
                v0 = fmaxf(v0, 0.f); v1 = fmaxf(v1, 0.f);
                v2 = fmaxf(v2, 0.f); v3 = fmaxf(v3, 0.f);
            }
            if (OUT_BF16) {
                ushort4 o;
                o.x = f2b(v0); o.y = f2b(v1); o.z = f2b(v2); o.w = f2b(v3);
                *(ushort4*)&((unsigned short*)C)[(size_t)row * N + col] = o;
            } else {
                float4 o;
                o.x = v0; o.y = v1; o.z = v2; o.w = v3;
                *(float4*)&((float*)C)[(size_t)row * N + col] = o;
            }
        }
    }
}

// ---------------- fp32 -> bf16 elementwise (n % 4 == 0) --------------------
__global__ void cvt_b16_kernel(const float* __restrict__ in, unsigned short* __restrict__ out, size_t n4)
{
    size_t i = (size_t)blockIdx.x * blockDim.x + threadIdx.x;
    if (i >= n4) return;
    float4 v = ((const float4*)in)[i];
    ushort4 o;
    o.x = f2b(v.x); o.y = f2b(v.y); o.z = f2b(v.z); o.w = f2b(v.w);
    ((ushort4*)out)[i] = o;
}

// ---------------- W[K,N] fp32 -> Wt[N,K] bf16 (K,N % 32 == 0) --------------
__global__ __launch_bounds__(256) void transpose_b16_kernel(
    const float* __restrict__ W, unsigned short* __restrict__ Wt, int Kd, int Nd)
{
    __shared__ float tile[32][33];
    int bx = blockIdx.x * 32;   // N
    int by = blockIdx.y * 32;   // K
    int tx = threadIdx.x & 31, ty = threadIdx.x >> 5;  // 32 x 8
#pragma unroll
    for (int i = 0; i < 32; i += 8)
        tile[ty + i][tx] = W[(size_t)(by + ty + i) * Nd + bx + tx];
    __syncthreads();
#pragma unroll
    for (int i = 0; i < 32; i += 8)
        Wt[(size_t)(bx + ty + i) * Kd + by + tx] = f2b(tile[tx][ty + i]);
}

// ---------------- bias concat for fused projection -------------------------
__global__ void bcat_kernel(const float* __restrict__ okb, const float* __restrict__ ovb,
                            const float* __restrict__ oqb, const float* __restrict__ skb,
                            const float* __restrict__ sqb, float* __restrict__ bcat)
{
    int i = blockIdx.x * 256 + threadIdx.x;  // 0..2047
    float v;
    if      (i < 512)  v = okb[i];
    else if (i < 1024) v = ovb[i - 512];
    else if (i < 1536) v = oqb[i - 1024];
    else if (i < 1792) v = skb[i - 1536];
    else               v = sqb[i - 1792];
    bcat[i] = v;
}

// ---------------- generic tiled fp32 GEMM (o-proj only) --------------------
__global__ __launch_bounds__(256) void gemm_kernel(
    const float* __restrict__ A, const float* __restrict__ W,
    const float* __restrict__ bias, float* __restrict__ C,
    int M, int N, int K, int relu)
{
    __shared__ float As[16][68];
    __shared__ float Ws[16][68];
    int t  = threadIdx.x;
    int tx = t & 15, ty = t >> 4;
    int bm = blockIdx.x * 64, bn = blockIdx.y * 64;
    float acc[4][4] = {};

    for (int k0 = 0; k0 < K; k0 += 16) {
#pragma unroll
        for (int e = 0; e < 4; ++e) {
            int idx = t + e * 256;
            int kk = idx & 15, m = idx >> 4;
            int row = bm + m;
            As[kk][m] = (row < M) ? A[(size_t)row * K + k0 + kk] : 0.f;
        }
#pragma unroll
        for (int e = 0; e < 4; ++e) {
            int idx = t + e * 256;
            int n = idx & 63, kk = idx >> 6;
            Ws[kk][n] = W[(size_t)(k0 + kk) * N + bn + n];
        }
        __syncthreads();
#pragma unroll
        for (int kk = 0; kk < 16; ++kk) {
            float4 a4 = *(const float4*)&As[kk][ty * 4];
            float4 b4 = *(const float4*)&Ws[kk][tx * 4];
            float av[4] = {a4.x, a4.y, a4.z, a4.w};
            float bv[4] = {b4.x, b4.y, b4.z, b4.w};
#pragma unroll
            for (int i = 0; i < 4; ++i)
#pragma unroll
                for (int j = 0; j < 4; ++j)
                    acc[i][j] += av[i] * bv[j];
        }
        __syncthreads();
    }

#pragma unroll
    for (int i = 0; i < 4; ++i) {
        int row = bm + ty * 4 + i;
        if (row >= M) continue;
        int col = bn + tx * 4;
        float4 bb = *(const float4*)&bias[col];
        float4 r;
        r.x = acc[i][0] + bb.x; r.y = acc[i][1] + bb.y;
        r.z = acc[i][2] + bb.z; r.w = acc[i][3] + bb.w;
        if (relu) {
            r.x = fmaxf(r.x, 0.f); r.y = fmaxf(r.y, 0.f);
            r.z = fmaxf(r.z, 0.f); r.w = fmaxf(r.w, 0.f);
        }
        *(float4*)&C[(size_t)row * N + col] = r;
    }
}

// ---------------- s = h2(bf16) @ t2w2 + t2b2 (one wave per row) ------------
__global__ __launch_bounds__(64) void rowdot512_b16_kernel(
    const unsigned short* __restrict__ A, const float* __restrict__ w,
    const float* __restrict__ bptr, float* __restrict__ out)
{
    int row = blockIdx.x;
    int lane = threadIdx.x;
    const unsigned short* a = A + (size_t)row * DD;
    float v = 0.f;
#pragma unroll
    for (int i = 0; i < 8; ++i) v += b2f(a[lane + 64 * i]) * w[lane + 64 * i];
#pragma unroll
    for (int d = 32; d > 0; d >>= 1) v += __shfl_down(v, d, 64);
    if (lane == 0) out[row] = v + bptr[0];
}

// ---------------- segment machinery ----------------------------------------
__global__ void seg_offsets_kernel(const int* __restrict__ lens, int* __restrict__ offs, int E)
{
    if (threadIdx.x == 0 && blockIdx.x == 0) {
        int acc = 0;
        for (int g = 0; g < E; ++g) { offs[g] = acc; acc += lens[g]; }
        offs[E] = acc;
    }
}

__global__ void fill_seg_kernel(const int* __restrict__ offs, int* __restrict__ seg)
{
    int g = blockIdx.x;
    int o = offs[g], e = offs[g + 1];
    for (int i = o + threadIdx.x; i < e; i += blockDim.x) seg[i] = g;
}

__global__ __launch_bounds__(384) void seg_softmax_kernel(
    const float* __restrict__ s, const int* __restrict__ offs, float* __restrict__ wgt)
{
    __shared__ float red[8];
    int g = blockIdx.x;
    int o = offs[g], len = offs[g + 1] - o;
    int t = threadIdx.x;
    int lane = t & 63, wid = t >> 6;

    float v = (t < len) ? s[o + t] : NEG_BIG;
    float m = v;
#pragma unroll
    for (int d = 32; d > 0; d >>= 1) m = fmaxf(m, __shfl_down(m, d, 64));
    if (lane == 0) red[wid] = m;
    __syncthreads();
    if (t == 0) {
        float mm = red[0];
        for (int i = 1; i < 6; ++i) mm = fmaxf(mm, red[i]);
        red[6] = mm;
    }
    __syncthreads();
    float M = red[6];

    float p = (t < len) ? expf(v - M) : 0.f;
    float sum = p;
#pragma unroll
    for (int d = 32; d > 0; d >>= 1) sum += __shfl_down(sum, d, 64);
    if (lane == 0) red[wid] = sum;
    __syncthreads();
    if (t == 0) {
        float ss = red[0];
        for (int i = 1; i < 6; ++i) ss += red[i];
        red[7] = ss;
    }
    __syncthreads();
    if (t < len) wgt[o + t] = p / red[7];
}

__global__ __launch_bounds__(256) void seg_wsum_kernel(
    const unsigned short* __restrict__ att_x, const float* __restrict__ wgt,
    const int* __restrict__ offs, float* __restrict__ rep)
{
    int g = blockIdx.x;
    int o = offs[g], e = offs[g + 1];
    int c = threadIdx.x;
    float a0 = 0.f, a1 = 0.f;
    for (int i = o; i < e; ++i) {
        float w = wgt[i];
        const unsigned short* r = att_x + (size_t)i * DD;
        a0 += b2f(r[c]) * w;
        a1 += b2f(r[c + 256]) * w;
    }
    rep[(size_t)g * DD + c] = a0;
    rep[(size_t)g * DD + c + 256] = a1;
}

// ---------------- block reduce helpers -------------------------------------
__device__ __forceinline__ float block_sum_256(float v, float* red)
{
    int lane = threadIdx.x & 63, wid = threadIdx.x >> 6;
#pragma unroll
    for (int d = 32; d > 0; d >>= 1) v += __shfl_down(v, d, 64);
    if (lane == 0) red[wid] = v;
    __syncthreads();
    float r = red[0] + red[1] + red[2] + red[3];
    __syncthreads();
    return r;
}

__device__ __forceinline__ float block_max_256(float v, float* red)
{
    int lane = threadIdx.x & 63, wid = threadIdx.x >> 6;
#pragma unroll
    for (int d = 32; d > 0; d >>= 1) v = fmaxf(v, __shfl_down(v, d, 64));
    if (lane == 0) red[wid] = v;
    __syncthreads();
    float r = fmaxf(fmaxf(red[0], red[1]), fmaxf(red[2], red[3]));
    __syncthreads();
    return r;
}

// ---------------- LN1: out = LN(x + att_x(bf16)*wgt[row]) ------------------
__global__ __launch_bounds__(256) void ln1_kernel(
    const float* __restrict__ x, const unsigned short* __restrict__ att_x,
    const float* __restrict__ wgt, const float* __restrict__ w,
    const float* __restrict__ b, float* __restrict__ out)
{
    __shared__ float red[4];
    size_t row = blockIdx.x;
    int c = threadIdx.x;
    float wr = wgt[row];
    const float* xr = x + row * DD;
    const unsigned short* ar = att_x + row * DD;
    float v0 = xr[c] + b2f(ar[c]) * wr;
    float v1 = xr[c + 256] + b2f(ar[c + 256]) * wr;
    float mean = block_sum_256(v0 + v1, red) * (1.f / 512.f);
    float d0 = v0 - mean, d1 = v1 - mean;
    float var = block_sum_256(d0 * d0 + d1 * d1, red) * (1.f / 512.f);
    float rstd = rsqrtf(var + 1e-5f);
    out[row * DD + c] = d0 * rstd * w[c] + b[c];
    out[row * DD + c + 256] = d1 * rstd * w[c + 256] + b[c + 256];
}

// ---------------- LN2 (in-place) + bf16 copy -------------------------------
__global__ __launch_bounds__(256) void ln2_kernel(
    float* __restrict__ xb, const float* __restrict__ o,
    const int* __restrict__ seg, const float* __restrict__ w,
    const float* __restrict__ b, unsigned short* __restrict__ xb16)
{
    __shared__ float red[4];
    size_t row = blockIdx.x;
    int c = threadIdx.x;
    int g = seg[row];
    const float* orow = o + (size_t)g * DD;
    float v0 = xb[row * DD + c] + orow[c];
    float v1 = xb[row * DD + c + 256] + orow[c + 256];
    float mean = block_sum_256(v0 + v1, red) * (1.f / 512.f);
    float d0 = v0 - mean, d1 = v1 - mean;
    float var = block_sum_256(d0 * d0 + d1 * d1, red) * (1.f / 512.f);
    float rstd = rsqrtf(var + 1e-5f);
    float y0 = d0 * rstd * w[c] + b[c];
    float y1 = d1 * rstd * w[c + 256] + b[c + 256];
    xb[row * DD + c] = y0;
    xb[row * DD + c + 256] = y1;
    xb16[row * DD + c] = f2b(y0);
    xb16[row * DD + c + 256] = f2b(y1);
}

// ---------------- LN3 + FiLM (ffn in bf16) ---------------------------------
__global__ __launch_bounds__(256) void ln3_film_kernel(
    const float* __restrict__ xb, const unsigned short* __restrict__ ffn,
    const int* __restrict__ mode, const float* __restrict__ w,
    const float* __restrict__ b, const float* __restrict__ msc,
    const float* __restrict__ msh, float* __restrict__ out)
{
    __shared__ float red[4];
    size_t row = blockIdx.x;
    int c = threadIdx.x;
    int md = mode[row];
    float v0 = xb[row * DD + c] + b2f(ffn[row * DD + c]);
    float v1 = xb[row * DD + c + 256] + b2f(ffn[row * DD + c + 256]);
    float mean = block_sum_256(v0 + v1, red) * (1.f / 512.f);
    float d0 = v0 - mean, d1 = v1 - mean;
    float var = block_sum_256(d0 * d0 + d1 * d1, red) * (1.f / 512.f);
    float rstd = rsqrtf(var + 1e-5f);
    float y0 = d0 * rstd * w[c] + b[c];
    float y1 = d1 * rstd * w[c + 256] + b[c + 256];
    float p0 = y0 * msc[(size_t)md * DD + c] + msh[(size_t)md * DD + c];
    float p1 = y1 * msc[(size_t)md * DD + c + 256] + msh[(size_t)md * DD + c + 256];
    out[row * DD + c] = fmaxf(p0, 0.f) + y0;
    out[row * DD + c + 256] = fmaxf(p1, 0.f) + y1;
}

// ---------------- new_rep = concat(past_rep, sample_rep) -------------------
__global__ void newrep_kernel(const float* __restrict__ past, const float* __restrict__ rep,
                              float* __restrict__ out, int total)
{
    int i = blockIdx.x * blockDim.x + threadIdx.x;
    if (i >= total) return;
    out[i] = (i < PP * DD) ? past[i] : rep[i - PP * DD];
}

// ---------------- attention scores: S[h][q][k] = (Q·K)/8 -------------------
__global__ __launch_bounds__(256) void attn_scores_kernel(
    const float* __restrict__ proj, float* __restrict__ S, int pe)
{
    int q0 = blockIdx.x * 64;
    int k0 = blockIdx.y * 64;
    int h  = blockIdx.z;
    if (k0 > PP + q0 + 63) return;          // fully-masked causal tile

    int qcol = (h < 8) ? (1024 + h * 64) : (1792 + (h - 8) * 64);
    int kcol = (h < 8) ? (h * 64)        : (1536 + (h - 8) * 64);

    __shared__ float Qs[64][LDT];   // [d][q]
    __shared__ float Ks[64][LDT];   // [d][k]
    int t = threadIdx.x;
    int r = t >> 2, c4 = (t & 3) * 16;
    const float* qsrc = proj + (size_t)(PP + q0 + r) * 2048 + qcol + c4;
    const float* ksrc = proj + (size_t)(k0 + r) * 2048 + kcol + c4;
#pragma unroll
    for (int e = 0; e < 4; ++e) {
        float4 v = *(const float4*)(qsrc + e * 4);
        Qs[c4 + e * 4 + 0][r] = v.x; Qs[c4 + e * 4 + 1][r] = v.y;
        Qs[c4 + e * 4 + 2][r] = v.z; Qs[c4 + e * 4 + 3][r] = v.w;
        float4 u = *(const float4*)(ksrc + e * 4);
        Ks[c4 + e * 4 + 0][r] = u.x; Ks[c4 + e * 4 + 1][r] = u.y;
        Ks[c4 + e * 4 + 2][r] = u.z; Ks[c4 + e * 4 + 3][r] = u.w;
    }
    __syncthreads();

    int tx = t & 15, ty = t >> 4;           // tx -> 4 k cols, ty -> 4 q rows
    float acc[4][4] = {};
#pragma unroll 4
    for (int d = 0; d < 64; ++d) {
        float4 a = *(const float4*)&Qs[d][ty * 4];
        float4 b = *(const float4*)&Ks[d][tx * 4];
        float av[4] = {a.x, a.y, a.z, a.w};
        float bv[4] = {b.x, b.y, b.z, b.w};
#pragma unroll
        for (int i = 0; i < 4; ++i)
#pragma unroll
            for (int j = 0; j < 4; ++j)
                acc[i][j] += av[i] * bv[j];
    }

    float* Sh = S + ((size_t)h * 256 + q0) * pe + k0;
#pragma unroll
    for (int i = 0; i < 4; ++i) {
        float4 o;
        o.x = acc[i][0] * 0.125f; o.y = acc[i][1] * 0.125f;
        o.z = acc[i][2] * 0.125f; o.w = acc[i][3] * 0.125f;
        *(float4*)&Sh[(size_t)(ty * 4 + i) * pe + tx * 4] = o;
    }
}

// ---------------- attention softmax: P in place, diag u for score heads ----
__global__ __launch_bounds__(256) void attn_softmax_kernel(
    float* __restrict__ S, float* __restrict__ u4, int pe)
{
    __shared__ float red[4];
    int q = blockIdx.x;
    int h = blockIdx.y;
    int limq = PP + q;                       // inclusive
    float* row = S + ((size_t)h * 256 + q) * pe;
    int t = threadIdx.x;

    float m = NEG_BIG;
    for (int k = t; k <= limq; k += 256) m = fmaxf(m, row[k]);
    float M = block_max_256(m, red);

    float s = 0.f;
    for (int k = t; k <= limq; k += 256) s += expf(row[k] - M);
    float SUM = block_sum_256(s, red);
    float inv = 1.f / SUM;

    if (h < 8) {
        for (int k = t; k < pe; k += 256)
            row[k] = (k <= limq) ? expf(row[k] - M) * inv : 0.f;
    } else {
        if (t == 0) u4[q * 4 + (h - 8)] = expf(row[limq] - M) * inv;
    }
}

// ---------------- attention PV: ob[q][h*64+d] = P[h][q][:] @ V[:][d] -------
__global__ __launch_bounds__(256) void attn_pv_kernel(
    const float* __restrict__ S, const float* __restrict__ proj,
    float* __restrict__ ob, int pe)
{
    __shared__ float Ps[64][36];    // [k][q] transposed, q-width 32
    __shared__ float Vs[64][LDT];   // [k][d]
    int q0 = blockIdx.x * 32;
    int h  = blockIdx.y;
    int ktiles = (PP + q0 + 31) / 64 + 1;    // covers all k <= PP+q0+31

    int t = threadIdx.x;
    int tx = t & 15, ty = t >> 4;            // tx -> 4 d cols, ty -> 2 q rows
    int rp = t >> 3, c8 = (t & 7) * 8;       // P staging: 32 rows x 8 cols
    int rv = t >> 2, c16 = (t & 3) * 16;     // V staging: 64 rows x 16 cols
    float acc[2][4] = {};

    for (int kt = 0; kt < ktiles; ++kt) {
        int k0 = kt * 64;
        const float* psrc = S + ((size_t)h * 256 + q0 + rp) * pe + k0 + c8;
        const float* vsrc = proj + (size_t)(k0 + rv) * 2048 + 512 + h * 64 + c16;
#pragma unroll
        for (int e = 0; e < 2; ++e) {
            float4 v = *(const float4*)(psrc + e * 4);
            Ps[c8 + e * 4 + 0][rp] = v.x; Ps[c8 + e * 4 + 1][rp] = v.y;
            Ps[c8 + e * 4 + 2][rp] = v.z; Ps[c8 + e * 4 + 3][rp] = v.w;
        }
#pragma unroll
        for (int e = 0; e < 4; ++e)
            *(float4*)&Vs[rv][c16 + e * 4] = *(const float4*)(vsrc + e * 4);
        __syncthreads();

#pragma unroll 8
        for (int kk = 0; kk < 64; ++kk) {
            float2 a = *(const float2*)&Ps[kk][ty * 2];
            float4 b = *(const float4*)&Vs[kk][tx * 4];
            float av[2] = {a.x, a.y};
            float bv[4] = {b.x, b.y, b.z, b.w};
#pragma unroll
            for (int i = 0; i < 2; ++i)
#pragma unroll
                for (int j = 0; j < 4; ++j)
                    acc[i][j] += av[i] * bv[j];
        }
        __syncthreads();
    }

#pragma unroll
    for (int i = 0; i < 2; ++i) {
        float4 o;
        o.x = acc[i][0]; o.y = acc[i][1]; o.z = acc[i][2]; o.w = acc[i][3];
        *(float4*)&ob[(size_t)(q0 + ty * 2 + i) * DD + h * 64 + tx * 4] = o;
    }
}

// ---------------- cumprod finalize (head-mean + reversed cumprod) ----------
__global__ void finalize_kernel(const float* __restrict__ u4, float* __restrict__ out_past,
                                float* __restrict__ out_us, int E)
{
    if (threadIdx.x == 0 && blockIdx.x == 0) {
        float uE = 0.25f * (u4[(E - 1) * 4] + u4[(E - 1) * 4 + 1] + u4[(E - 1) * 4 + 2] + u4[(E - 1) * 4 + 3]);
        out_us[E - 1] = uE;
        float pf = 1.f;
        for (int i = E - 1; i >= 0; --i) {
            float u = 0.25f * (u4[i * 4] + u4[i * 4 + 1] + u4[i * 4 + 2] + u4[i * 4 + 3]);
            if (i < E - 1) out_us[i] = u * pf;
            pf = (1.f - u) * pf;
        }
        out_past[0] = pf;
    }
}

// ---------------------------------------------------------------------------
extern "C" void kernel_launch(void* const* d_in, const int* in_sizes, int n_in,
                              void* d_out, int out_size, void* d_ws, size_t ws_size,
                              hipStream_t stream)
{
    const float* x    = (const float*)d_in[0];
    const float* past = (const float*)d_in[1];
    const int*   lens = (const int*)d_in[2];
    const int*   mode = (const int*)d_in[3];
    const float* t1w1 = (const float*)d_in[4];
    const float* t1b1 = (const float*)d_in[5];
    const float* t1w2 = (const float*)d_in[6];
    const float* t1b2 = (const float*)d_in[7];
    const float* t2w1 = (const float*)d_in[8];
    const float* t2b1 = (const float*)d_in[9];
    const float* t2w2 = (const float*)d_in[10];
    const float* t2b2 = (const float*)d_in[11];
    const float* oq_w = (const float*)d_in[12];
    const float* oq_b = (const float*)d_in[13];
    const float* ok_w = (const float*)d_in[14];
    const float* ok_b = (const float*)d_in[15];
    const float* ov_w = (const float*)d_in[16];
    const float* ov_b = (const float*)d_in[17];
    const float* oo_w = (const float*)d_in[18];
    const float* oo_b = (const float*)d_in[19];
    const float* sq_w = (const float*)d_in[20];
    const float* sq_b = (const float*)d_in[21];
    const float* sk_w = (const float*)d_in[22];
    const float* sk_b = (const float*)d_in[23];
    const float* f1w  = (const float*)d_in[24];
    const float* f1b  = (const float*)d_in[25];
    const float* f2w  = (const float*)d_in[26];
    const float* f2b_ = (const float*)d_in[27];
    const float* ln1w = (const float*)d_in[28];
    const float* ln1b = (const float*)d_in[29];
    const float* ln2w = (const float*)d_in[30];
    const float* ln2b = (const float*)d_in[31];
    const float* ln3w = (const float*)d_in[32];
    const float* ln3b = (const float*)d_in[33];
    const float* msc  = (const float*)d_in[34];
    const float* msh  = (const float*)d_in[35];

    int N  = in_sizes[0] / DD;
    int E  = in_sizes[2];
    int PE = PP + E;
    if (N <= 0) return;

    float* out        = (float*)d_out;
    float* out_x      = out;
    float* out_past   = out + (size_t)N * DD;
    float* out_us     = out_past + 1;
    float* out_newrep = out_us + E;

    // ---- workspace layout ----
    const int CH = 16384;                               // FFN row-chunk
    char* wp = (char*)d_ws;
    unsigned short* b16_a = (unsigned short*)wp;  wp += (size_t)N * DD * 2;
    unsigned short* b16_b = (unsigned short*)wp;  wp += (size_t)N * DD * 2;
    unsigned short* ffh   = (unsigned short*)wp;  wp += (size_t)CH * FF * 2;
    unsigned short* wt1   = (unsigned short*)wp;  wp += (size_t)DD * DD * 2;
    unsigned short* wt2   = (unsigned short*)wp;  wp += (size_t)DD * DD * 2;
    unsigned short* wt3   = (unsigned short*)wp;  wp += (size_t)DD * DD * 2;
    unsigned short* wtf1  = (unsigned short*)wp;  wp += (size_t)FF * DD * 2;
    unsigned short* wtf2  = (unsigned short*)wp;  wp += (size_t)DD * FF * 2;
    unsigned short* wtcat = (unsigned short*)wp;  wp += (size_t)2048 * DD * 2;  // [2048][512]
    unsigned short* nr16  = (unsigned short*)wp;  wp += (size_t)PE * DD * 2;
    float* bcat = (float*)wp;  wp += 2048 * 4;
    float* proj = (float*)wp;  wp += (size_t)PE * 2048 * 4;   // fused projections
    float* sbuf = (float*)wp;  wp += (size_t)N * 4;
    float* wgt  = (float*)wp;  wp += (size_t)N * 4;
    float* rep  = (float*)wp;  wp += (size_t)E * DD * 4;
    float* ob   = (float*)wp;  wp += (size_t)E * DD * 4;
    float* oprj = (float*)wp;  wp += (size_t)E * DD * 4;
    float* u4   = (float*)wp;  wp += (size_t)E * 4 * 4;
    int*   seg  = (int*)wp;    wp += (size_t)N * 4;
    int*   offs = (int*)wp;

    // S/P buffer [12][E][PE] fp32 aliases ffh (attention completes before FFN)
    float* S = (float*)ffh;

    int mg128 = (N + 127) / 128;

    // ---- weight prep: transposes to [N,K] bf16 + fused-projection concat ----
    transpose_b16_kernel<<<dim3(DD / 32, DD / 32), 256, 0, stream>>>(t1w1, wt1, DD, DD);
    transpose_b16_kernel<<<dim3(DD / 32, DD / 32), 256, 0, stream>>>(t1w2, wt2, DD, DD);
    transpose_b16_kernel<<<dim3(DD / 32, DD / 32), 256, 0, stream>>>(t2w1, wt3, DD, DD);
    transpose_b16_kernel<<<dim3(FF / 32, DD / 32), 256, 0, stream>>>(f1w, wtf1, DD, FF);
    transpose_b16_kernel<<<dim3(DD / 32, FF / 32), 256, 0, stream>>>(f2w, wtf2, FF, DD);
    transpose_b16_kernel<<<dim3(DD / 32, DD / 32), 256, 0, stream>>>(ok_w, wtcat,              DD, DD);
    transpose_b16_kernel<<<dim3(DD / 32, DD / 32), 256, 0, stream>>>(ov_w, wtcat + 512 * DD,  DD, DD);
    transpose_b16_kernel<<<dim3(DD / 32, DD / 32), 256, 0, stream>>>(oq_w, wtcat + 1024 * DD, DD, DD);
    transpose_b16_kernel<<<dim3(256 / 32, DD / 32), 256, 0, stream>>>(sk_w, wtcat + 1536 * DD, DD, 256);
    transpose_b16_kernel<<<dim3(256 / 32, DD / 32), 256, 0, stream>>>(sq_w, wtcat + 1792 * DD, DD, 256);
    bcat_kernel<<<8, 256, 0, stream>>>(ok_b, ov_b, oq_b, sk_b, sq_b, bcat);

    // ---- x -> bf16 ----
    size_t n4 = (size_t)N * DD / 4;
    cvt_b16_kernel<<<(int)((n4 + 255) / 256), 256, 0, stream>>>(x, b16_a, n4);

    // ---- inner attention MLPs (bf16 MFMA) ----
    gemm_bf16_kernel<1, 1><<<dim3(mg128, DD / 128), 256, 0, stream>>>(b16_a, wt1, t1b1, b16_b, N, DD, DD);
    gemm_bf16_kernel<1, 0><<<dim3(mg128, DD / 128), 256, 0, stream>>>(b16_b, wt2, t1b2, b16_a, N, DD, DD);
    gemm_bf16_kernel<1, 1><<<dim3(mg128, DD / 128), 256, 0, stream>>>(b16_a, wt3, t2b1, b16_b, N, DD, DD);
    rowdot512_b16_kernel<<<N, 64, 0, stream>>>(b16_b, t2w2, t2b2, sbuf);

    // ---- segment softmax + rep + LN1 ----
    seg_offsets_kernel<<<1, 64, 0, stream>>>(lens, offs, E);
    fill_seg_kernel<<<E, 256, 0, stream>>>(offs, seg);
    seg_softmax_kernel<<<E, 384, 0, stream>>>(sbuf, offs, wgt);
    seg_wsum_kernel<<<E, 256, 0, stream>>>(b16_a, wgt, offs, rep);
    ln1_kernel<<<N, 256, 0, stream>>>(x, b16_a, wgt, ln1w, ln1b, out_x);

    // ---- new_rep output + bf16 copy ----
    int nr_total = PE * DD;
    newrep_kernel<<<(nr_total + 255) / 256, 256, 0, stream>>>(past, rep, out_newrep, nr_total);
    cvt_b16_kernel<<<(nr_total / 4 + 255) / 256, 256, 0, stream>>>(out_newrep, nr16, nr_total / 4);

    // ---- fused K|V|Q|K2|Q2 projection (one MFMA GEMM, N=2048) ----
    gemm_bf16_kernel<0, 0><<<dim3(PE / 128, 2048 / 128), 256, 0, stream>>>(nr16, wtcat, bcat, proj, PE, 2048, DD);

    // ---- outer + score attention as fp32 tiled GEMMs ----
    attn_scores_kernel<<<dim3(E / 64, PE / 64, 12), 256, 0, stream>>>(proj, S, PE);
    attn_softmax_kernel<<<dim3(E, 12), 256, 0, stream>>>(S, u4, PE);
    attn_pv_kernel<<<dim3(E / 32, 8), 256, 0, stream>>>(S, proj, ob, PE);
    gemm_kernel<<<dim3(E / 64, DD / 64), 256, 0, stream>>>(ob, oo_w, oo_b, oprj, E, DD, DD, 0);
    ln2_kernel<<<N, 256, 0, stream>>>(out_x, oprj, seg, ln2w, ln2b, b16_b);
    finalize_kernel<<<1, 64, 0, stream>>>(u4, out_past, out_us, E);

    // ---- FFN (bf16 MFMA, chunked) ----
    for (int r0 = 0; r0 < N; r0 += CH) {
        int mr = N - r0; if (mr > CH) mr = CH;
        int mgc = (mr + 127) / 128;
        gemm_bf16_kernel<1, 1><<<dim3(mgc, FF / 128), 256, 0, stream>>>(
            b16_b + (size_t)r0 * DD, wtf1, f1b, ffh, mr, FF, DD);
        gemm_bf16_kernel<1, 0><<<dim3(mgc, DD / 128), 256, 0, stream>>>(
            ffh, wtf2, f2b_, b16_a + (size_t)r0 * DD, mr, DD, FF);
    }
    ln3_film_kernel<<<N, 256, 0, stream>>>(out_x, b16_a, mode, ln3w, ln3b, msc, msh, out_x);
}

// Round 4
// 1585.037 us; speedup vs baseline: 1.2209x; 1.0486x over previous
//
#include <hip/hip_runtime.h>
#include <hip/hip_bf16.h>
#include <cmath>

// ---------------------------------------------------------------------------
// DAFNetBaseLayer — round 7: parallelized segment-weighted-sum (8-way chunk
// split, 16B/lane loads, deterministic partials+reduce) and vectorized
// rowdot. GEMM/attention structure from r6 (pipelined MFMA, fp32 attention).
// D=512, H=8, DK=64, HS=4, FF=2048, P=512, E=256
// ---------------------------------------------------------------------------

#define DD 512
#define FF 2048
#define PP 512
#define NEG_BIG (-1e30f)
#define LDT 68   // padded LDS stride for 64-wide fp32 tiles

typedef __attribute__((ext_vector_type(8))) short shortx8;   // 8 bf16 = 4 VGPR
typedef __attribute__((ext_vector_type(4))) float floatx4;

__device__ __forceinline__ unsigned short f2b(float f) {
    unsigned int u = __float_as_uint(f);
    unsigned int r = (u + 0x7fffu + ((u >> 16) & 1u)) >> 16;
    return (unsigned short)r;
}
__device__ __forceinline__ float b2f(unsigned short h) {
    return __uint_as_float(((unsigned int)h) << 16);
}

__device__ __forceinline__ void async_copy16(const void* g, void* l) {
    __builtin_amdgcn_global_load_lds(
        (const __attribute__((address_space(1))) unsigned int*)g,
        (__attribute__((address_space(3))) unsigned int*)l, 16, 0, 0);
}

// ---------------- bf16 MFMA GEMM:  C[M,N] = act(A[M,K] @ Bt[N,K]^T + bias) --
// 128x128 tile, BK=32, 256 threads = 4 waves (2x2 of 64x64), 16x16x32 MFMA.
// N % 128 == 0, K % 64 == 0. A,Bt bf16 row-major; bias fp32; C fp32 or bf16.
// Pipeline: 2x LDS buffers, stage(t+1) issued BEFORE compute(t); one
// __syncthreads (vmcnt+lgkmcnt drain) per K-step. Static buffer indices.
template<int OUT_BF16, int RELU>
__global__ __launch_bounds__(256) void gemm_bf16_kernel(
    const unsigned short* __restrict__ A, const unsigned short* __restrict__ Bt,
    const float* __restrict__ bias, void* __restrict__ C,
    int M, int N, int K)
{
    __shared__ unsigned short As[2][128 * 32];
    __shared__ unsigned short Bs[2][128 * 32];

    int t = threadIdx.x;
    int w = t >> 6, l = t & 63;

    // ---- block remap: XCD-contiguous chunks (bijective), N-tile fastest ----
    int nwg = gridDim.x * gridDim.y;
    int bid = blockIdx.x + blockIdx.y * gridDim.x;
    int qch = nwg >> 3, rch = nwg & 7;
    int xcd = bid & 7, lo = bid >> 3;
    int swz = (xcd < rch ? xcd * (qch + 1) : rch * (qch + 1) + (xcd - rch) * qch) + lo;
    int bm = (swz / gridDim.y) * 128;
    int bn = (swz % gridDim.y) * 128;

    int wm = (w >> 1) * 64, wn = (w & 1) * 64;

    // Swapped operands: mfma(bf, af) -> lane&15 indexes M rows, reg-dim
    // indexes 4 consecutive N cols -> vectorized epilogue.
    floatx4 acc[4][4];
#pragma unroll
    for (int i = 0; i < 4; ++i)
#pragma unroll
        for (int j = 0; j < 4; ++j)
#pragma unroll
            for (int r = 0; r < 4; ++r) acc[i][j][r] = 0.f;

    int s0 = t, s1 = 256 + t;
    int ar0 = s0 >> 2, ak0 = (s0 & 3) * 8;
    int ar1 = s1 >> 2, ak1 = (s1 & 3) * 8;
    int am0 = min(bm + ar0, M - 1);
    int am1 = min(bm + ar1, M - 1);
    const unsigned short* Ap0 = A + (size_t)am0 * K + ak0;
    const unsigned short* Ap1 = A + (size_t)am1 * K + ak1;
    const unsigned short* Bp0 = Bt + (size_t)(bn + ar0) * K + ak0;
    const unsigned short* Bp1 = Bt + (size_t)(bn + ar1) * K + ak1;

    int o0 = (w * 64) * 8, o1 = (256 + w * 64) * 8;

    int fr = l & 15, fq = l >> 4;
    int aoff = (wm + fr) * 32 + fq * 8;
    int boff = (wn + fr) * 32 + fq * 8;

    int nt = K >> 5;   // even for all call sites (K % 64 == 0)

    // ---- prologue: stage tile 0 -> buf 0 ----
    async_copy16(Ap0, &As[0][o0]);
    async_copy16(Ap1, &As[0][o1]);
    async_copy16(Bp0, &Bs[0][o0]);
    async_copy16(Bp1, &Bs[0][o1]);
    __syncthreads();

    for (int tt = 0; tt < nt; tt += 2) {
        // ---- phase A: stage tile tt+1 -> buf1, then compute buf0 ----
        {
            int k1 = (tt + 1) << 5;
            async_copy16(Ap0 + k1, &As[1][o0]);
            async_copy16(Ap1 + k1, &As[1][o1]);
            async_copy16(Bp0 + k1, &Bs[1][o0]);
            async_copy16(Bp1 + k1, &Bs[1][o1]);
        }
        {
            shortx8 af[4], bf[4];
#pragma unroll
            for (int i = 0; i < 4; ++i) af[i] = *(const shortx8*)&As[0][aoff + i * 16 * 32];
#pragma unroll
            for (int j = 0; j < 4; ++j) bf[j] = *(const shortx8*)&Bs[0][boff + j * 16 * 32];
#pragma unroll
            for (int i = 0; i < 4; ++i)
#pragma unroll
                for (int j = 0; j < 4; ++j)
                    acc[i][j] = __builtin_amdgcn_mfma_f32_16x16x32_bf16(bf[j], af[i], acc[i][j], 0, 0, 0);
        }
        __syncthreads();

        // ---- phase B: stage tile tt+2 -> buf0, then compute buf1 ----
        if (tt + 2 < nt) {
            int k2 = (tt + 2) << 5;
            async_copy16(Ap0 + k2, &As[0][o0]);
            async_copy16(Ap1 + k2, &As[0][o1]);
            async_copy16(Bp0 + k2, &Bs[0][o0]);
            async_copy16(Bp1 + k2, &Bs[0][o1]);
        }
        {
            shortx8 af[4], bf[4];
#pragma unroll
            for (int i = 0; i < 4; ++i) af[i] = *(const shortx8*)&As[1][aoff + i * 16 * 32];
#pragma unroll
            for (int j = 0; j < 4; ++j) bf[j] = *(const shortx8*)&Bs[1][boff + j * 16 * 32];
#pragma unroll
            for (int i = 0; i < 4; ++i)
#pragma unroll
                for (int j = 0; j < 4; ++j)
                    acc[i][j] = __builtin_amdgcn_mfma_f32_16x16x32_bf16(bf[j], af[i], acc[i][j], 0, 0, 0);
        }
        __syncthreads();
    }

    // ---- epilogue: lane owns rows (i*16+fr), cols (j*16+fq*4 .. +3) ----
    float4 bb[4];
#pragma unroll
    for (int j = 0; j < 4; ++j)
        bb[j] = *(const float4*)&bias[bn + wn + j * 16 + fq * 4];

#pragma unroll
    for (int i = 0; i < 4; ++i) {
        int row = bm + wm + i * 16 + fr;
        if (row >= M) continue;
#pragma unroll
        for (int j = 0; j < 4; ++j) {
            int col = bn + wn + j * 16 + fq * 4;
            float v0 = acc[i][j][0] + bb[j].x;
            float v1 = acc[i][j][1] + bb[j].y;
            float v2 = acc[i][j][2] + bb[j].z;
            float v3 = acc[i][j][3] + bb[j].w;
            if (RELU) {
                v0 = fmaxf(v0, 0.f); v1 = fmaxf(v1, 0.f);
                v2 = fmaxf(v2, 0.f); v3 = fmaxf(v3, 0.f);
            }
            if (OUT_BF16) {
                ushort4 o;
                o.x = f2b(v0); o.y = f2b(v1); o.z = f2b(v2); o.w = f2b(v3);
                *(ushort4*)&((unsigned short*)C)[(size_t)row * N + col] = o;
            } else {
                float4 o;
                o.x = v0; o.y = v1; o.z = v2; o.w = v3;
                *(float4*)&((float*)C)[(size_t)row * N + col] = o;
            }
        }
    }
}

// ---------------- fp32 -> bf16 elementwise (n % 4 == 0) --------------------
__global__ void cvt_b16_kernel(const float* __restrict__ in, unsigned short* __restrict__ out, size_t n4)
{
    size_t i = (size_t)blockIdx.x * blockDim.x + threadIdx.x;
    if (i >= n4) return;
    float4 v = ((const float4*)in)[i];
    ushort4 o;
    o.x = f2b(v.x); o.y = f2b(v.y); o.z = f2b(v.z); o.w = f2b(v.w);
    ((ushort4*)out)[i] = o;
}

// ---------------- W[K,N] fp32 -> Wt[N,K] bf16 (K,N % 32 == 0) --------------
__global__ __launch_bounds__(256) void transpose_b16_kernel(
    const float* __restrict__ W, unsigned short* __restrict__ Wt, int Kd, int Nd)
{
    __shared__ float tile[32][33];
    int bx = blockIdx.x * 32;   // N
    int by = blockIdx.y * 32;   // K
    int tx = threadIdx.x & 31, ty = threadIdx.x >> 5;  // 32 x 8
#pragma unroll
    for (int i = 0; i < 32; i += 8)
        tile[ty + i][tx] = W[(size_t)(by + ty + i) * Nd + bx + tx];
    __syncthreads();
#pragma unroll
    for (int i = 0; i < 32; i += 8)
        Wt[(size_t)(bx + ty + i) * Kd + by + tx] = f2b(tile[tx][ty + i]);
}

// ---------------- bias concat for fused projection -------------------------
__global__ void bcat_kernel(const float* __restrict__ okb, const float* __restrict__ ovb,
                            const float* __restrict__ oqb, const float* __restrict__ skb,
                            const float* __restrict__ sqb, float* __restrict__ bcat)
{
    int i = blockIdx.x * 256 + threadIdx.x;  // 0..2047
    float v;
    if      (i < 512)  v = okb[i];
    else if (i < 1024) v = ovb[i - 512];
    else if (i < 1536) v = oqb[i - 1024];
    else if (i < 1792) v = skb[i - 1536];
    else               v = sqb[i - 1792];
    bcat[i] = v;
}

// ---------------- generic tiled fp32 GEMM (o-proj only) --------------------
__global__ __launch_bounds__(256) void gemm_kernel(
    const float* __restrict__ A, const float* __restrict__ W,
    const float* __restrict__ bias, float* __restrict__ C,
    int M, int N, int K, int relu)
{
    __shared__ float As[16][68];
    __shared__ float Ws[16][68];
    int t  = threadIdx.x;
    int tx = t & 15, ty = t >> 4;
    int bm = blockIdx.x * 64, bn = blockIdx.y * 64;
    float acc[4][4] = {};

    for (int k0 = 0; k0 < K; k0 += 16) {
#pragma unroll
        for (int e = 0; e < 4; ++e) {
            int idx = t + e * 256;
            int kk = idx & 15, m = idx >> 4;
            int row = bm + m;
            As[kk][m] = (row < M) ? A[(size_t)row * K + k0 + kk] : 0.f;
        }
#pragma unroll
        for (int e = 0; e < 4; ++e) {
            int idx = t + e * 256;
            int n = idx & 63, kk = idx >> 6;
            Ws[kk][n] = W[(size_t)(k0 + kk) * N + bn + n];
        }
        __syncthreads();
#pragma unroll
        for (int kk = 0; kk < 16; ++kk) {
            float4 a4 = *(const float4*)&As[kk][ty * 4];
            float4 b4 = *(const float4*)&Ws[kk][tx * 4];
            float av[4] = {a4.x, a4.y, a4.z, a4.w};
            float bv[4] = {b4.x, b4.y, b4.z, b4.w};
#pragma unroll
            for (int i = 0; i < 4; ++i)
#pragma unroll
                for (int j = 0; j < 4; ++j)
                    acc[i][j] += av[i] * bv[j];
        }
        __syncthreads();
    }

#pragma unroll
    for (int i = 0; i < 4; ++i) {
        int row = bm + ty * 4 + i;
        if (row >= M) continue;
        int col = bn + tx * 4;
        float4 bb = *(const float4*)&bias[col];
        float4 r;
        r.x = acc[i][0] + bb.x; r.y = acc[i][1] + bb.y;
        r.z = acc[i][2] + bb.z; r.w = acc[i][3] + bb.w;
        if (relu) {
            r.x = fmaxf(r.x, 0.f); r.y = fmaxf(r.y, 0.f);
            r.z = fmaxf(r.z, 0.f); r.w = fmaxf(r.w, 0.f);
        }
        *(float4*)&C[(size_t)row * N + col] = r;
    }
}

// ---------------- s = h2(bf16) @ t2w2 + t2b2 (one wave per row) ------------
// Lane owns 8 contiguous cols (16B shortx8 load); 64 lanes x 8 = 512.
__global__ __launch_bounds__(64) void rowdot512_b16_kernel(
    const unsigned short* __restrict__ A, const float* __restrict__ w,
    const float* __restrict__ bptr, float* __restrict__ out)
{
    int row = blockIdx.x;
    int lane = threadIdx.x;
    int col = lane * 8;
    shortx8 a8 = *(const shortx8*)(A + (size_t)row * DD + col);
    float4 w0 = *(const float4*)(w + col);
    float4 w1 = *(const float4*)(w + col + 4);
    float v = b2f((unsigned short)a8[0]) * w0.x + b2f((unsigned short)a8[1]) * w0.y
            + b2f((unsigned short)a8[2]) * w0.z + b2f((unsigned short)a8[3]) * w0.w
            + b2f((unsigned short)a8[4]) * w1.x + b2f((unsigned short)a8[5]) * w1.y
            + b2f((unsigned short)a8[6]) * w1.z + b2f((unsigned short)a8[7]) * w1.w;
#pragma unroll
    for (int d = 32; d > 0; d >>= 1) v += __shfl_down(v, d, 64);
    if (lane == 0) out[row] = v + bptr[0];
}

// ---------------- segment machinery ----------------------------------------
__global__ void seg_offsets_kernel(const int* __restrict__ lens, int* __restrict__ offs, int E)
{
    if (threadIdx.x == 0 && blockIdx.x == 0) {
        int acc = 0;
        for (int g = 0; g < E; ++g) { offs[g] = acc; acc += lens[g]; }
        offs[E] = acc;
    }
}

__global__ void fill_seg_kernel(const int* __restrict__ offs, int* __restrict__ seg)
{
    int g = blockIdx.x;
    int o = offs[g], e = offs[g + 1];
    for (int i = o + threadIdx.x; i < e; i += blockDim.x) seg[i] = g;
}

__global__ __launch_bounds__(384) void seg_softmax_kernel(
    const float* __restrict__ s, const int* __restrict__ offs, float* __restrict__ wgt)
{
    __shared__ float red[8];
    int g = blockIdx.x;
    int o = offs[g], len = offs[g + 1] - o;
    int t = threadIdx.x;
    int lane = t & 63, wid = t >> 6;

    float v = (t < len) ? s[o + t] : NEG_BIG;
    float m = v;
#pragma unroll
    for (int d = 32; d > 0; d >>= 1) m = fmaxf(m, __shfl_down(m, d, 64));
    if (lane == 0) red[wid] = m;
    __syncthreads();
    if (t == 0) {
        float mm = red[0];
        for (int i = 1; i < 6; ++i) mm = fmaxf(mm, red[i]);
        red[6] = mm;
    }
    __syncthreads();
    float M = red[6];

    float p = (t < len) ? expf(v - M) : 0.f;
    float sum = p;
#pragma unroll
    for (int d = 32; d > 0; d >>= 1) sum += __shfl_down(sum, d, 64);
    if (lane == 0) red[wid] = sum;
    __syncthreads();
    if (t == 0) {
        float ss = red[0];
        for (int i = 1; i < 6; ++i) ss += red[i];
        red[7] = ss;
    }
    __syncthreads();
    if (t < len) wgt[o + t] = p / red[7];
}

// ---------------- seg weighted sum: 8-way chunk split, partials ------------
// grid (E, 8). 4 warps stride rows by 4; lane owns 8 cols (16B load).
// part[g][ch][512] written deterministically; reduced by the kernel below.
__global__ __launch_bounds__(256) void seg_wsum_part_kernel(
    const unsigned short* __restrict__ att_x, const float* __restrict__ wgt,
    const int* __restrict__ offs, float* __restrict__ part)
{
    __shared__ float sm[4][DD];
    int g = blockIdx.x, ch = blockIdx.y;
    int o = offs[g], e = offs[g + 1];
    int len = e - o;
    int per = (len + 7) >> 3;
    int s = o + ch * per;
    int en = min(s + per, e);

    int t = threadIdx.x, lane = t & 63, w = t >> 6;
    int col = lane * 8;
    float acc[8] = {};
    for (int i = s + w; i < en; i += 4) {
        float wt = wgt[i];
        shortx8 v = *(const shortx8*)(att_x + (size_t)i * DD + col);
#pragma unroll
        for (int j = 0; j < 8; ++j)
            acc[j] += b2f((unsigned short)v[j]) * wt;
    }
#pragma unroll
    for (int j = 0; j < 8; ++j) sm[w][col + j] = acc[j];
    __syncthreads();

    float* pr = part + ((size_t)g * 8 + ch) * DD;
#pragma unroll
    for (int j = 0; j < 2; ++j) {
        int c = t * 2 + j;
        pr[c] = (sm[0][c] + sm[1][c]) + (sm[2][c] + sm[3][c]);
    }
}

__global__ __launch_bounds__(256) void seg_wsum_reduce_kernel(
    const float* __restrict__ part, float* __restrict__ rep)
{
    int g = blockIdx.x;
    int t = threadIdx.x;
#pragma unroll
    for (int j = 0; j < 2; ++j) {
        int c = t * 2 + j;
        float s = 0.f;
#pragma unroll
        for (int ch = 0; ch < 8; ++ch)
            s += part[((size_t)g * 8 + ch) * DD + c];
        rep[(size_t)g * DD + c] = s;
    }
}

// ---------------- block reduce helpers -------------------------------------
__device__ __forceinline__ float block_sum_256(float v, float* red)
{
    int lane = threadIdx.x & 63, wid = threadIdx.x >> 6;
#pragma unroll
    for (int d = 32; d > 0; d >>= 1) v += __shfl_down(v, d, 64);
    if (lane == 0) red[wid] = v;
    __syncthreads();
    float r = red[0] + red[1] + red[2] + red[3];
    __syncthreads();
    return r;
}

__device__ __forceinline__ float block_max_256(float v, float* red)
{
    int lane = threadIdx.x & 63, wid = threadIdx.x >> 6;
#pragma unroll
    for (int d = 32; d > 0; d >>= 1) v = fmaxf(v, __shfl_down(v, d, 64));
    if (lane == 0) red[wid] = v;
    __syncthreads();
    float r = fmaxf(fmaxf(red[0], red[1]), fmaxf(red[2], red[3]));
    __syncthreads();
    return r;
}

// ---------------- LN1: out = LN(x + att_x(bf16)*wgt[row]) ------------------
__global__ __launch_bounds__(256) void ln1_kernel(
    const float* __restrict__ x, const unsigned short* __restrict__ att_x,
    const float* __restrict__ wgt, const float* __restrict__ w,
    const float* __restrict__ b, float* __restrict__ out)
{
    __shared__ float red[4];
    size_t row = blockIdx.x;
    int c = threadIdx.x;
    float wr = wgt[row];
    const float* xr = x + row * DD;
    const unsigned short* ar = att_x + row * DD;
    float v0 = xr[c] + b2f(ar[c]) * wr;
    float v1 = xr[c + 256] + b2f(ar[c + 256]) * wr;
    float mean = block_sum_256(v0 + v1, red) * (1.f / 512.f);
    float d0 = v0 - mean, d1 = v1 - mean;
    float var = block_sum_256(d0 * d0 + d1 * d1, red) * (1.f / 512.f);
    float rstd = rsqrtf(var + 1e-5f);
    out[row * DD + c] = d0 * rstd * w[c] + b[c];
    out[row * DD + c + 256] = d1 * rstd * w[c + 256] + b[c + 256];
}

// ---------------- LN2 (in-place) + bf16 copy -------------------------------
__global__ __launch_bounds__(256) void ln2_kernel(
    float* __restrict__ xb, const float* __restrict__ o,
    const int* __restrict__ seg, const float* __restrict__ w,
    const float* __restrict__ b, unsigned short* __restrict__ xb16)
{
    __shared__ float red[4];
    size_t row = blockIdx.x;
    int c = threadIdx.x;
    int g = seg[row];
    const float* orow = o + (size_t)g * DD;
    float v0 = xb[row * DD + c] + orow[c];
    float v1 = xb[row * DD + c + 256] + orow[c + 256];
    float mean = block_sum_256(v0 + v1, red) * (1.f / 512.f);
    float d0 = v0 - mean, d1 = v1 - mean;
    float var = block_sum_256(d0 * d0 + d1 * d1, red) * (1.f / 512.f);
    float rstd = rsqrtf(var + 1e-5f);
    float y0 = d0 * rstd * w[c] + b[c];
    float y1 = d1 * rstd * w[c + 256] + b[c + 256];
    xb[row * DD + c] = y0;
    xb[row * DD + c + 256] = y1;
    xb16[row * DD + c] = f2b(y0);
    xb16[row * DD + c + 256] = f2b(y1);
}

// ---------------- LN3 + FiLM (ffn in bf16) ---------------------------------
__global__ __launch_bounds__(256) void ln3_film_kernel(
    const float* __restrict__ xb, const unsigned short* __restrict__ ffn,
    const int* __restrict__ mode, const float* __restrict__ w,
    const float* __restrict__ b, const float* __restrict__ msc,
    const float* __restrict__ msh, float* __restrict__ out)
{
    __shared__ float red[4];
    size_t row = blockIdx.x;
    int c = threadIdx.x;
    int md = mode[row];
    float v0 = xb[row * DD + c] + b2f(ffn[row * DD + c]);
    float v1 = xb[row * DD + c + 256] + b2f(ffn[row * DD + c + 256]);
    float mean = block_sum_256(v0 + v1, red) * (1.f / 512.f);
    float d0 = v0 - mean, d1 = v1 - mean;
    float var = block_sum_256(d0 * d0 + d1 * d1, red) * (1.f / 512.f);
    float rstd = rsqrtf(var + 1e-5f);
    float y0 = d0 * rstd * w[c] + b[c];
    float y1 = d1 * rstd * w[c + 256] + b[c + 256];
    float p0 = y0 * msc[(size_t)md * DD + c] + msh[(size_t)md * DD + c];
    float p1 = y1 * msc[(size_t)md * DD + c + 256] + msh[(size_t)md * DD + c + 256];
    out[row * DD + c] = fmaxf(p0, 0.f) + y0;
    out[row * DD + c + 256] = fmaxf(p1, 0.f) + y1;
}

// ---------------- new_rep = concat(past_rep, sample_rep) -------------------
__global__ void newrep_kernel(const float* __restrict__ past, const float* __restrict__ rep,
                              float* __restrict__ out, int total)
{
    int i = blockIdx.x * blockDim.x + threadIdx.x;
    if (i >= total) return;
    out[i] = (i < PP * DD) ? past[i] : rep[i - PP * DD];
}

// ---------------- attention scores: S[h][q][k] = (Q·K)/8 -------------------
__global__ __launch_bounds__(256) void attn_scores_kernel(
    const float* __restrict__ proj, float* __restrict__ S, int pe)
{
    int q0 = blockIdx.x * 64;
    int k0 = blockIdx.y * 64;
    int h  = blockIdx.z;
    if (k0 > PP + q0 + 63) return;          // fully-masked causal tile

    int qcol = (h < 8) ? (1024 + h * 64) : (1792 + (h - 8) * 64);
    int kcol = (h < 8) ? (h * 64)        : (1536 + (h - 8) * 64);

    __shared__ float Qs[64][LDT];   // [d][q]
    __shared__ float Ks[64][LDT];   // [d][k]
    int t = threadIdx.x;
    int r = t >> 2, c4 = (t & 3) * 16;
    const float* qsrc = proj + (size_t)(PP + q0 + r) * 2048 + qcol + c4;
    const float* ksrc = proj + (size_t)(k0 + r) * 2048 + kcol + c4;
#pragma unroll
    for (int e = 0; e < 4; ++e) {
        float4 v = *(const float4*)(qsrc + e * 4);
        Qs[c4 + e * 4 + 0][r] = v.x; Qs[c4 + e * 4 + 1][r] = v.y;
        Qs[c4 + e * 4 + 2][r] = v.z; Qs[c4 + e * 4 + 3][r] = v.w;
        float4 u = *(const float4*)(ksrc + e * 4);
        Ks[c4 + e * 4 + 0][r] = u.x; Ks[c4 + e * 4 + 1][r] = u.y;
        Ks[c4 + e * 4 + 2][r] = u.z; Ks[c4 + e * 4 + 3][r] = u.w;
    }
    __syncthreads();

    int tx = t & 15, ty = t >> 4;           // tx -> 4 k cols, ty -> 4 q rows
    float acc[4][4] = {};
#pragma unroll 4
    for (int d = 0; d < 64; ++d) {
        float4 a = *(const float4*)&Qs[d][ty * 4];
        float4 b = *(const float4*)&Ks[d][tx * 4];
        float av[4] = {a.x, a.y, a.z, a.w};
        float bv[4] = {b.x, b.y, b.z, b.w};
#pragma unroll
        for (int i = 0; i < 4; ++i)
#pragma unroll
            for (int j = 0; j < 4; ++j)
                acc[i][j] += av[i] * bv[j];
    }

    float* Sh = S + ((size_t)h * 256 + q0) * pe + k0;
#pragma unroll
    for (int i = 0; i < 4; ++i) {
        float4 o;
        o.x = acc[i][0] * 0.125f; o.y = acc[i][1] * 0.125f;
        o.z = acc[i][2] * 0.125f; o.w = acc[i][3] * 0.125f;
        *(float4*)&Sh[(size_t)(ty * 4 + i) * pe + tx * 4] = o;
    }
}

// ---------------- attention softmax: P in place, diag u for score heads ----
__global__ __launch_bounds__(256) void attn_softmax_kernel(
    float* __restrict__ S, float* __restrict__ u4, int pe)
{
    __shared__ float red[4];
    int q = blockIdx.x;
    int h = blockIdx.y;
    int limq = PP + q;                       // inclusive
    float* row = S + ((size_t)h * 256 + q) * pe;
    int t = threadIdx.x;

    float m = NEG_BIG;
    for (int k = t; k <= limq; k += 256) m = fmaxf(m, row[k]);
    float M = block_max_256(m, red);

    float s = 0.f;
    for (int k = t; k <= limq; k += 256) s += expf(row[k] - M);
    float SUM = block_sum_256(s, red);
    float inv = 1.f / SUM;

    if (h < 8) {
        for (int k = t; k < pe; k += 256)
            row[k] = (k <= limq) ? expf(row[k] - M) * inv : 0.f;
    } else {
        if (t == 0) u4[q * 4 + (h - 8)] = expf(row[limq] - M) * inv;
    }
}

// ---------------- attention PV: ob[q][h*64+d] = P[h][q][:] @ V[:][d] -------
__global__ __launch_bounds__(256) void attn_pv_kernel(
    const float* __restrict__ S, const float* __restrict__ proj,
    float* __restrict__ ob, int pe)
{
    __shared__ float Ps[64][36];    // [k][q] transposed, q-width 32
    __shared__ float Vs[64][LDT];   // [k][d]
    int q0 = blockIdx.x * 32;
    int h  = blockIdx.y;
    int ktiles = (PP + q0 + 31) / 64 + 1;    // covers all k <= PP+q0+31

    int t = threadIdx.x;
    int tx = t & 15, ty = t >> 4;            // tx -> 4 d cols, ty -> 2 q rows
    int rp = t >> 3, c8 = (t & 7) * 8;       // P staging: 32 rows x 8 cols
    int rv = t >> 2, c16 = (t & 3) * 16;     // V staging: 64 rows x 16 cols
    float acc[2][4] = {};

    for (int kt = 0; kt < ktiles; ++kt) {
        int k0 = kt * 64;
        const float* psrc = S + ((size_t)h * 256 + q0 + rp) * pe + k0 + c8;
        const float* vsrc = proj + (size_t)(k0 + rv) * 2048 + 512 + h * 64 + c16;
#pragma unroll
        for (int e = 0; e < 2; ++e) {
            float4 v = *(const float4*)(psrc + e * 4);
            Ps[c8 + e * 4 + 0][rp] = v.x; Ps[c8 + e * 4 + 1][rp] = v.y;
            Ps[c8 + e * 4 + 2][rp] = v.z; Ps[c8 + e * 4 + 3][rp] = v.w;
        }
#pragma unroll
        for (int e = 0; e < 4; ++e)
            *(float4*)&Vs[rv][c16 + e * 4] = *(const float4*)(vsrc + e * 4);
        __syncthreads();

#pragma unroll 8
        for (int kk = 0; kk < 64; ++kk) {
            float2 a = *(const float2*)&Ps[kk][ty * 2];
            float4 b = *(const float4*)&Vs[kk][tx * 4];
            float av[2] = {a.x, a.y};
            float bv[4] = {b.x, b.y, b.z, b.w};
#pragma unroll
            for (int i = 0; i < 2; ++i)
#pragma unroll
                for (int j = 0; j < 4; ++j)
                    acc[i][j] += av[i] * bv[j];
        }
        __syncthreads();
    }

#pragma unroll
    for (int i = 0; i < 2; ++i) {
        float4 o;
        o.x = acc[i][0]; o.y = acc[i][1]; o.z = acc[i][2]; o.w = acc[i][3];
        *(float4*)&ob[(size_t)(q0 + ty * 2 + i) * DD + h * 64 + tx * 4] = o;
    }
}

// ---------------- cumprod finalize (head-mean + reversed cumprod) ----------
__global__ void finalize_kernel(const float* __restrict__ u4, float* __restrict__ out_past,
                                float* __restrict__ out_us, int E)
{
    if (threadIdx.x == 0 && blockIdx.x == 0) {
        float uE = 0.25f * (u4[(E - 1) * 4] + u4[(E - 1) * 4 + 1] + u4[(E - 1) * 4 + 2] + u4[(E - 1) * 4 + 3]);
        out_us[E - 1] = uE;
        float pf = 1.f;
        for (int i = E - 1; i >= 0; --i) {
            float u = 0.25f * (u4[i * 4] + u4[i * 4 + 1] + u4[i * 4 + 2] + u4[i * 4 + 3]);
            if (i < E - 1) out_us[i] = u * pf;
            pf = (1.f - u) * pf;
        }
        out_past[0] = pf;
    }
}

// ---------------------------------------------------------------------------
extern "C" void kernel_launch(void* const* d_in, const int* in_sizes, int n_in,
                              void* d_out, int out_size, void* d_ws, size_t ws_size,
                              hipStream_t stream)
{
    const float* x    = (const float*)d_in[0];
    const float* past = (const float*)d_in[1];
    const int*   lens = (const int*)d_in[2];
    const int*   mode = (const int*)d_in[3];
    const float* t1w1 = (const float*)d_in[4];
    const float* t1b1 = (const float*)d_in[5];
    const float* t1w2 = (const float*)d_in[6];
    const float* t1b2 = (const float*)d_in[7];
    const float* t2w1 = (const float*)d_in[8];
    const float* t2b1 = (const float*)d_in[9];
    const float* t2w2 = (const float*)d_in[10];
    const float* t2b2 = (const float*)d_in[11];
    const float* oq_w = (const float*)d_in[12];
    const float* oq_b = (const float*)d_in[13];
    const float* ok_w = (const float*)d_in[14];
    const float* ok_b = (const float*)d_in[15];
    const float* ov_w = (const float*)d_in[16];
    const float* ov_b = (const float*)d_in[17];
    const float* oo_w = (const float*)d_in[18];
    const float* oo_b = (const float*)d_in[19];
    const float* sq_w = (const float*)d_in[20];
    const float* sq_b = (const float*)d_in[21];
    const float* sk_w = (const float*)d_in[22];
    const float* sk_b = (const float*)d_in[23];
    const float* f1w  = (const float*)d_in[24];
    const float* f1b  = (const float*)d_in[25];
    const float* f2w  = (const float*)d_in[26];
    const float* f2b_ = (const float*)d_in[27];
    const float* ln1w = (const float*)d_in[28];
    const float* ln1b = (const float*)d_in[29];
    const float* ln2w = (const float*)d_in[30];
    const float* ln2b = (const float*)d_in[31];
    const float* ln3w = (const float*)d_in[32];
    const float* ln3b = (const float*)d_in[33];
    const float* msc  = (const float*)d_in[34];
    const float* msh  = (const float*)d_in[35];

    int N  = in_sizes[0] / DD;
    int E  = in_sizes[2];
    int PE = PP + E;
    if (N <= 0) return;

    float* out        = (float*)d_out;
    float* out_x      = out;
    float* out_past   = out + (size_t)N * DD;
    float* out_us     = out_past + 1;
    float* out_newrep = out_us + E;

    // ---- workspace layout ----
    const int CH = 16384;                               // FFN row-chunk
    char* wp = (char*)d_ws;
    unsigned short* b16_a = (unsigned short*)wp;  wp += (size_t)N * DD * 2;
    unsigned short* b16_b = (unsigned short*)wp;  wp += (size_t)N * DD * 2;
    unsigned short* ffh   = (unsigned short*)wp;  wp += (size_t)CH * FF * 2;
    unsigned short* wt1   = (unsigned short*)wp;  wp += (size_t)DD * DD * 2;
    unsigned short* wt2   = (unsigned short*)wp;  wp += (size_t)DD * DD * 2;
    unsigned short* wt3   = (unsigned short*)wp;  wp += (size_t)DD * DD * 2;
    unsigned short* wtf1  = (unsigned short*)wp;  wp += (size_t)FF * DD * 2;
    unsigned short* wtf2  = (unsigned short*)wp;  wp += (size_t)DD * FF * 2;
    unsigned short* wtcat = (unsigned short*)wp;  wp += (size_t)2048 * DD * 2;  // [2048][512]
    unsigned short* nr16  = (unsigned short*)wp;  wp += (size_t)PE * DD * 2;
    float* bcat = (float*)wp;  wp += 2048 * 4;
    float* proj = (float*)wp;  wp += (size_t)PE * 2048 * 4;   // fused projections
    float* sbuf = (float*)wp;  wp += (size_t)N * 4;
    float* wgt  = (float*)wp;  wp += (size_t)N * 4;
    float* rep  = (float*)wp;  wp += (size_t)E * DD * 4;
    float* ob   = (float*)wp;  wp += (size_t)E * DD * 4;
    float* oprj = (float*)wp;  wp += (size_t)E * DD * 4;
    float* u4   = (float*)wp;  wp += (size_t)E * 4 * 4;
    int*   seg  = (int*)wp;    wp += (size_t)N * 4;
    int*   offs = (int*)wp;

    // aliases into ffh (used strictly before the FFN/attention writes them):
    // seg_wsum partials [E][8][512] f32, then S/P buffer [12][E][PE] f32.
    float* part = (float*)ffh;
    float* S    = (float*)ffh;

    int mg128 = (N + 127) / 128;

    // ---- weight prep: transposes to [N,K] bf16 + fused-projection concat ----
    transpose_b16_kernel<<<dim3(DD / 32, DD / 32), 256, 0, stream>>>(t1w1, wt1, DD, DD);
    transpose_b16_kernel<<<dim3(DD / 32, DD / 32), 256, 0, stream>>>(t1w2, wt2, DD, DD);
    transpose_b16_kernel<<<dim3(DD / 32, DD / 32), 256, 0, stream>>>(t2w1, wt3, DD, DD);
    transpose_b16_kernel<<<dim3(FF / 32, DD / 32), 256, 0, stream>>>(f1w, wtf1, DD, FF);
    transpose_b16_kernel<<<dim3(DD / 32, FF / 32), 256, 0, stream>>>(f2w, wtf2, FF, DD);
    transpose_b16_kernel<<<dim3(DD / 32, DD / 32), 256, 0, stream>>>(ok_w, wtcat,              DD, DD);
    transpose_b16_kernel<<<dim3(DD / 32, DD / 32), 256, 0, stream>>>(ov_w, wtcat + 512 * DD,  DD, DD);
    transpose_b16_kernel<<<dim3(DD / 32, DD / 32), 256, 0, stream>>>(oq_w, wtcat + 1024 * DD, DD, DD);
    transpose_b16_kernel<<<dim3(256 / 32, DD / 32), 256, 0, stream>>>(sk_w, wtcat + 1536 * DD, DD, 256);
    transpose_b16_kernel<<<dim3(256 / 32, DD / 32), 256, 0, stream>>>(sq_w, wtcat + 1792 * DD, DD, 256);
    bcat_kernel<<<8, 256, 0, stream>>>(ok_b, ov_b, oq_b, sk_b, sq_b, bcat);

    // ---- x -> bf16 ----
    size_t n4 = (size_t)N * DD / 4;
    cvt_b16_kernel<<<(int)((n4 + 255) / 256), 256, 0, stream>>>(x, b16_a, n4);

    // ---- inner attention MLPs (bf16 MFMA) ----
    gemm_bf16_kernel<1, 1><<<dim3(mg128, DD / 128), 256, 0, stream>>>(b16_a, wt1, t1b1, b16_b, N, DD, DD);
    gemm_bf16_kernel<1, 0><<<dim3(mg128, DD / 128), 256, 0, stream>>>(b16_b, wt2, t1b2, b16_a, N, DD, DD);
    gemm_bf16_kernel<1, 1><<<dim3(mg128, DD / 128), 256, 0, stream>>>(b16_a, wt3, t2b1, b16_b, N, DD, DD);
    rowdot512_b16_kernel<<<N, 64, 0, stream>>>(b16_b, t2w2, t2b2, sbuf);

    // ---- segment softmax + rep + LN1 ----
    seg_offsets_kernel<<<1, 64, 0, stream>>>(lens, offs, E);
    fill_seg_kernel<<<E, 256, 0, stream>>>(offs, seg);
    seg_softmax_kernel<<<E, 384, 0, stream>>>(sbuf, offs, wgt);
    seg_wsum_part_kernel<<<dim3(E, 8), 256, 0, stream>>>(b16_a, wgt, offs, part);
    seg_wsum_reduce_kernel<<<E, 256, 0, stream>>>(part, rep);
    ln1_kernel<<<N, 256, 0, stream>>>(x, b16_a, wgt, ln1w, ln1b, out_x);

    // ---- new_rep output + bf16 copy ----
    int nr_total = PE * DD;
    newrep_kernel<<<(nr_total + 255) / 256, 256, 0, stream>>>(past, rep, out_newrep, nr_total);
    cvt_b16_kernel<<<(nr_total / 4 + 255) / 256, 256, 0, stream>>>(out_newrep, nr16, nr_total / 4);

    // ---- fused K|V|Q|K2|Q2 projection (one MFMA GEMM, N=2048) ----
    gemm_bf16_kernel<0, 0><<<dim3(PE / 128, 2048 / 128), 256, 0, stream>>>(nr16, wtcat, bcat, proj, PE, 2048, DD);

    // ---- outer + score attention as fp32 tiled GEMMs ----
    attn_scores_kernel<<<dim3(E / 64, PE / 64, 12), 256, 0, stream>>>(proj, S, PE);
    attn_softmax_kernel<<<dim3(E, 12), 256, 0, stream>>>(S, u4, PE);
    attn_pv_kernel<<<dim3(E / 32, 8), 256, 0, stream>>>(S, proj, ob, PE);
    gemm_kernel<<<dim3(E / 64, DD / 64), 256, 0, stream>>>(ob, oo_w, oo_b, oprj, E, DD, DD, 0);
    ln2_kernel<<<N, 256, 0, stream>>>(out_x, oprj, seg, ln2w, ln2b, b16_b);
    finalize_kernel<<<1, 64, 0, stream>>>(u4, out_past, out_us, E);

    // ---- FFN (bf16 MFMA, chunked) ----
    for (int r0 = 0; r0 < N; r0 += CH) {
        int mr = N - r0; if (mr > CH) mr = CH;
        int mgc = (mr + 127) / 128;
        gemm_bf16_kernel<1, 1><<<dim3(mgc, FF / 128), 256, 0, stream>>>(
            b16_b + (size_t)r0 * DD, wtf1, f1b, ffh, mr, FF, DD);
        gemm_bf16_kernel<1, 0><<<dim3(mgc, DD / 128), 256, 0, stream>>>(
            ffh, wtf2, f2b_, b16_a + (size_t)r0 * DD, mr, DD, FF);
    }
    ln3_film_kernel<<<N, 256, 0, stream>>>(out_x, b16_a, mode, ln3w, ln3b, msc, msh, out_x);
}

// Round 5
// 1534.922 us; speedup vs baseline: 1.2607x; 1.0326x over previous
//
#include <hip/hip_runtime.h>
#include <hip/hip_bf16.h>
#include <cmath>

// ---------------------------------------------------------------------------
// DAFNetBaseLayer — round 8: wave-per-row LayerNorms (16-32B/lane vector
// loads, shfl-butterfly reductions, zero barriers). GEMM/attention/seg
// structure from r7 (pipelined MFMA, fp32 attention, 8-way seg_wsum).
// D=512, H=8, DK=64, HS=4, FF=2048, P=512, E=256
// ---------------------------------------------------------------------------

#define DD 512
#define FF 2048
#define PP 512
#define NEG_BIG (-1e30f)
#define LDT 68   // padded LDS stride for 64-wide fp32 tiles

typedef __attribute__((ext_vector_type(8))) short shortx8;   // 8 bf16 = 4 VGPR
typedef __attribute__((ext_vector_type(4))) float floatx4;

__device__ __forceinline__ unsigned short f2b(float f) {
    unsigned int u = __float_as_uint(f);
    unsigned int r = (u + 0x7fffu + ((u >> 16) & 1u)) >> 16;
    return (unsigned short)r;
}
__device__ __forceinline__ float b2f(unsigned short h) {
    return __uint_as_float(((unsigned int)h) << 16);
}

__device__ __forceinline__ void async_copy16(const void* g, void* l) {
    __builtin_amdgcn_global_load_lds(
        (const __attribute__((address_space(1))) unsigned int*)g,
        (__attribute__((address_space(3))) unsigned int*)l, 16, 0, 0);
}

__device__ __forceinline__ float wave_sum64(float v) {
#pragma unroll
    for (int d = 32; d > 0; d >>= 1) v += __shfl_xor(v, d, 64);
    return v;
}

// ---------------- bf16 MFMA GEMM:  C[M,N] = act(A[M,K] @ Bt[N,K]^T + bias) --
// 128x128 tile, BK=32, 256 threads = 4 waves (2x2 of 64x64), 16x16x32 MFMA.
// N % 128 == 0, K % 64 == 0. A,Bt bf16 row-major; bias fp32; C fp32 or bf16.
// Pipeline: 2x LDS buffers, stage(t+1) issued BEFORE compute(t); one
// __syncthreads (vmcnt+lgkmcnt drain) per K-step. Static buffer indices.
template<int OUT_BF16, int RELU>
__global__ __launch_bounds__(256) void gemm_bf16_kernel(
    const unsigned short* __restrict__ A, const unsigned short* __restrict__ Bt,
    const float* __restrict__ bias, void* __restrict__ C,
    int M, int N, int K)
{
    __shared__ unsigned short As[2][128 * 32];
    __shared__ unsigned short Bs[2][128 * 32];

    int t = threadIdx.x;
    int w = t >> 6, l = t & 63;

    // ---- block remap: XCD-contiguous chunks (bijective), N-tile fastest ----
    int nwg = gridDim.x * gridDim.y;
    int bid = blockIdx.x + blockIdx.y * gridDim.x;
    int qch = nwg >> 3, rch = nwg & 7;
    int xcd = bid & 7, lo = bid >> 3;
    int swz = (xcd < rch ? xcd * (qch + 1) : rch * (qch + 1) + (xcd - rch) * qch) + lo;
    int bm = (swz / gridDim.y) * 128;
    int bn = (swz % gridDim.y) * 128;

    int wm = (w >> 1) * 64, wn = (w & 1) * 64;

    // Swapped operands: mfma(bf, af) -> lane&15 indexes M rows, reg-dim
    // indexes 4 consecutive N cols -> vectorized epilogue.
    floatx4 acc[4][4];
#pragma unroll
    for (int i = 0; i < 4; ++i)
#pragma unroll
        for (int j = 0; j < 4; ++j)
#pragma unroll
            for (int r = 0; r < 4; ++r) acc[i][j][r] = 0.f;

    int s0 = t, s1 = 256 + t;
    int ar0 = s0 >> 2, ak0 = (s0 & 3) * 8;
    int ar1 = s1 >> 2, ak1 = (s1 & 3) * 8;
    int am0 = min(bm + ar0, M - 1);
    int am1 = min(bm + ar1, M - 1);
    const unsigned short* Ap0 = A + (size_t)am0 * K + ak0;
    const unsigned short* Ap1 = A + (size_t)am1 * K + ak1;
    const unsigned short* Bp0 = Bt + (size_t)(bn + ar0) * K + ak0;
    const unsigned short* Bp1 = Bt + (size_t)(bn + ar1) * K + ak1;

    int o0 = (w * 64) * 8, o1 = (256 + w * 64) * 8;

    int fr = l & 15, fq = l >> 4;
    int aoff = (wm + fr) * 32 + fq * 8;
    int boff = (wn + fr) * 32 + fq * 8;

    int nt = K >> 5;   // even for all call sites (K % 64 == 0)

    // ---- prologue: stage tile 0 -> buf 0 ----
    async_copy16(Ap0, &As[0][o0]);
    async_copy16(Ap1, &As[0][o1]);
    async_copy16(Bp0, &Bs[0][o0]);
    async_copy16(Bp1, &Bs[0][o1]);
    __syncthreads();

    for (int tt = 0; tt < nt; tt += 2) {
        // ---- phase A: stage tile tt+1 -> buf1, then compute buf0 ----
        {
            int k1 = (tt + 1) << 5;
            async_copy16(Ap0 + k1, &As[1][o0]);
            async_copy16(Ap1 + k1, &As[1][o1]);
            async_copy16(Bp0 + k1, &Bs[1][o0]);
            async_copy16(Bp1 + k1, &Bs[1][o1]);
        }
        {
            shortx8 af[4], bf[4];
#pragma unroll
            for (int i = 0; i < 4; ++i) af[i] = *(const shortx8*)&As[0][aoff + i * 16 * 32];
#pragma unroll
            for (int j = 0; j < 4; ++j) bf[j] = *(const shortx8*)&Bs[0][boff + j * 16 * 32];
#pragma unroll
            for (int i = 0; i < 4; ++i)
#pragma unroll
                for (int j = 0; j < 4; ++j)
                    acc[i][j] = __builtin_amdgcn_mfma_f32_16x16x32_bf16(bf[j], af[i], acc[i][j], 0, 0, 0);
        }
        __syncthreads();

        // ---- phase B: stage tile tt+2 -> buf0, then compute buf1 ----
        if (tt + 2 < nt) {
            int k2 = (tt + 2) << 5;
            async_copy16(Ap0 + k2, &As[0][o0]);
            async_copy16(Ap1 + k2, &As[0][o1]);
            async_copy16(Bp0 + k2, &Bs[0][o0]);
            async_copy16(Bp1 + k2, &Bs[0][o1]);
        }
        {
            shortx8 af[4], bf[4];
#pragma unroll
            for (int i = 0; i < 4; ++i) af[i] = *(const shortx8*)&As[1][aoff + i * 16 * 32];
#pragma unroll
            for (int j = 0; j < 4; ++j) bf[j] = *(const shortx8*)&Bs[1][boff + j * 16 * 32];
#pragma unroll
            for (int i = 0; i < 4; ++i)
#pragma unroll
                for (int j = 0; j < 4; ++j)
                    acc[i][j] = __builtin_amdgcn_mfma_f32_16x16x32_bf16(bf[j], af[i], acc[i][j], 0, 0, 0);
        }
        __syncthreads();
    }

    // ---- epilogue: lane owns rows (i*16+fr), cols (j*16+fq*4 .. +3) ----
    float4 bb[4];
#pragma unroll
    for (int j = 0; j < 4; ++j)
        bb[j] = *(const float4*)&bias[bn + wn + j * 16 + fq * 4];

#pragma unroll
    for (int i = 0; i < 4; ++i) {
        int row = bm + wm + i * 16 + fr;
        if (row >= M) continue;
#pragma unroll
        for (int j = 0; j < 4; ++j) {
            int col = bn + wn + j * 16 + fq * 4;
            float v0 = acc[i][j][0] + bb[j].x;
            float v1 = acc[i][j][1] + bb[j].y;
            float v2 = acc[i][j][2] + bb[j].z;
            float v3 = acc[i][j][3] + bb[j].w;
            if (RELU) {
                v0 = fmaxf(v0, 0.f); v1 = fmaxf(v1, 0.f);
                v2 = fmaxf(v2, 0.f); v3 = fmaxf(v3, 0.f);
            }
            if (OUT_BF16) {
                ushort4 o;
                o.x = f2b(v0); o.y = f2b(v1); o.z = f2b(v2); o.w = f2b(v3);
                *(ushort4*)&((unsigned short*)C)[(size_t)row * N + col] = o;
            } else {
                float4 o;
                o.x = v0; o.y = v1; o.z = v2; o.w = v3;
                *(float4*)&((float*)C)[(size_t)row * N + col] = o;
            }
        }
    }
}

// ---------------- fp32 -> bf16 elementwise (n % 4 == 0) --------------------
__global__ void cvt_b16_kernel(const float* __restrict__ in, unsigned short* __restrict__ out, size_t n4)
{
    size_t i = (size_t)blockIdx.x * blockDim.x + threadIdx.x;
    if (i >= n4) return;
    float4 v = ((const float4*)in)[i];
    ushort4 o;
    o.x = f2b(v.x); o.y = f2b(v.y); o.z = f2b(v.z); o.w = f2b(v.w);
    ((ushort4*)out)[i] = o;
}

// ---------------- W[K,N] fp32 -> Wt[N,K] bf16 (K,N % 32 == 0) --------------
__global__ __launch_bounds__(256) void transpose_b16_kernel(
    const float* __restrict__ W, unsigned short* __restrict__ Wt, int Kd, int Nd)
{
    __shared__ float tile[32][33];
    int bx = blockIdx.x * 32;   // N
    int by = blockIdx.y * 32;   // K
    int tx = threadIdx.x & 31, ty = threadIdx.x >> 5;  // 32 x 8
#pragma unroll
    for (int i = 0; i < 32; i += 8)
        tile[ty + i][tx] = W[(size_t)(by + ty + i) * Nd + bx + tx];
    __syncthreads();
#pragma unroll
    for (int i = 0; i < 32; i += 8)
        Wt[(size_t)(bx + ty + i) * Kd + by + tx] = f2b(tile[tx][ty + i]);
}

// ---------------- bias concat for fused projection -------------------------
__global__ void bcat_kernel(const float* __restrict__ okb, const float* __restrict__ ovb,
                            const float* __restrict__ oqb, const float* __restrict__ skb,
                            const float* __restrict__ sqb, float* __restrict__ bcat)
{
    int i = blockIdx.x * 256 + threadIdx.x;  // 0..2047
    float v;
    if      (i < 512)  v = okb[i];
    else if (i < 1024) v = ovb[i - 512];
    else if (i < 1536) v = oqb[i - 1024];
    else if (i < 1792) v = skb[i - 1536];
    else               v = sqb[i - 1792];
    bcat[i] = v;
}

// ---------------- generic tiled fp32 GEMM (o-proj only) --------------------
__global__ __launch_bounds__(256) void gemm_kernel(
    const float* __restrict__ A, const float* __restrict__ W,
    const float* __restrict__ bias, float* __restrict__ C,
    int M, int N, int K, int relu)
{
    __shared__ float As[16][68];
    __shared__ float Ws[16][68];
    int t  = threadIdx.x;
    int tx = t & 15, ty = t >> 4;
    int bm = blockIdx.x * 64, bn = blockIdx.y * 64;
    float acc[4][4] = {};

    for (int k0 = 0; k0 < K; k0 += 16) {
#pragma unroll
        for (int e = 0; e < 4; ++e) {
            int idx = t + e * 256;
            int kk = idx & 15, m = idx >> 4;
            int row = bm + m;
            As[kk][m] = (row < M) ? A[(size_t)row * K + k0 + kk] : 0.f;
        }
#pragma unroll
        for (int e = 0; e < 4; ++e) {
            int idx = t + e * 256;
            int n = idx & 63, kk = idx >> 6;
            Ws[kk][n] = W[(size_t)(k0 + kk) * N + bn + n];
        }
        __syncthreads();
#pragma unroll
        for (int kk = 0; kk < 16; ++kk) {
            float4 a4 = *(const float4*)&As[kk][ty * 4];
            float4 b4 = *(const float4*)&Ws[kk][tx * 4];
            float av[4] = {a4.x, a4.y, a4.z, a4.w};
            float bv[4] = {b4.x, b4.y, b4.z, b4.w};
#pragma unroll
            for (int i = 0; i < 4; ++i)
#pragma unroll
                for (int j = 0; j < 4; ++j)
                    acc[i][j] += av[i] * bv[j];
        }
        __syncthreads();
    }

#pragma unroll
    for (int i = 0; i < 4; ++i) {
        int row = bm + ty * 4 + i;
        if (row >= M) continue;
        int col = bn + tx * 4;
        float4 bb = *(const float4*)&bias[col];
        float4 r;
        r.x = acc[i][0] + bb.x; r.y = acc[i][1] + bb.y;
        r.z = acc[i][2] + bb.z; r.w = acc[i][3] + bb.w;
        if (relu) {
            r.x = fmaxf(r.x, 0.f); r.y = fmaxf(r.y, 0.f);
            r.z = fmaxf(r.z, 0.f); r.w = fmaxf(r.w, 0.f);
        }
        *(float4*)&C[(size_t)row * N + col] = r;
    }
}

// ---------------- s = h2(bf16) @ t2w2 + t2b2 (one wave per row) ------------
__global__ __launch_bounds__(64) void rowdot512_b16_kernel(
    const unsigned short* __restrict__ A, const float* __restrict__ w,
    const float* __restrict__ bptr, float* __restrict__ out)
{
    int row = blockIdx.x;
    int lane = threadIdx.x;
    int col = lane * 8;
    shortx8 a8 = *(const shortx8*)(A + (size_t)row * DD + col);
    float4 w0 = *(const float4*)(w + col);
    float4 w1 = *(const float4*)(w + col + 4);
    float v = b2f((unsigned short)a8[0]) * w0.x + b2f((unsigned short)a8[1]) * w0.y
            + b2f((unsigned short)a8[2]) * w0.z + b2f((unsigned short)a8[3]) * w0.w
            + b2f((unsigned short)a8[4]) * w1.x + b2f((unsigned short)a8[5]) * w1.y
            + b2f((unsigned short)a8[6]) * w1.z + b2f((unsigned short)a8[7]) * w1.w;
#pragma unroll
    for (int d = 32; d > 0; d >>= 1) v += __shfl_down(v, d, 64);
    if (lane == 0) out[row] = v + bptr[0];
}

// ---------------- segment machinery ----------------------------------------
__global__ void seg_offsets_kernel(const int* __restrict__ lens, int* __restrict__ offs, int E)
{
    if (threadIdx.x == 0 && blockIdx.x == 0) {
        int acc = 0;
        for (int g = 0; g < E; ++g) { offs[g] = acc; acc += lens[g]; }
        offs[E] = acc;
    }
}

__global__ void fill_seg_kernel(const int* __restrict__ offs, int* __restrict__ seg)
{
    int g = blockIdx.x;
    int o = offs[g], e = offs[g + 1];
    for (int i = o + threadIdx.x; i < e; i += blockDim.x) seg[i] = g;
}

__global__ __launch_bounds__(384) void seg_softmax_kernel(
    const float* __restrict__ s, const int* __restrict__ offs, float* __restrict__ wgt)
{
    __shared__ float red[8];
    int g = blockIdx.x;
    int o = offs[g], len = offs[g + 1] - o;
    int t = threadIdx.x;
    int lane = t & 63, wid = t >> 6;

    float v = (t < len) ? s[o + t] : NEG_BIG;
    float m = v;
#pragma unroll
    for (int d = 32; d > 0; d >>= 1) m = fmaxf(m, __shfl_down(m, d, 64));
    if (lane == 0) red[wid] = m;
    __syncthreads();
    if (t == 0) {
        float mm = red[0];
        for (int i = 1; i < 6; ++i) mm = fmaxf(mm, red[i]);
        red[6] = mm;
    }
    __syncthreads();
    float M = red[6];

    float p = (t < len) ? expf(v - M) : 0.f;
    float sum = p;
#pragma unroll
    for (int d = 32; d > 0; d >>= 1) sum += __shfl_down(sum, d, 64);
    if (lane == 0) red[wid] = sum;
    __syncthreads();
    if (t == 0) {
        float ss = red[0];
        for (int i = 1; i < 6; ++i) ss += red[i];
        red[7] = ss;
    }
    __syncthreads();
    if (t < len) wgt[o + t] = p / red[7];
}

// ---------------- seg weighted sum: 8-way chunk split, partials ------------
__global__ __launch_bounds__(256) void seg_wsum_part_kernel(
    const unsigned short* __restrict__ att_x, const float* __restrict__ wgt,
    const int* __restrict__ offs, float* __restrict__ part)
{
    __shared__ float sm[4][DD];
    int g = blockIdx.x, ch = blockIdx.y;
    int o = offs[g], e = offs[g + 1];
    int len = e - o;
    int per = (len + 7) >> 3;
    int s = o + ch * per;
    int en = min(s + per, e);

    int t = threadIdx.x, lane = t & 63, w = t >> 6;
    int col = lane * 8;
    float acc[8] = {};
    for (int i = s + w; i < en; i += 4) {
        float wt = wgt[i];
        shortx8 v = *(const shortx8*)(att_x + (size_t)i * DD + col);
#pragma unroll
        for (int j = 0; j < 8; ++j)
            acc[j] += b2f((unsigned short)v[j]) * wt;
    }
#pragma unroll
    for (int j = 0; j < 8; ++j) sm[w][col + j] = acc[j];
    __syncthreads();

    float* pr = part + ((size_t)g * 8 + ch) * DD;
#pragma unroll
    for (int j = 0; j < 2; ++j) {
        int c = t * 2 + j;
        pr[c] = (sm[0][c] + sm[1][c]) + (sm[2][c] + sm[3][c]);
    }
}

__global__ __launch_bounds__(256) void seg_wsum_reduce_kernel(
    const float* __restrict__ part, float* __restrict__ rep)
{
    int g = blockIdx.x;
    int t = threadIdx.x;
#pragma unroll
    for (int j = 0; j < 2; ++j) {
        int c = t * 2 + j;
        float s = 0.f;
#pragma unroll
        for (int ch = 0; ch < 8; ++ch)
            s += part[((size_t)g * 8 + ch) * DD + c];
        rep[(size_t)g * DD + c] = s;
    }
}

// ---------------- LN1 (wave-per-row): out = LN(x + att_x*wgt[row]) ---------
__global__ __launch_bounds__(256) void ln1_kernel(
    const float* __restrict__ x, const unsigned short* __restrict__ att_x,
    const float* __restrict__ wgt, const float* __restrict__ w,
    const float* __restrict__ b, float* __restrict__ out, int N)
{
    int row = blockIdx.x * 4 + (threadIdx.x >> 6);
    if (row >= N) return;
    int col = (threadIdx.x & 63) * 8;
    const float* xr = x + (size_t)row * DD + col;
    const unsigned short* ar = att_x + (size_t)row * DD + col;
    float wr = wgt[row];
    float4 x0 = *(const float4*)xr;
    float4 x1 = *(const float4*)(xr + 4);
    shortx8 a8 = *(const shortx8*)ar;
    float v[8];
    v[0] = x0.x + b2f((unsigned short)a8[0]) * wr;
    v[1] = x0.y + b2f((unsigned short)a8[1]) * wr;
    v[2] = x0.z + b2f((unsigned short)a8[2]) * wr;
    v[3] = x0.w + b2f((unsigned short)a8[3]) * wr;
    v[4] = x1.x + b2f((unsigned short)a8[4]) * wr;
    v[5] = x1.y + b2f((unsigned short)a8[5]) * wr;
    v[6] = x1.z + b2f((unsigned short)a8[6]) * wr;
    v[7] = x1.w + b2f((unsigned short)a8[7]) * wr;
    float s = (v[0] + v[1] + v[2] + v[3]) + (v[4] + v[5] + v[6] + v[7]);
    float mean = wave_sum64(s) * (1.f / 512.f);
    float q = 0.f;
#pragma unroll
    for (int j = 0; j < 8; ++j) { v[j] -= mean; q += v[j] * v[j]; }
    float rstd = rsqrtf(wave_sum64(q) * (1.f / 512.f) + 1e-5f);
    float4 w0 = *(const float4*)(w + col), w1 = *(const float4*)(w + col + 4);
    float4 b0 = *(const float4*)(b + col), b1 = *(const float4*)(b + col + 4);
    float4 o0, o1;
    o0.x = v[0] * rstd * w0.x + b0.x; o0.y = v[1] * rstd * w0.y + b0.y;
    o0.z = v[2] * rstd * w0.z + b0.z; o0.w = v[3] * rstd * w0.w + b0.w;
    o1.x = v[4] * rstd * w1.x + b1.x; o1.y = v[5] * rstd * w1.y + b1.y;
    o1.z = v[6] * rstd * w1.z + b1.z; o1.w = v[7] * rstd * w1.w + b1.w;
    *(float4*)(out + (size_t)row * DD + col) = o0;
    *(float4*)(out + (size_t)row * DD + col + 4) = o1;
}

// ---------------- LN2 (wave-per-row, in-place) + bf16 copy -----------------
__global__ __launch_bounds__(256) void ln2_kernel(
    float* __restrict__ xb, const float* __restrict__ o,
    const int* __restrict__ seg, const float* __restrict__ w,
    const float* __restrict__ b, unsigned short* __restrict__ xb16, int N)
{
    int row = blockIdx.x * 4 + (threadIdx.x >> 6);
    if (row >= N) return;
    int col = (threadIdx.x & 63) * 8;
    int g = seg[row];
    const float* xr = xb + (size_t)row * DD + col;
    const float* orow = o + (size_t)g * DD + col;
    float4 x0 = *(const float4*)xr;
    float4 x1 = *(const float4*)(xr + 4);
    float4 a0 = *(const float4*)orow;
    float4 a1 = *(const float4*)(orow + 4);
    float v[8];
    v[0] = x0.x + a0.x; v[1] = x0.y + a0.y; v[2] = x0.z + a0.z; v[3] = x0.w + a0.w;
    v[4] = x1.x + a1.x; v[5] = x1.y + a1.y; v[6] = x1.z + a1.z; v[7] = x1.w + a1.w;
    float s = (v[0] + v[1] + v[2] + v[3]) + (v[4] + v[5] + v[6] + v[7]);
    float mean = wave_sum64(s) * (1.f / 512.f);
    float q = 0.f;
#pragma unroll
    for (int j = 0; j < 8; ++j) { v[j] -= mean; q += v[j] * v[j]; }
    float rstd = rsqrtf(wave_sum64(q) * (1.f / 512.f) + 1e-5f);
    float4 w0 = *(const float4*)(w + col), w1 = *(const float4*)(w + col + 4);
    float4 b0 = *(const float4*)(b + col), b1 = *(const float4*)(b + col + 4);
    float y[8];
    y[0] = v[0] * rstd * w0.x + b0.x; y[1] = v[1] * rstd * w0.y + b0.y;
    y[2] = v[2] * rstd * w0.z + b0.z; y[3] = v[3] * rstd * w0.w + b0.w;
    y[4] = v[4] * rstd * w1.x + b1.x; y[5] = v[5] * rstd * w1.y + b1.y;
    y[6] = v[6] * rstd * w1.z + b1.z; y[7] = v[7] * rstd * w1.w + b1.w;
    float4 o0, o1;
    o0.x = y[0]; o0.y = y[1]; o0.z = y[2]; o0.w = y[3];
    o1.x = y[4]; o1.y = y[5]; o1.z = y[6]; o1.w = y[7];
    *(float4*)(xb + (size_t)row * DD + col) = o0;
    *(float4*)(xb + (size_t)row * DD + col + 4) = o1;
    ushort4 h0, h1;
    h0.x = f2b(y[0]); h0.y = f2b(y[1]); h0.z = f2b(y[2]); h0.w = f2b(y[3]);
    h1.x = f2b(y[4]); h1.y = f2b(y[5]); h1.z = f2b(y[6]); h1.w = f2b(y[7]);
    *(ushort4*)(xb16 + (size_t)row * DD + col) = h0;
    *(ushort4*)(xb16 + (size_t)row * DD + col + 4) = h1;
}

// ---------------- LN3 + FiLM (wave-per-row, ffn in bf16) -------------------
__global__ __launch_bounds__(256) void ln3_film_kernel(
    const float* __restrict__ xb, const unsigned short* __restrict__ ffn,
    const int* __restrict__ mode, const float* __restrict__ w,
    const float* __restrict__ b, const float* __restrict__ msc,
    const float* __restrict__ msh, float* __restrict__ out, int N)
{
    int row = blockIdx.x * 4 + (threadIdx.x >> 6);
    if (row >= N) return;
    int col = (threadIdx.x & 63) * 8;
    int md = mode[row];
    const float* xr = xb + (size_t)row * DD + col;
    const unsigned short* fr = ffn + (size_t)row * DD + col;
    float4 x0 = *(const float4*)xr;
    float4 x1 = *(const float4*)(xr + 4);
    shortx8 f8 = *(const shortx8*)fr;
    float v[8];
    v[0] = x0.x + b2f((unsigned short)f8[0]);
    v[1] = x0.y + b2f((unsigned short)f8[1]);
    v[2] = x0.z + b2f((unsigned short)f8[2]);
    v[3] = x0.w + b2f((unsigned short)f8[3]);
    v[4] = x1.x + b2f((unsigned short)f8[4]);
    v[5] = x1.y + b2f((unsigned short)f8[5]);
    v[6] = x1.z + b2f((unsigned short)f8[6]);
    v[7] = x1.w + b2f((unsigned short)f8[7]);
    float s = (v[0] + v[1] + v[2] + v[3]) + (v[4] + v[5] + v[6] + v[7]);
    float mean = wave_sum64(s) * (1.f / 512.f);
    float q = 0.f;
#pragma unroll
    for (int j = 0; j < 8; ++j) { v[j] -= mean; q += v[j] * v[j]; }
    float rstd = rsqrtf(wave_sum64(q) * (1.f / 512.f) + 1e-5f);
    float4 w0 = *(const float4*)(w + col), w1 = *(const float4*)(w + col + 4);
    float4 b0 = *(const float4*)(b + col), b1 = *(const float4*)(b + col + 4);
    const float* mscr = msc + (size_t)md * DD + col;
    const float* mshr = msh + (size_t)md * DD + col;
    float4 s0 = *(const float4*)mscr, s1 = *(const float4*)(mscr + 4);
    float4 t0 = *(const float4*)mshr, t1 = *(const float4*)(mshr + 4);
    float y[8], sc[8], sh[8], wv[8], bv[8];
    wv[0] = w0.x; wv[1] = w0.y; wv[2] = w0.z; wv[3] = w0.w;
    wv[4] = w1.x; wv[5] = w1.y; wv[6] = w1.z; wv[7] = w1.w;
    bv[0] = b0.x; bv[1] = b0.y; bv[2] = b0.z; bv[3] = b0.w;
    bv[4] = b1.x; bv[5] = b1.y; bv[6] = b1.z; bv[7] = b1.w;
    sc[0] = s0.x; sc[1] = s0.y; sc[2] = s0.z; sc[3] = s0.w;
    sc[4] = s1.x; sc[5] = s1.y; sc[6] = s1.z; sc[7] = s1.w;
    sh[0] = t0.x; sh[1] = t0.y; sh[2] = t0.z; sh[3] = t0.w;
    sh[4] = t1.x; sh[5] = t1.y; sh[6] = t1.z; sh[7] = t1.w;
    float r[8];
#pragma unroll
    for (int j = 0; j < 8; ++j) {
        y[j] = v[j] * rstd * wv[j] + bv[j];
        float p = y[j] * sc[j] + sh[j];
        r[j] = fmaxf(p, 0.f) + y[j];
    }
    float4 o0, o1;
    o0.x = r[0]; o0.y = r[1]; o0.z = r[2]; o0.w = r[3];
    o1.x = r[4]; o1.y = r[5]; o1.z = r[6]; o1.w = r[7];
    *(float4*)(out + (size_t)row * DD + col) = o0;
    *(float4*)(out + (size_t)row * DD + col + 4) = o1;
}

// ---------------- new_rep = concat(past_rep, sample_rep) -------------------
__global__ void newrep_kernel(const float* __restrict__ past, const float* __restrict__ rep,
                              float* __restrict__ out, int total)
{
    int i = blockIdx.x * blockDim.x + threadIdx.x;
    if (i >= total) return;
    out[i] = (i < PP * DD) ? past[i] : rep[i - PP * DD];
}

// ---------------- attention scores: S[h][q][k] = (Q·K)/8 -------------------
__global__ __launch_bounds__(256) void attn_scores_kernel(
    const float* __restrict__ proj, float* __restrict__ S, int pe)
{
    int q0 = blockIdx.x * 64;
    int k0 = blockIdx.y * 64;
    int h  = blockIdx.z;
    if (k0 > PP + q0 + 63) return;          // fully-masked causal tile

    int qcol = (h < 8) ? (1024 + h * 64) : (1792 + (h - 8) * 64);
    int kcol = (h < 8) ? (h * 64)        : (1536 + (h - 8) * 64);

    __shared__ float Qs[64][LDT];   // [d][q]
    __shared__ float Ks[64][LDT];   // [d][k]
    int t = threadIdx.x;
    int r = t >> 2, c4 = (t & 3) * 16;
    const float* qsrc = proj + (size_t)(PP + q0 + r) * 2048 + qcol + c4;
    const float* ksrc = proj + (size_t)(k0 + r) * 2048 + kcol + c4;
#pragma unroll
    for (int e = 0; e < 4; ++e) {
        float4 v = *(const float4*)(qsrc + e * 4);
        Qs[c4 + e * 4 + 0][r] = v.x; Qs[c4 + e * 4 + 1][r] = v.y;
        Qs[c4 + e * 4 + 2][r] = v.z; Qs[c4 + e * 4 + 3][r] = v.w;
        float4 u = *(const float4*)(ksrc + e * 4);
        Ks[c4 + e * 4 + 0][r] = u.x; Ks[c4 + e * 4 + 1][r] = u.y;
        Ks[c4 + e * 4 + 2][r] = u.z; Ks[c4 + e * 4 + 3][r] = u.w;
    }
    __syncthreads();

    int tx = t & 15, ty = t >> 4;           // tx -> 4 k cols, ty -> 4 q rows
    float acc[4][4] = {};
#pragma unroll 4
    for (int d = 0; d < 64; ++d) {
        float4 a = *(const float4*)&Qs[d][ty * 4];
        float4 b = *(const float4*)&Ks[d][tx * 4];
        float av[4] = {a.x, a.y, a.z, a.w};
        float bv[4] = {b.x, b.y, b.z, b.w};
#pragma unroll
        for (int i = 0; i < 4; ++i)
#pragma unroll
            for (int j = 0; j < 4; ++j)
                acc[i][j] += av[i] * bv[j];
    }

    float* Sh = S + ((size_t)h * 256 + q0) * pe + k0;
#pragma unroll
    for (int i = 0; i < 4; ++i) {
        float4 o;
        o.x = acc[i][0] * 0.125f; o.y = acc[i][1] * 0.125f;
        o.z = acc[i][2] * 0.125f; o.w = acc[i][3] * 0.125f;
        *(float4*)&Sh[(size_t)(ty * 4 + i) * pe + tx * 4] = o;
    }
}

// ---------------- attention softmax: P in place, diag u for score heads ----
__global__ __launch_bounds__(256) void attn_softmax_kernel(
    float* __restrict__ S, float* __restrict__ u4, int pe)
{
    __shared__ float red[8];
    int q = blockIdx.x;
    int h = blockIdx.y;
    int limq = PP + q;                       // inclusive
    float* row = S + ((size_t)h * 256 + q) * pe;
    int t = threadIdx.x;
    int lane = t & 63, wid = t >> 6;

    float m = NEG_BIG;
    for (int k = t; k <= limq; k += 256) m = fmaxf(m, row[k]);
#pragma unroll
    for (int d = 32; d > 0; d >>= 1) m = fmaxf(m, __shfl_xor(m, d, 64));
    if (lane == 0) red[wid] = m;
    __syncthreads();
    float M = fmaxf(fmaxf(red[0], red[1]), fmaxf(red[2], red[3]));

    float s = 0.f;
    for (int k = t; k <= limq; k += 256) s += expf(row[k] - M);
#pragma unroll
    for (int d = 32; d > 0; d >>= 1) s += __shfl_xor(s, d, 64);
    if (lane == 0) red[4 + wid] = s;
    __syncthreads();
    float SUM = (red[4] + red[5]) + (red[6] + red[7]);
    float inv = 1.f / SUM;

    if (h < 8) {
        for (int k = t; k < pe; k += 256)
            row[k] = (k <= limq) ? expf(row[k] - M) * inv : 0.f;
    } else {
        if (t == 0) u4[q * 4 + (h - 8)] = expf(row[limq] - M) * inv;
    }
}

// ---------------- attention PV: ob[q][h*64+d] = P[h][q][:] @ V[:][d] -------
__global__ __launch_bounds__(256) void attn_pv_kernel(
    const float* __restrict__ S, const float* __restrict__ proj,
    float* __restrict__ ob, int pe)
{
    __shared__ float Ps[64][36];    // [k][q] transposed, q-width 32
    __shared__ float Vs[64][LDT];   // [k][d]
    int q0 = blockIdx.x * 32;
    int h  = blockIdx.y;
    int ktiles = (PP + q0 + 31) / 64 + 1;    // covers all k <= PP+q0+31

    int t = threadIdx.x;
    int tx = t & 15, ty = t >> 4;            // tx -> 4 d cols, ty -> 2 q rows
    int rp = t >> 3, c8 = (t & 7) * 8;       // P staging: 32 rows x 8 cols
    int rv = t >> 2, c16 = (t & 3) * 16;     // V staging: 64 rows x 16 cols
    float acc[2][4] = {};

    for (int kt = 0; kt < ktiles; ++kt) {
        int k0 = kt * 64;
        const float* psrc = S + ((size_t)h * 256 + q0 + rp) * pe + k0 + c8;
        const float* vsrc = proj + (size_t)(k0 + rv) * 2048 + 512 + h * 64 + c16;
#pragma unroll
        for (int e = 0; e < 2; ++e) {
            float4 v = *(const float4*)(psrc + e * 4);
            Ps[c8 + e * 4 + 0][rp] = v.x; Ps[c8 + e * 4 + 1][rp] = v.y;
            Ps[c8 + e * 4 + 2][rp] = v.z; Ps[c8 + e * 4 + 3][rp] = v.w;
        }
#pragma unroll
        for (int e = 0; e < 4; ++e)
            *(float4*)&Vs[rv][c16 + e * 4] = *(const float4*)(vsrc + e * 4);
        __syncthreads();

#pragma unroll 8
        for (int kk = 0; kk < 64; ++kk) {
            float2 a = *(const float2*)&Ps[kk][ty * 2];
            float4 b = *(const float4*)&Vs[kk][tx * 4];
            float av[2] = {a.x, a.y};
            float bv[4] = {b.x, b.y, b.z, b.w};
#pragma unroll
            for (int i = 0; i < 2; ++i)
#pragma unroll
                for (int j = 0; j < 4; ++j)
                    acc[i][j] += av[i] * bv[j];
        }
        __syncthreads();
    }

#pragma unroll
    for (int i = 0; i < 2; ++i) {
        float4 o;
        o.x = acc[i][0]; o.y = acc[i][1]; o.z = acc[i][2]; o.w = acc[i][3];
        *(float4*)&ob[(size_t)(q0 + ty * 2 + i) * DD + h * 64 + tx * 4] = o;
    }
}

// ---------------- cumprod finalize (head-mean + reversed cumprod) ----------
__global__ void finalize_kernel(const float* __restrict__ u4, float* __restrict__ out_past,
                                float* __restrict__ out_us, int E)
{
    if (threadIdx.x == 0 && blockIdx.x == 0) {
        float uE = 0.25f * (u4[(E - 1) * 4] + u4[(E - 1) * 4 + 1] + u4[(E - 1) * 4 + 2] + u4[(E - 1) * 4 + 3]);
        out_us[E - 1] = uE;
        float pf = 1.f;
        for (int i = E - 1; i >= 0; --i) {
            float u = 0.25f * (u4[i * 4] + u4[i * 4 + 1] + u4[i * 4 + 2] + u4[i * 4 + 3]);
            if (i < E - 1) out_us[i] = u * pf;
            pf = (1.f - u) * pf;
        }
        out_past[0] = pf;
    }
}

// ---------------------------------------------------------------------------
extern "C" void kernel_launch(void* const* d_in, const int* in_sizes, int n_in,
                              void* d_out, int out_size, void* d_ws, size_t ws_size,
                              hipStream_t stream)
{
    const float* x    = (const float*)d_in[0];
    const float* past = (const float*)d_in[1];
    const int*   lens = (const int*)d_in[2];
    const int*   mode = (const int*)d_in[3];
    const float* t1w1 = (const float*)d_in[4];
    const float* t1b1 = (const float*)d_in[5];
    const float* t1w2 = (const float*)d_in[6];
    const float* t1b2 = (const float*)d_in[7];
    const float* t2w1 = (const float*)d_in[8];
    const float* t2b1 = (const float*)d_in[9];
    const float* t2w2 = (const float*)d_in[10];
    const float* t2b2 = (const float*)d_in[11];
    const float* oq_w = (const float*)d_in[12];
    const float* oq_b = (const float*)d_in[13];
    const float* ok_w = (const float*)d_in[14];
    const float* ok_b = (const float*)d_in[15];
    const float* ov_w = (const float*)d_in[16];
    const float* ov_b = (const float*)d_in[17];
    const float* oo_w = (const float*)d_in[18];
    const float* oo_b = (const float*)d_in[19];
    const float* sq_w = (const float*)d_in[20];
    const float* sq_b = (const float*)d_in[21];
    const float* sk_w = (const float*)d_in[22];
    const float* sk_b = (const float*)d_in[23];
    const float* f1w  = (const float*)d_in[24];
    const float* f1b  = (const float*)d_in[25];
    const float* f2w  = (const float*)d_in[26];
    const float* f2b_ = (const float*)d_in[27];
    const float* ln1w = (const float*)d_in[28];
    const float* ln1b = (const float*)d_in[29];
    const float* ln2w = (const float*)d_in[30];
    const float* ln2b = (const float*)d_in[31];
    const float* ln3w = (const float*)d_in[32];
    const float* ln3b = (const float*)d_in[33];
    const float* msc  = (const float*)d_in[34];
    const float* msh  = (const float*)d_in[35];

    int N  = in_sizes[0] / DD;
    int E  = in_sizes[2];
    int PE = PP + E;
    if (N <= 0) return;

    float* out        = (float*)d_out;
    float* out_x      = out;
    float* out_past   = out + (size_t)N * DD;
    float* out_us     = out_past + 1;
    float* out_newrep = out_us + E;

    // ---- workspace layout ----
    const int CH = 16384;                               // FFN row-chunk
    char* wp = (char*)d_ws;
    unsigned short* b16_a = (unsigned short*)wp;  wp += (size_t)N * DD * 2;
    unsigned short* b16_b = (unsigned short*)wp;  wp += (size_t)N * DD * 2;
    unsigned short* ffh   = (unsigned short*)wp;  wp += (size_t)CH * FF * 2;
    unsigned short* wt1   = (unsigned short*)wp;  wp += (size_t)DD * DD * 2;
    unsigned short* wt2   = (unsigned short*)wp;  wp += (size_t)DD * DD * 2;
    unsigned short* wt3   = (unsigned short*)wp;  wp += (size_t)DD * DD * 2;
    unsigned short* wtf1  = (unsigned short*)wp;  wp += (size_t)FF * DD * 2;
    unsigned short* wtf2  = (unsigned short*)wp;  wp += (size_t)DD * FF * 2;
    unsigned short* wtcat = (unsigned short*)wp;  wp += (size_t)2048 * DD * 2;  // [2048][512]
    unsigned short* nr16  = (unsigned short*)wp;  wp += (size_t)PE * DD * 2;
    float* bcat = (float*)wp;  wp += 2048 * 4;
    float* proj = (float*)wp;  wp += (size_t)PE * 2048 * 4;   // fused projections
    float* sbuf = (float*)wp;  wp += (size_t)N * 4;
    float* wgt  = (float*)wp;  wp += (size_t)N * 4;
    float* rep  = (float*)wp;  wp += (size_t)E * DD * 4;
    float* ob   = (float*)wp;  wp += (size_t)E * DD * 4;
    float* oprj = (float*)wp;  wp += (size_t)E * DD * 4;
    float* u4   = (float*)wp;  wp += (size_t)E * 4 * 4;
    int*   seg  = (int*)wp;    wp += (size_t)N * 4;
    int*   offs = (int*)wp;

    // aliases into ffh (used strictly before the FFN/attention writes them):
    // seg_wsum partials [E][8][512] f32, then S/P buffer [12][E][PE] f32.
    float* part = (float*)ffh;
    float* S    = (float*)ffh;

    int mg128 = (N + 127) / 128;
    int ln_grid = (N + 3) / 4;

    // ---- weight prep: transposes to [N,K] bf16 + fused-projection concat ----
    transpose_b16_kernel<<<dim3(DD / 32, DD / 32), 256, 0, stream>>>(t1w1, wt1, DD, DD);
    transpose_b16_kernel<<<dim3(DD / 32, DD / 32), 256, 0, stream>>>(t1w2, wt2, DD, DD);
    transpose_b16_kernel<<<dim3(DD / 32, DD / 32), 256, 0, stream>>>(t2w1, wt3, DD, DD);
    transpose_b16_kernel<<<dim3(FF / 32, DD / 32), 256, 0, stream>>>(f1w, wtf1, DD, FF);
    transpose_b16_kernel<<<dim3(DD / 32, FF / 32), 256, 0, stream>>>(f2w, wtf2, FF, DD);
    transpose_b16_kernel<<<dim3(DD / 32, DD / 32), 256, 0, stream>>>(ok_w, wtcat,              DD, DD);
    transpose_b16_kernel<<<dim3(DD / 32, DD / 32), 256, 0, stream>>>(ov_w, wtcat + 512 * DD,  DD, DD);
    transpose_b16_kernel<<<dim3(DD / 32, DD / 32), 256, 0, stream>>>(oq_w, wtcat + 1024 * DD, DD, DD);
    transpose_b16_kernel<<<dim3(256 / 32, DD / 32), 256, 0, stream>>>(sk_w, wtcat + 1536 * DD, DD, 256);
    transpose_b16_kernel<<<dim3(256 / 32, DD / 32), 256, 0, stream>>>(sq_w, wtcat + 1792 * DD, DD, 256);
    bcat_kernel<<<8, 256, 0, stream>>>(ok_b, ov_b, oq_b, sk_b, sq_b, bcat);

    // ---- x -> bf16 ----
    size_t n4 = (size_t)N * DD / 4;
    cvt_b16_kernel<<<(int)((n4 + 255) / 256), 256, 0, stream>>>(x, b16_a, n4);

    // ---- inner attention MLPs (bf16 MFMA) ----
    gemm_bf16_kernel<1, 1><<<dim3(mg128, DD / 128), 256, 0, stream>>>(b16_a, wt1, t1b1, b16_b, N, DD, DD);
    gemm_bf16_kernel<1, 0><<<dim3(mg128, DD / 128), 256, 0, stream>>>(b16_b, wt2, t1b2, b16_a, N, DD, DD);
    gemm_bf16_kernel<1, 1><<<dim3(mg128, DD / 128), 256, 0, stream>>>(b16_a, wt3, t2b1, b16_b, N, DD, DD);
    rowdot512_b16_kernel<<<N, 64, 0, stream>>>(b16_b, t2w2, t2b2, sbuf);

    // ---- segment softmax + rep + LN1 ----
    seg_offsets_kernel<<<1, 64, 0, stream>>>(lens, offs, E);
    fill_seg_kernel<<<E, 256, 0, stream>>>(offs, seg);
    seg_softmax_kernel<<<E, 384, 0, stream>>>(sbuf, offs, wgt);
    seg_wsum_part_kernel<<<dim3(E, 8), 256, 0, stream>>>(b16_a, wgt, offs, part);
    seg_wsum_reduce_kernel<<<E, 256, 0, stream>>>(part, rep);
    ln1_kernel<<<ln_grid, 256, 0, stream>>>(x, b16_a, wgt, ln1w, ln1b, out_x, N);

    // ---- new_rep output + bf16 copy ----
    int nr_total = PE * DD;
    newrep_kernel<<<(nr_total + 255) / 256, 256, 0, stream>>>(past, rep, out_newrep, nr_total);
    cvt_b16_kernel<<<(nr_total / 4 + 255) / 256, 256, 0, stream>>>(out_newrep, nr16, nr_total / 4);

    // ---- fused K|V|Q|K2|Q2 projection (one MFMA GEMM, N=2048) ----
    gemm_bf16_kernel<0, 0><<<dim3(PE / 128, 2048 / 128), 256, 0, stream>>>(nr16, wtcat, bcat, proj, PE, 2048, DD);

    // ---- outer + score attention as fp32 tiled GEMMs ----
    attn_scores_kernel<<<dim3(E / 64, PE / 64, 12), 256, 0, stream>>>(proj, S, PE);
    attn_softmax_kernel<<<dim3(E, 12), 256, 0, stream>>>(S, u4, PE);
    attn_pv_kernel<<<dim3(E / 32, 8), 256, 0, stream>>>(S, proj, ob, PE);
    gemm_kernel<<<dim3(E / 64, DD / 64), 256, 0, stream>>>(ob, oo_w, oo_b, oprj, E, DD, DD, 0);
    ln2_kernel<<<ln_grid, 256, 0, stream>>>(out_x, oprj, seg, ln2w, ln2b, b16_b, N);
    finalize_kernel<<<1, 64, 0, stream>>>(u4, out_past, out_us, E);

    // ---- FFN (bf16 MFMA, chunked) ----
    for (int r0 = 0; r0 < N; r0 += CH) {
        int mr = N - r0; if (mr > CH) mr = CH;
        int mgc = (mr + 127) / 128;
        gemm_bf16_kernel<1, 1><<<dim3(mgc, FF / 128), 256, 0, stream>>>(
            b16_b + (size_t)r0 * DD, wtf1, f1b, ffh, mr, FF, DD);
        gemm_bf16_kernel<1, 0><<<dim3(mgc, DD / 128), 256, 0, stream>>>(
            ffh, wtf2, f2b_, b16_a + (size_t)r0 * DD, mr, DD, FF);
    }
    ln3_film_kernel<<<ln_grid, 256, 0, stream>>>(out_x, b16_a, mode, ln3w, ln3b, msc, msh, out_x, N);
}

// Round 6
// 1525.671 us; speedup vs baseline: 1.2684x; 1.0061x over previous
//
#include <hip/hip_runtime.h>
#include <hip/hip_bf16.h>
#include <cmath>

// ---------------------------------------------------------------------------
// DAFNetBaseLayer — round 9: LDS XOR-swizzle (T2) in the MFMA GEMM.
// chunk ^= (row>>1)&3 applied to BOTH the global_load_lds source column and
// the ds_read fragment address (linear LDS dest, rule #21). Kills the 8-way
// bank conflict (4.19M/dispatch) on the 64B-stride fragment reads.
// Everything else identical to round 8.
// D=512, H=8, DK=64, HS=4, FF=2048, P=512, E=256
// ---------------------------------------------------------------------------

#define DD 512
#define FF 2048
#define PP 512
#define NEG_BIG (-1e30f)
#define LDT 68   // padded LDS stride for 64-wide fp32 tiles

typedef __attribute__((ext_vector_type(8))) short shortx8;   // 8 bf16 = 4 VGPR
typedef __attribute__((ext_vector_type(4))) float floatx4;

__device__ __forceinline__ unsigned short f2b(float f) {
    unsigned int u = __float_as_uint(f);
    unsigned int r = (u + 0x7fffu + ((u >> 16) & 1u)) >> 16;
    return (unsigned short)r;
}
__device__ __forceinline__ float b2f(unsigned short h) {
    return __uint_as_float(((unsigned int)h) << 16);
}

__device__ __forceinline__ void async_copy16(const void* g, void* l) {
    __builtin_amdgcn_global_load_lds(
        (const __attribute__((address_space(1))) unsigned int*)g,
        (__attribute__((address_space(3))) unsigned int*)l, 16, 0, 0);
}

__device__ __forceinline__ float wave_sum64(float v) {
#pragma unroll
    for (int d = 32; d > 0; d >>= 1) v += __shfl_xor(v, d, 64);
    return v;
}

// ---------------- bf16 MFMA GEMM:  C[M,N] = act(A[M,K] @ Bt[N,K]^T + bias) --
// 128x128 tile, BK=32, 256 threads = 4 waves (2x2 of 64x64), 16x16x32 MFMA.
// N % 128 == 0, K % 64 == 0. A,Bt bf16 row-major; bias fp32; C fp32 or bf16.
// Pipeline: 2x LDS buffers, stage(t+1) issued BEFORE compute(t); one
// __syncthreads per K-step. LDS k-chunk XOR-swizzled by (row>>1)&3 on both
// the staging source address and the fragment read (linear LDS dest).
template<int OUT_BF16, int RELU>
__global__ __launch_bounds__(256) void gemm_bf16_kernel(
    const unsigned short* __restrict__ A, const unsigned short* __restrict__ Bt,
    const float* __restrict__ bias, void* __restrict__ C,
    int M, int N, int K)
{
    __shared__ unsigned short As[2][128 * 32];
    __shared__ unsigned short Bs[2][128 * 32];

    int t = threadIdx.x;
    int w = t >> 6, l = t & 63;

    // ---- block remap: XCD-contiguous chunks (bijective), N-tile fastest ----
    int nwg = gridDim.x * gridDim.y;
    int bid = blockIdx.x + blockIdx.y * gridDim.x;
    int qch = nwg >> 3, rch = nwg & 7;
    int xcd = bid & 7, lo = bid >> 3;
    int swz = (xcd < rch ? xcd * (qch + 1) : rch * (qch + 1) + (xcd - rch) * qch) + lo;
    int bm = (swz / gridDim.y) * 128;
    int bn = (swz % gridDim.y) * 128;

    int wm = (w >> 1) * 64, wn = (w & 1) * 64;

    // Swapped operands: mfma(bf, af) -> lane&15 indexes M rows, reg-dim
    // indexes 4 consecutive N cols -> vectorized epilogue.
    floatx4 acc[4][4];
#pragma unroll
    for (int i = 0; i < 4; ++i)
#pragma unroll
        for (int j = 0; j < 4; ++j)
#pragma unroll
            for (int r = 0; r < 4; ++r) acc[i][j][r] = 0.f;

    int s0 = t, s1 = 256 + t;
    int ar0 = s0 >> 2, ar1 = s1 >> 2;                 // LDS tile rows
    int ak0 = ((s0 & 3) ^ ((ar0 >> 1) & 3)) * 8;      // swizzled k-chunk
    int ak1 = ((s1 & 3) ^ ((ar1 >> 1) & 3)) * 8;
    int am0 = min(bm + ar0, M - 1);
    int am1 = min(bm + ar1, M - 1);
    const unsigned short* Ap0 = A + (size_t)am0 * K + ak0;
    const unsigned short* Ap1 = A + (size_t)am1 * K + ak1;
    const unsigned short* Bp0 = Bt + (size_t)(bn + ar0) * K + ak0;
    const unsigned short* Bp1 = Bt + (size_t)(bn + ar1) * K + ak1;

    int o0 = (w * 64) * 8, o1 = (256 + w * 64) * 8;

    int fr = l & 15, fq = l >> 4;
    int sw = (fr >> 1) & 3;                           // read-side swizzle sel
    int aoff = (wm + fr) * 32 + ((fq ^ sw) * 8);
    int boff = (wn + fr) * 32 + ((fq ^ sw) * 8);

    int nt = K >> 5;   // even for all call sites (K % 64 == 0)

    // ---- prologue: stage tile 0 -> buf 0 ----
    async_copy16(Ap0, &As[0][o0]);
    async_copy16(Ap1, &As[0][o1]);
    async_copy16(Bp0, &Bs[0][o0]);
    async_copy16(Bp1, &Bs[0][o1]);
    __syncthreads();

    for (int tt = 0; tt < nt; tt += 2) {
        // ---- phase A: stage tile tt+1 -> buf1, then compute buf0 ----
        {
            int k1 = (tt + 1) << 5;
            async_copy16(Ap0 + k1, &As[1][o0]);
            async_copy16(Ap1 + k1, &As[1][o1]);
            async_copy16(Bp0 + k1, &Bs[1][o0]);
            async_copy16(Bp1 + k1, &Bs[1][o1]);
        }
        {
            shortx8 af[4], bf[4];
#pragma unroll
            for (int i = 0; i < 4; ++i) af[i] = *(const shortx8*)&As[0][aoff + i * 16 * 32];
#pragma unroll
            for (int j = 0; j < 4; ++j) bf[j] = *(const shortx8*)&Bs[0][boff + j * 16 * 32];
#pragma unroll
            for (int i = 0; i < 4; ++i)
#pragma unroll
                for (int j = 0; j < 4; ++j)
                    acc[i][j] = __builtin_amdgcn_mfma_f32_16x16x32_bf16(bf[j], af[i], acc[i][j], 0, 0, 0);
        }
        __syncthreads();

        // ---- phase B: stage tile tt+2 -> buf0, then compute buf1 ----
        if (tt + 2 < nt) {
            int k2 = (tt + 2) << 5;
            async_copy16(Ap0 + k2, &As[0][o0]);
            async_copy16(Ap1 + k2, &As[0][o1]);
            async_copy16(Bp0 + k2, &Bs[0][o0]);
            async_copy16(Bp1 + k2, &Bs[0][o1]);
        }
        {
            shortx8 af[4], bf[4];
#pragma unroll
            for (int i = 0; i < 4; ++i) af[i] = *(const shortx8*)&As[1][aoff + i * 16 * 32];
#pragma unroll
            for (int j = 0; j < 4; ++j) bf[j] = *(const shortx8*)&Bs[1][boff + j * 16 * 32];
#pragma unroll
            for (int i = 0; i < 4; ++i)
#pragma unroll
                for (int j = 0; j < 4; ++j)
                    acc[i][j] = __builtin_amdgcn_mfma_f32_16x16x32_bf16(bf[j], af[i], acc[i][j], 0, 0, 0);
        }
        __syncthreads();
    }

    // ---- epilogue: lane owns rows (i*16+fr), cols (j*16+fq*4 .. +3) ----
    float4 bb[4];
#pragma unroll
    for (int j = 0; j < 4; ++j)
        bb[j] = *(const float4*)&bias[bn + wn + j * 16 + fq * 4];

#pragma unroll
    for (int i = 0; i < 4; ++i) {
        int row = bm + wm + i * 16 + fr;
        if (row >= M) continue;
#pragma unroll
        for (int j = 0; j < 4; ++j) {
            int col = bn + wn + j * 16 + fq * 4;
            float v0 = acc[i][j][0] + bb[j].x;
            float v1 = acc[i][j][1] + bb[j].y;
            float v2 = acc[i][j][2] + bb[j].z;
            float v3 = acc[i][j][3] + bb[j].w;
            if (RELU) {
                v0 = fmaxf(v0, 0.f); v1 = fmaxf(v1, 0.f);
                v2 = fmaxf(v2, 0.f); v3 = fmaxf(v3, 0.f);
            }
            if (OUT_BF16) {
                ushort4 o;
                o.x = f2b(v0); o.y = f2b(v1); o.z = f2b(v2); o.w = f2b(v3);
                *(ushort4*)&((unsigned short*)C)[(size_t)row * N + col] = o;
            } else {
                float4 o;
                o.x = v0; o.y = v1; o.z = v2; o.w = v3;
                *(float4*)&((float*)C)[(size_t)row * N + col] = o;
            }
        }
    }
}

// ---------------- fp32 -> bf16 elementwise (n % 4 == 0) --------------------
__global__ void cvt_b16_kernel(const float* __restrict__ in, unsigned short* __restrict__ out, size_t n4)
{
    size_t i = (size_t)blockIdx.x * blockDim.x + threadIdx.x;
    if (i >= n4) return;
    float4 v = ((const float4*)in)[i];
    ushort4 o;
    o.x = f2b(v.x); o.y = f2b(v.y); o.z = f2b(v.z); o.w = f2b(v.w);
    ((ushort4*)out)[i] = o;
}

// ---------------- W[K,N] fp32 -> Wt[N,K] bf16 (K,N % 32 == 0) --------------
__global__ __launch_bounds__(256) void transpose_b16_kernel(
    const float* __restrict__ W, unsigned short* __restrict__ Wt, int Kd, int Nd)
{
    __shared__ float tile[32][33];
    int bx = blockIdx.x * 32;   // N
    int by = blockIdx.y * 32;   // K
    int tx = threadIdx.x & 31, ty = threadIdx.x >> 5;  // 32 x 8
#pragma unroll
    for (int i = 0; i < 32; i += 8)
        tile[ty + i][tx] = W[(size_t)(by + ty + i) * Nd + bx + tx];
    __syncthreads();
#pragma unroll
    for (int i = 0; i < 32; i += 8)
        Wt[(size_t)(bx + ty + i) * Kd + by + tx] = f2b(tile[tx][ty + i]);
}

// ---------------- bias concat for fused projection -------------------------
__global__ void bcat_kernel(const float* __restrict__ okb, const float* __restrict__ ovb,
                            const float* __restrict__ oqb, const float* __restrict__ skb,
                            const float* __restrict__ sqb, float* __restrict__ bcat)
{
    int i = blockIdx.x * 256 + threadIdx.x;  // 0..2047
    float v;
    if      (i < 512)  v = okb[i];
    else if (i < 1024) v = ovb[i - 512];
    else if (i < 1536) v = oqb[i - 1024];
    else if (i < 1792) v = skb[i - 1536];
    else               v = sqb[i - 1792];
    bcat[i] = v;
}

// ---------------- generic tiled fp32 GEMM (o-proj only) --------------------
__global__ __launch_bounds__(256) void gemm_kernel(
    const float* __restrict__ A, const float* __restrict__ W,
    const float* __restrict__ bias, float* __restrict__ C,
    int M, int N, int K, int relu)
{
    __shared__ float As[16][68];
    __shared__ float Ws[16][68];
    int t  = threadIdx.x;
    int tx = t & 15, ty = t >> 4;
    int bm = blockIdx.x * 64, bn = blockIdx.y * 64;
    float acc[4][4] = {};

    for (int k0 = 0; k0 < K; k0 += 16) {
#pragma unroll
        for (int e = 0; e < 4; ++e) {
            int idx = t + e * 256;
            int kk = idx & 15, m = idx >> 4;
            int row = bm + m;
            As[kk][m] = (row < M) ? A[(size_t)row * K + k0 + kk] : 0.f;
        }
#pragma unroll
        for (int e = 0; e < 4; ++e) {
            int idx = t + e * 256;
            int n = idx & 63, kk = idx >> 6;
            Ws[kk][n] = W[(size_t)(k0 + kk) * N + bn + n];
        }
        __syncthreads();
#pragma unroll
        for (int kk = 0; kk < 16; ++kk) {
            float4 a4 = *(const float4*)&As[kk][ty * 4];
            float4 b4 = *(const float4*)&Ws[kk][tx * 4];
            float av[4] = {a4.x, a4.y, a4.z, a4.w};
            float bv[4] = {b4.x, b4.y, b4.z, b4.w};
#pragma unroll
            for (int i = 0; i < 4; ++i)
#pragma unroll
                for (int j = 0; j < 4; ++j)
                    acc[i][j] += av[i] * bv[j];
        }
        __syncthreads();
    }

#pragma unroll
    for (int i = 0; i < 4; ++i) {
        int row = bm + ty * 4 + i;
        if (row >= M) continue;
        int col = bn + tx * 4;
        float4 bb = *(const float4*)&bias[col];
        float4 r;
        r.x = acc[i][0] + bb.x; r.y = acc[i][1] + bb.y;
        r.z = acc[i][2] + bb.z; r.w = acc[i][3] + bb.w;
        if (relu) {
            r.x = fmaxf(r.x, 0.f); r.y = fmaxf(r.y, 0.f);
            r.z = fmaxf(r.z, 0.f); r.w = fmaxf(r.w, 0.f);
        }
        *(float4*)&C[(size_t)row * N + col] = r;
    }
}

// ---------------- s = h2(bf16) @ t2w2 + t2b2 (one wave per row) ------------
__global__ __launch_bounds__(64) void rowdot512_b16_kernel(
    const unsigned short* __restrict__ A, const float* __restrict__ w,
    const float* __restrict__ bptr, float* __restrict__ out)
{
    int row = blockIdx.x;
    int lane = threadIdx.x;
    int col = lane * 8;
    shortx8 a8 = *(const shortx8*)(A + (size_t)row * DD + col);
    float4 w0 = *(const float4*)(w + col);
    float4 w1 = *(const float4*)(w + col + 4);
    float v = b2f((unsigned short)a8[0]) * w0.x + b2f((unsigned short)a8[1]) * w0.y
            + b2f((unsigned short)a8[2]) * w0.z + b2f((unsigned short)a8[3]) * w0.w
            + b2f((unsigned short)a8[4]) * w1.x + b2f((unsigned short)a8[5]) * w1.y
            + b2f((unsigned short)a8[6]) * w1.z + b2f((unsigned short)a8[7]) * w1.w;
#pragma unroll
    for (int d = 32; d > 0; d >>= 1) v += __shfl_down(v, d, 64);
    if (lane == 0) out[row] = v + bptr[0];
}

// ---------------- segment machinery ----------------------------------------
__global__ void seg_offsets_kernel(const int* __restrict__ lens, int* __restrict__ offs, int E)
{
    if (threadIdx.x == 0 && blockIdx.x == 0) {
        int acc = 0;
        for (int g = 0; g < E; ++g) { offs[g] = acc; acc += lens[g]; }
        offs[E] = acc;
    }
}

__global__ void fill_seg_kernel(const int* __restrict__ offs, int* __restrict__ seg)
{
    int g = blockIdx.x;
    int o = offs[g], e = offs[g + 1];
    for (int i = o + threadIdx.x; i < e; i += blockDim.x) seg[i] = g;
}

__global__ __launch_bounds__(384) void seg_softmax_kernel(
    const float* __restrict__ s, const int* __restrict__ offs, float* __restrict__ wgt)
{
    __shared__ float red[8];
    int g = blockIdx.x;
    int o = offs[g], len = offs[g + 1] - o;
    int t = threadIdx.x;
    int lane = t & 63, wid = t >> 6;

    float v = (t < len) ? s[o + t] : NEG_BIG;
    float m = v;
#pragma unroll
    for (int d = 32; d > 0; d >>= 1) m = fmaxf(m, __shfl_down(m, d, 64));
    if (lane == 0) red[wid] = m;
    __syncthreads();
    if (t == 0) {
        float mm = red[0];
        for (int i = 1; i < 6; ++i) mm = fmaxf(mm, red[i]);
        red[6] = mm;
    }
    __syncthreads();
    float M = red[6];

    float p = (t < len) ? expf(v - M) : 0.f;
    float sum = p;
#pragma unroll
    for (int d = 32; d > 0; d >>= 1) sum += __shfl_down(sum, d, 64);
    if (lane == 0) red[wid] = sum;
    __syncthreads();
    if (t == 0) {
        float ss = red[0];
        for (int i = 1; i < 6; ++i) ss += red[i];
        red[7] = ss;
    }
    __syncthreads();
    if (t < len) wgt[o + t] = p / red[7];
}

// ---------------- seg weighted sum: 8-way chunk split, partials ------------
__global__ __launch_bounds__(256) void seg_wsum_part_kernel(
    const unsigned short* __restrict__ att_x, const float* __restrict__ wgt,
    const int* __restrict__ offs, float* __restrict__ part)
{
    __shared__ float sm[4][DD];
    int g = blockIdx.x, ch = blockIdx.y;
    int o = offs[g], e = offs[g + 1];
    int len = e - o;
    int per = (len + 7) >> 3;
    int s = o + ch * per;
    int en = min(s + per, e);

    int t = threadIdx.x, lane = t & 63, w = t >> 6;
    int col = lane * 8;
    float acc[8] = {};
    for (int i = s + w; i < en; i += 4) {
        float wt = wgt[i];
        shortx8 v = *(const shortx8*)(att_x + (size_t)i * DD + col);
#pragma unroll
        for (int j = 0; j < 8; ++j)
            acc[j] += b2f((unsigned short)v[j]) * wt;
    }
#pragma unroll
    for (int j = 0; j < 8; ++j) sm[w][col + j] = acc[j];
    __syncthreads();

    float* pr = part + ((size_t)g * 8 + ch) * DD;
#pragma unroll
    for (int j = 0; j < 2; ++j) {
        int c = t * 2 + j;
        pr[c] = (sm[0][c] + sm[1][c]) + (sm[2][c] + sm[3][c]);
    }
}

__global__ __launch_bounds__(256) void seg_wsum_reduce_kernel(
    const float* __restrict__ part, float* __restrict__ rep)
{
    int g = blockIdx.x;
    int t = threadIdx.x;
#pragma unroll
    for (int j = 0; j < 2; ++j) {
        int c = t * 2 + j;
        float s = 0.f;
#pragma unroll
        for (int ch = 0; ch < 8; ++ch)
            s += part[((size_t)g * 8 + ch) * DD + c];
        rep[(size_t)g * DD + c] = s;
    }
}

// ---------------- LN1 (wave-per-row): out = LN(x + att_x*wgt[row]) ---------
__global__ __launch_bounds__(256) void ln1_kernel(
    const float* __restrict__ x, const unsigned short* __restrict__ att_x,
    const float* __restrict__ wgt, const float* __restrict__ w,
    const float* __restrict__ b, float* __restrict__ out, int N)
{
    int row = blockIdx.x * 4 + (threadIdx.x >> 6);
    if (row >= N) return;
    int col = (threadIdx.x & 63) * 8;
    const float* xr = x + (size_t)row * DD + col;
    const unsigned short* ar = att_x + (size_t)row * DD + col;
    float wr = wgt[row];
    float4 x0 = *(const float4*)xr;
    float4 x1 = *(const float4*)(xr + 4);
    shortx8 a8 = *(const shortx8*)ar;
    float v[8];
    v[0] = x0.x + b2f((unsigned short)a8[0]) * wr;
    v[1] = x0.y + b2f((unsigned short)a8[1]) * wr;
    v[2] = x0.z + b2f((unsigned short)a8[2]) * wr;
    v[3] = x0.w + b2f((unsigned short)a8[3]) * wr;
    v[4] = x1.x + b2f((unsigned short)a8[4]) * wr;
    v[5] = x1.y + b2f((unsigned short)a8[5]) * wr;
    v[6] = x1.z + b2f((unsigned short)a8[6]) * wr;
    v[7] = x1.w + b2f((unsigned short)a8[7]) * wr;
    float s = (v[0] + v[1] + v[2] + v[3]) + (v[4] + v[5] + v[6] + v[7]);
    float mean = wave_sum64(s) * (1.f / 512.f);
    float q = 0.f;
#pragma unroll
    for (int j = 0; j < 8; ++j) { v[j] -= mean; q += v[j] * v[j]; }
    float rstd = rsqrtf(wave_sum64(q) * (1.f / 512.f) + 1e-5f);
    float4 w0 = *(const float4*)(w + col), w1 = *(const float4*)(w + col + 4);
    float4 b0 = *(const float4*)(b + col), b1 = *(const float4*)(b + col + 4);
    float4 o0, o1;
    o0.x = v[0] * rstd * w0.x + b0.x; o0.y = v[1] * rstd * w0.y + b0.y;
    o0.z = v[2] * rstd * w0.z + b0.z; o0.w = v[3] * rstd * w0.w + b0.w;
    o1.x = v[4] * rstd * w1.x + b1.x; o1.y = v[5] * rstd * w1.y + b1.y;
    o1.z = v[6] * rstd * w1.z + b1.z; o1.w = v[7] * rstd * w1.w + b1.w;
    *(float4*)(out + (size_t)row * DD + col) = o0;
    *(float4*)(out + (size_t)row * DD + col + 4) = o1;
}

// ---------------- LN2 (wave-per-row, in-place) + bf16 copy -----------------
__global__ __launch_bounds__(256) void ln2_kernel(
    float* __restrict__ xb, const float* __restrict__ o,
    const int* __restrict__ seg, const float* __restrict__ w,
    const float* __restrict__ b, unsigned short* __restrict__ xb16, int N)
{
    int row = blockIdx.x * 4 + (threadIdx.x >> 6);
    if (row >= N) return;
    int col = (threadIdx.x & 63) * 8;
    int g = seg[row];
    const float* xr = xb + (size_t)row * DD + col;
    const float* orow = o + (size_t)g * DD + col;
    float4 x0 = *(const float4*)xr;
    float4 x1 = *(const float4*)(xr + 4);
    float4 a0 = *(const float4*)orow;
    float4 a1 = *(const float4*)(orow + 4);
    float v[8];
    v[0] = x0.x + a0.x; v[1] = x0.y + a0.y; v[2] = x0.z + a0.z; v[3] = x0.w + a0.w;
    v[4] = x1.x + a1.x; v[5] = x1.y + a1.y; v[6] = x1.z + a1.z; v[7] = x1.w + a1.w;
    float s = (v[0] + v[1] + v[2] + v[3]) + (v[4] + v[5] + v[6] + v[7]);
    float mean = wave_sum64(s) * (1.f / 512.f);
    float q = 0.f;
#pragma unroll
    for (int j = 0; j < 8; ++j) { v[j] -= mean; q += v[j] * v[j]; }
    float rstd = rsqrtf(wave_sum64(q) * (1.f / 512.f) + 1e-5f);
    float4 w0 = *(const float4*)(w + col), w1 = *(const float4*)(w + col + 4);
    float4 b0 = *(const float4*)(b + col), b1 = *(const float4*)(b + col + 4);
    float y[8];
    y[0] = v[0] * rstd * w0.x + b0.x; y[1] = v[1] * rstd * w0.y + b0.y;
    y[2] = v[2] * rstd * w0.z + b0.z; y[3] = v[3] * rstd * w0.w + b0.w;
    y[4] = v[4] * rstd * w1.x + b1.x; y[5] = v[5] * rstd * w1.y + b1.y;
    y[6] = v[6] * rstd * w1.z + b1.z; y[7] = v[7] * rstd * w1.w + b1.w;
    float4 o0, o1;
    o0.x = y[0]; o0.y = y[1]; o0.z = y[2]; o0.w = y[3];
    o1.x = y[4]; o1.y = y[5]; o1.z = y[6]; o1.w = y[7];
    *(float4*)(xb + (size_t)row * DD + col) = o0;
    *(float4*)(xb + (size_t)row * DD + col + 4) = o1;
    ushort4 h0, h1;
    h0.x = f2b(y[0]); h0.y = f2b(y[1]); h0.z = f2b(y[2]); h0.w = f2b(y[3]);
    h1.x = f2b(y[4]); h1.y = f2b(y[5]); h1.z = f2b(y[6]); h1.w = f2b(y[7]);
    *(ushort4*)(xb16 + (size_t)row * DD + col) = h0;
    *(ushort4*)(xb16 + (size_t)row * DD + col + 4) = h1;
}

// ---------------- LN3 + FiLM (wave-per-row, ffn in bf16) -------------------
__global__ __launch_bounds__(256) void ln3_film_kernel(
    const float* __restrict__ xb, const unsigned short* __restrict__ ffn,
    const int* __restrict__ mode, const float* __restrict__ w,
    const float* __restrict__ b, const float* __restrict__ msc,
    const float* __restrict__ msh, float* __restrict__ out, int N)
{
    int row = blockIdx.x * 4 + (threadIdx.x >> 6);
    if (row >= N) return;
    int col = (threadIdx.x & 63) * 8;
    int md = mode[row];
    const float* xr = xb + (size_t)row * DD + col;
    const unsigned short* fr = ffn + (size_t)row * DD + col;
    float4 x0 = *(const float4*)xr;
    float4 x1 = *(const float4*)(xr + 4);
    shortx8 f8 = *(const shortx8*)fr;
    float v[8];
    v[0] = x0.x + b2f((unsigned short)f8[0]);
    v[1] = x0.y + b2f((unsigned short)f8[1]);
    v[2] = x0.z + b2f((unsigned short)f8[2]);
    v[3] = x0.w + b2f((unsigned short)f8[3]);
    v[4] = x1.x + b2f((unsigned short)f8[4]);
    v[5] = x1.y + b2f((unsigned short)f8[5]);
    v[6] = x1.z + b2f((unsigned short)f8[6]);
    v[7] = x1.w + b2f((unsigned short)f8[7]);
    float s = (v[0] + v[1] + v[2] + v[3]) + (v[4] + v[5] + v[6] + v[7]);
    float mean = wave_sum64(s) * (1.f / 512.f);
    float q = 0.f;
#pragma unroll
    for (int j = 0; j < 8; ++j) { v[j] -= mean; q += v[j] * v[j]; }
    float rstd = rsqrtf(wave_sum64(q) * (1.f / 512.f) + 1e-5f);
    float4 w0 = *(const float4*)(w + col), w1 = *(const float4*)(w + col + 4);
    float4 b0 = *(const float4*)(b + col), b1 = *(const float4*)(b + col + 4);
    const float* mscr = msc + (size_t)md * DD + col;
    const float* mshr = msh + (size_t)md * DD + col;
    float4 s0 = *(const float4*)mscr, s1 = *(const float4*)(mscr + 4);
    float4 t0 = *(const float4*)mshr, t1 = *(const float4*)(mshr + 4);
    float y[8], sc[8], sh[8], wv[8], bv[8];
    wv[0] = w0.x; wv[1] = w0.y; wv[2] = w0.z; wv[3] = w0.w;
    wv[4] = w1.x; wv[5] = w1.y; wv[6] = w1.z; wv[7] = w1.w;
    bv[0] = b0.x; bv[1] = b0.y; bv[2] = b0.z; bv[3] = b0.w;
    bv[4] = b1.x; bv[5] = b1.y; bv[6] = b1.z; bv[7] = b1.w;
    sc[0] = s0.x; sc[1] = s0.y; sc[2] = s0.z; sc[3] = s0.w;
    sc[4] = s1.x; sc[5] = s1.y; sc[6] = s1.z; sc[7] = s1.w;
    sh[0] = t0.x; sh[1] = t0.y; sh[2] = t0.z; sh[3] = t0.w;
    sh[4] = t1.x; sh[5] = t1.y; sh[6] = t1.z; sh[7] = t1.w;
    float r[8];
#pragma unroll
    for (int j = 0; j < 8; ++j) {
        y[j] = v[j] * rstd * wv[j] + bv[j];
        float p = y[j] * sc[j] + sh[j];
        r[j] = fmaxf(p, 0.f) + y[j];
    }
    float4 o0, o1;
    o0.x = r[0]; o0.y = r[1]; o0.z = r[2]; o0.w = r[3];
    o1.x = r[4]; o1.y = r[5]; o1.z = r[6]; o1.w = r[7];
    *(float4*)(out + (size_t)row * DD + col) = o0;
    *(float4*)(out + (size_t)row * DD + col + 4) = o1;
}

// ---------------- new_rep = concat(past_rep, sample_rep) -------------------
__global__ void newrep_kernel(const float* __restrict__ past, const float* __restrict__ rep,
                              float* __restrict__ out, int total)
{
    int i = blockIdx.x * blockDim.x + threadIdx.x;
    if (i >= total) return;
    out[i] = (i < PP * DD) ? past[i] : rep[i - PP * DD];
}

// ---------------- attention scores: S[h][q][k] = (Q·K)/8 -------------------
__global__ __launch_bounds__(256) void attn_scores_kernel(
    const float* __restrict__ proj, float* __restrict__ S, int pe)
{
    int q0 = blockIdx.x * 64;
    int k0 = blockIdx.y * 64;
    int h  = blockIdx.z;
    if (k0 > PP + q0 + 63) return;          // fully-masked causal tile

    int qcol = (h < 8) ? (1024 + h * 64) : (1792 + (h - 8) * 64);
    int kcol = (h < 8) ? (h * 64)        : (1536 + (h - 8) * 64);

    __shared__ float Qs[64][LDT];   // [d][q]
    __shared__ float Ks[64][LDT];   // [d][k]
    int t = threadIdx.x;
    int r = t >> 2, c4 = (t & 3) * 16;
    const float* qsrc = proj + (size_t)(PP + q0 + r) * 2048 + qcol + c4;
    const float* ksrc = proj + (size_t)(k0 + r) * 2048 + kcol + c4;
#pragma unroll
    for (int e = 0; e < 4; ++e) {
        float4 v = *(const float4*)(qsrc + e * 4);
        Qs[c4 + e * 4 + 0][r] = v.x; Qs[c4 + e * 4 + 1][r] = v.y;
        Qs[c4 + e * 4 + 2][r] = v.z; Qs[c4 + e * 4 + 3][r] = v.w;
        float4 u = *(const float4*)(ksrc + e * 4);
        Ks[c4 + e * 4 + 0][r] = u.x; Ks[c4 + e * 4 + 1][r] = u.y;
        Ks[c4 + e * 4 + 2][r] = u.z; Ks[c4 + e * 4 + 3][r] = u.w;
    }
    __syncthreads();

    int tx = t & 15, ty = t >> 4;           // tx -> 4 k cols, ty -> 4 q rows
    float acc[4][4] = {};
#pragma unroll 4
    for (int d = 0; d < 64; ++d) {
        float4 a = *(const float4*)&Qs[d][ty * 4];
        float4 b = *(const float4*)&Ks[d][tx * 4];
        float av[4] = {a.x, a.y, a.z, a.w};
        float bv[4] = {b.x, b.y, b.z, b.w};
#pragma unroll
        for (int i = 0; i < 4; ++i)
#pragma unroll
            for (int j = 0; j < 4; ++j)
                acc[i][j] += av[i] * bv[j];
    }

    float* Sh = S + ((size_t)h * 256 + q0) * pe + k0;
#pragma unroll
    for (int i = 0; i < 4; ++i) {
        float4 o;
        o.x = acc[i][0] * 0.125f; o.y = acc[i][1] * 0.125f;
        o.z = acc[i][2] * 0.125f; o.w = acc[i][3] * 0.125f;
        *(float4*)&Sh[(size_t)(ty * 4 + i) * pe + tx * 4] = o;
    }
}

// ---------------- attention softmax: P in place, diag u for score heads ----
__global__ __launch_bounds__(256) void attn_softmax_kernel(
    float* __restrict__ S, float* __restrict__ u4, int pe)
{
    __shared__ float red[8];
    int q = blockIdx.x;
    int h = blockIdx.y;
    int limq = PP + q;                       // inclusive
    float* row = S + ((size_t)h * 256 + q) * pe;
    int t = threadIdx.x;
    int lane = t & 63, wid = t >> 6;

    float m = NEG_BIG;
    for (int k = t; k <= limq; k += 256) m = fmaxf(m, row[k]);
#pragma unroll
    for (int d = 32; d > 0; d >>= 1) m = fmaxf(m, __shfl_xor(m, d, 64));
    if (lane == 0) red[wid] = m;
    __syncthreads();
    float M = fmaxf(fmaxf(red[0], red[1]), fmaxf(red[2], red[3]));

    float s = 0.f;
    for (int k = t; k <= limq; k += 256) s += expf(row[k] - M);
#pragma unroll
    for (int d = 32; d > 0; d >>= 1) s += __shfl_xor(s, d, 64);
    if (lane == 0) red[4 + wid] = s;
    __syncthreads();
    float SUM = (red[4] + red[5]) + (red[6] + red[7]);
    float inv = 1.f / SUM;

    if (h < 8) {
        for (int k = t; k < pe; k += 256)
            row[k] = (k <= limq) ? expf(row[k] - M) * inv : 0.f;
    } else {
        if (t == 0) u4[q * 4 + (h - 8)] = expf(row[limq] - M) * inv;
    }
}

// ---------------- attention PV: ob[q][h*64+d] = P[h][q][:] @ V[:][d] -------
__global__ __launch_bounds__(256) void attn_pv_kernel(
    const float* __restrict__ S, const float* __restrict__ proj,
    float* __restrict__ ob, int pe)
{
    __shared__ float Ps[64][36];    // [k][q] transposed, q-width 32
    __shared__ float Vs[64][LDT];   // [k][d]
    int q0 = blockIdx.x * 32;
    int h  = blockIdx.y;
    int ktiles = (PP + q0 + 31) / 64 + 1;    // covers all k <= PP+q0+31

    int t = threadIdx.x;
    int tx = t & 15, ty = t >> 4;            // tx -> 4 d cols, ty -> 2 q rows
    int rp = t >> 3, c8 = (t & 7) * 8;       // P staging: 32 rows x 8 cols
    int rv = t >> 2, c16 = (t & 3) * 16;     // V staging: 64 rows x 16 cols
    float acc[2][4] = {};

    for (int kt = 0; kt < ktiles; ++kt) {
        int k0 = kt * 64;
        const float* psrc = S + ((size_t)h * 256 + q0 + rp) * pe + k0 + c8;
        const float* vsrc = proj + (size_t)(k0 + rv) * 2048 + 512 + h * 64 + c16;
#pragma unroll
        for (int e = 0; e < 2; ++e) {
            float4 v = *(const float4*)(psrc + e * 4);
            Ps[c8 + e * 4 + 0][rp] = v.x; Ps[c8 + e * 4 + 1][rp] = v.y;
            Ps[c8 + e * 4 + 2][rp] = v.z; Ps[c8 + e * 4 + 3][rp] = v.w;
        }
#pragma unroll
        for (int e = 0; e < 4; ++e)
            *(float4*)&Vs[rv][c16 + e * 4] = *(const float4*)(vsrc + e * 4);
        __syncthreads();

#pragma unroll 8
        for (int kk = 0; kk < 64; ++kk) {
            float2 a = *(const float2*)&Ps[kk][ty * 2];
            float4 b = *(const float4*)&Vs[kk][tx * 4];
            float av[2] = {a.x, a.y};
            float bv[4] = {b.x, b.y, b.z, b.w};
#pragma unroll
            for (int i = 0; i < 2; ++i)
#pragma unroll
                for (int j = 0; j < 4; ++j)
                    acc[i][j] += av[i] * bv[j];
        }
        __syncthreads();
    }

#pragma unroll
    for (int i = 0; i < 2; ++i) {
        float4 o;
        o.x = acc[i][0]; o.y = acc[i][1]; o.z = acc[i][2]; o.w = acc[i][3];
        *(float4*)&ob[(size_t)(q0 + ty * 2 + i) * DD + h * 64 + tx * 4] = o;
    }
}

// ---------------- cumprod finalize (head-mean + reversed cumprod) ----------
__global__ void finalize_kernel(const float* __restrict__ u4, float* __restrict__ out_past,
                                float* __restrict__ out_us, int E)
{
    if (threadIdx.x == 0 && blockIdx.x == 0) {
        float uE = 0.25f * (u4[(E - 1) * 4] + u4[(E - 1) * 4 + 1] + u4[(E - 1) * 4 + 2] + u4[(E - 1) * 4 + 3]);
        out_us[E - 1] = uE;
        float pf = 1.f;
        for (int i = E - 1; i >= 0; --i) {
            float u = 0.25f * (u4[i * 4] + u4[i * 4 + 1] + u4[i * 4 + 2] + u4[i * 4 + 3]);
            if (i < E - 1) out_us[i] = u * pf;
            pf = (1.f - u) * pf;
        }
        out_past[0] = pf;
    }
}

// ---------------------------------------------------------------------------
extern "C" void kernel_launch(void* const* d_in, const int* in_sizes, int n_in,
                              void* d_out, int out_size, void* d_ws, size_t ws_size,
                              hipStream_t stream)
{
    const float* x    = (const float*)d_in[0];
    const float* past = (const float*)d_in[1];
    const int*   lens = (const int*)d_in[2];
    const int*   mode = (const int*)d_in[3];
    const float* t1w1 = (const float*)d_in[4];
    const float* t1b1 = (const float*)d_in[5];
    const float* t1w2 = (const float*)d_in[6];
    const float* t1b2 = (const float*)d_in[7];
    const float* t2w1 = (const float*)d_in[8];
    const float* t2b1 = (const float*)d_in[9];
    const float* t2w2 = (const float*)d_in[10];
    const float* t2b2 = (const float*)d_in[11];
    const float* oq_w = (const float*)d_in[12];
    const float* oq_b = (const float*)d_in[13];
    const float* ok_w = (const float*)d_in[14];
    const float* ok_b = (const float*)d_in[15];
    const float* ov_w = (const float*)d_in[16];
    const float* ov_b = (const float*)d_in[17];
    const float* oo_w = (const float*)d_in[18];
    const float* oo_b = (const float*)d_in[19];
    const float* sq_w = (const float*)d_in[20];
    const float* sq_b = (const float*)d_in[21];
    const float* sk_w = (const float*)d_in[22];
    const float* sk_b = (const float*)d_in[23];
    const float* f1w  = (const float*)d_in[24];
    const float* f1b  = (const float*)d_in[25];
    const float* f2w  = (const float*)d_in[26];
    const float* f2b_ = (const float*)d_in[27];
    const float* ln1w = (const float*)d_in[28];
    const float* ln1b = (const float*)d_in[29];
    const float* ln2w = (const float*)d_in[30];
    const float* ln2b = (const float*)d_in[31];
    const float* ln3w = (const float*)d_in[32];
    const float* ln3b = (const float*)d_in[33];
    const float* msc  = (const float*)d_in[34];
    const float* msh  = (const float*)d_in[35];

    int N  = in_sizes[0] / DD;
    int E  = in_sizes[2];
    int PE = PP + E;
    if (N <= 0) return;

    float* out        = (float*)d_out;
    float* out_x      = out;
    float* out_past   = out + (size_t)N * DD;
    float* out_us     = out_past + 1;
    float* out_newrep = out_us + E;

    // ---- workspace layout ----
    const int CH = 16384;                               // FFN row-chunk
    char* wp = (char*)d_ws;
    unsigned short* b16_a = (unsigned short*)wp;  wp += (size_t)N * DD * 2;
    unsigned short* b16_b = (unsigned short*)wp;  wp += (size_t)N * DD * 2;
    unsigned short* ffh   = (unsigned short*)wp;  wp += (size_t)CH * FF * 2;
    unsigned short* wt1   = (unsigned short*)wp;  wp += (size_t)DD * DD * 2;
    unsigned short* wt2   = (unsigned short*)wp;  wp += (size_t)DD * DD * 2;
    unsigned short* wt3   = (unsigned short*)wp;  wp += (size_t)DD * DD * 2;
    unsigned short* wtf1  = (unsigned short*)wp;  wp += (size_t)FF * DD * 2;
    unsigned short* wtf2  = (unsigned short*)wp;  wp += (size_t)DD * FF * 2;
    unsigned short* wtcat = (unsigned short*)wp;  wp += (size_t)2048 * DD * 2;  // [2048][512]
    unsigned short* nr16  = (unsigned short*)wp;  wp += (size_t)PE * DD * 2;
    float* bcat = (float*)wp;  wp += 2048 * 4;
    float* proj = (float*)wp;  wp += (size_t)PE * 2048 * 4;   // fused projections
    float* sbuf = (float*)wp;  wp += (size_t)N * 4;
    float* wgt  = (float*)wp;  wp += (size_t)N * 4;
    float* rep  = (float*)wp;  wp += (size_t)E * DD * 4;
    float* ob   = (float*)wp;  wp += (size_t)E * DD * 4;
    float* oprj = (float*)wp;  wp += (size_t)E * DD * 4;
    float* u4   = (float*)wp;  wp += (size_t)E * 4 * 4;
    int*   seg  = (int*)wp;    wp += (size_t)N * 4;
    int*   offs = (int*)wp;

    // aliases into ffh (used strictly before the FFN/attention writes them):
    // seg_wsum partials [E][8][512] f32, then S/P buffer [12][E][PE] f32.
    float* part = (float*)ffh;
    float* S    = (float*)ffh;

    int mg128 = (N + 127) / 128;
    int ln_grid = (N + 3) / 4;

    // ---- weight prep: transposes to [N,K] bf16 + fused-projection concat ----
    transpose_b16_kernel<<<dim3(DD / 32, DD / 32), 256, 0, stream>>>(t1w1, wt1, DD, DD);
    transpose_b16_kernel<<<dim3(DD / 32, DD / 32), 256, 0, stream>>>(t1w2, wt2, DD, DD);
    transpose_b16_kernel<<<dim3(DD / 32, DD / 32), 256, 0, stream>>>(t2w1, wt3, DD, DD);
    transpose_b16_kernel<<<dim3(FF / 32, DD / 32), 256, 0, stream>>>(f1w, wtf1, DD, FF);
    transpose_b16_kernel<<<dim3(DD / 32, FF / 32), 256, 0, stream>>>(f2w, wtf2, FF, DD);
    transpose_b16_kernel<<<dim3(DD / 32, DD / 32), 256, 0, stream>>>(ok_w, wtcat,              DD, DD);
    transpose_b16_kernel<<<dim3(DD / 32, DD / 32), 256, 0, stream>>>(ov_w, wtcat + 512 * DD,  DD, DD);
    transpose_b16_kernel<<<dim3(DD / 32, DD / 32), 256, 0, stream>>>(oq_w, wtcat + 1024 * DD, DD, DD);
    transpose_b16_kernel<<<dim3(256 / 32, DD / 32), 256, 0, stream>>>(sk_w, wtcat + 1536 * DD, DD, 256);
    transpose_b16_kernel<<<dim3(256 / 32, DD / 32), 256, 0, stream>>>(sq_w, wtcat + 1792 * DD, DD, 256);
    bcat_kernel<<<8, 256, 0, stream>>>(ok_b, ov_b, oq_b, sk_b, sq_b, bcat);

    // ---- x -> bf16 ----
    size_t n4 = (size_t)N * DD / 4;
    cvt_b16_kernel<<<(int)((n4 + 255) / 256), 256, 0, stream>>>(x, b16_a, n4);

    // ---- inner attention MLPs (bf16 MFMA) ----
    gemm_bf16_kernel<1, 1><<<dim3(mg128, DD / 128), 256, 0, stream>>>(b16_a, wt1, t1b1, b16_b, N, DD, DD);
    gemm_bf16_kernel<1, 0><<<dim3(mg128, DD / 128), 256, 0, stream>>>(b16_b, wt2, t1b2, b16_a, N, DD, DD);
    gemm_bf16_kernel<1, 1><<<dim3(mg128, DD / 128), 256, 0, stream>>>(b16_a, wt3, t2b1, b16_b, N, DD, DD);
    rowdot512_b16_kernel<<<N, 64, 0, stream>>>(b16_b, t2w2, t2b2, sbuf);

    // ---- segment softmax + rep + LN1 ----
    seg_offsets_kernel<<<1, 64, 0, stream>>>(lens, offs, E);
    fill_seg_kernel<<<E, 256, 0, stream>>>(offs, seg);
    seg_softmax_kernel<<<E, 384, 0, stream>>>(sbuf, offs, wgt);
    seg_wsum_part_kernel<<<dim3(E, 8), 256, 0, stream>>>(b16_a, wgt, offs, part);
    seg_wsum_reduce_kernel<<<E, 256, 0, stream>>>(part, rep);
    ln1_kernel<<<ln_grid, 256, 0, stream>>>(x, b16_a, wgt, ln1w, ln1b, out_x, N);

    // ---- new_rep output + bf16 copy ----
    int nr_total = PE * DD;
    newrep_kernel<<<(nr_total + 255) / 256, 256, 0, stream>>>(past, rep, out_newrep, nr_total);
    cvt_b16_kernel<<<(nr_total / 4 + 255) / 256, 256, 0, stream>>>(out_newrep, nr16, nr_total / 4);

    // ---- fused K|V|Q|K2|Q2 projection (one MFMA GEMM, N=2048) ----
    gemm_bf16_kernel<0, 0><<<dim3(PE / 128, 2048 / 128), 256, 0, stream>>>(nr16, wtcat, bcat, proj, PE, 2048, DD);

    // ---- outer + score attention as fp32 tiled GEMMs ----
    attn_scores_kernel<<<dim3(E / 64, PE / 64, 12), 256, 0, stream>>>(proj, S, PE);
    attn_softmax_kernel<<<dim3(E, 12), 256, 0, stream>>>(S, u4, PE);
    attn_pv_kernel<<<dim3(E / 32, 8), 256, 0, stream>>>(S, proj, ob, PE);
    gemm_kernel<<<dim3(E / 64, DD / 64), 256, 0, stream>>>(ob, oo_w, oo_b, oprj, E, DD, DD, 0);
    ln2_kernel<<<ln_grid, 256, 0, stream>>>(out_x, oprj, seg, ln2w, ln2b, b16_b, N);
    finalize_kernel<<<1, 64, 0, stream>>>(u4, out_past, out_us, E);

    // ---- FFN (bf16 MFMA, chunked) ----
    for (int r0 = 0; r0 < N; r0 += CH) {
        int mr = N - r0; if (mr > CH) mr = CH;
        int mgc = (mr + 127) / 128;
        gemm_bf16_kernel<1, 1><<<dim3(mgc, FF / 128), 256, 0, stream>>>(
            b16_b + (size_t)r0 * DD, wtf1, f1b, ffh, mr, FF, DD);
        gemm_bf16_kernel<1, 0><<<dim3(mgc, DD / 128), 256, 0, stream>>>(
            ffh, wtf2, f2b_, b16_a + (size_t)r0 * DD, mr, DD, FF);
    }
    ln3_film_kernel<<<ln_grid, 256, 0, stream>>>(out_x, b16_a, mode, ln3w, ln3b, msc, msh, out_x, N);
}

// Round 7
// 1411.630 us; speedup vs baseline: 1.3708x; 1.0808x over previous
//
#include <hip/hip_runtime.h>
#include <hip/hip_bf16.h>
#include <cmath>

// ---------------------------------------------------------------------------
// DAFNetBaseLayer — round 10: T4 counted-vmcnt deep pipeline in the MFMA GEMM.
// 3 LDS buffers; stage(t+2) while computing t; s_waitcnt vmcnt(4) (NOT 0) +
// raw s_barrier per K-step -> prefetch loads stay in flight across barriers.
// Keeps r9's conflict-free LDS XOR-swizzle. Everything else unchanged.
// D=512, H=8, DK=64, HS=4, FF=2048, P=512, E=256
// ---------------------------------------------------------------------------

#define DD 512
#define FF 2048
#define PP 512
#define NEG_BIG (-1e30f)
#define LDT 68   // padded LDS stride for 64-wide fp32 tiles
#define LBUF (128 * 32)   // one GEMM LDS buffer: 4096 bf16 = 8KB

typedef __attribute__((ext_vector_type(8))) short shortx8;   // 8 bf16 = 4 VGPR
typedef __attribute__((ext_vector_type(4))) float floatx4;

__device__ __forceinline__ unsigned short f2b(float f) {
    unsigned int u = __float_as_uint(f);
    unsigned int r = (u + 0x7fffu + ((u >> 16) & 1u)) >> 16;
    return (unsigned short)r;
}
__device__ __forceinline__ float b2f(unsigned short h) {
    return __uint_as_float(((unsigned int)h) << 16);
}

__device__ __forceinline__ void async_copy16(const void* g, void* l) {
    __builtin_amdgcn_global_load_lds(
        (const __attribute__((address_space(1))) unsigned int*)g,
        (__attribute__((address_space(3))) unsigned int*)l, 16, 0, 0);
}

__device__ __forceinline__ float wave_sum64(float v) {
#pragma unroll
    for (int d = 32; d > 0; d >>= 1) v += __shfl_xor(v, d, 64);
    return v;
}

// ---------------- bf16 MFMA GEMM:  C[M,N] = act(A[M,K] @ Bt[N,K]^T + bias) --
// 128x128 tile, BK=32, 256 threads = 4 waves (2x2 of 64x64), 16x16x32 MFMA.
// N % 128 == 0, K % 64 == 0. A,Bt bf16 row-major; bias fp32; C fp32 or bf16.
// 3-buffer pipeline: iter t reads buf b0, stages tile t+2 into buf b2, MFMAs,
// then s_waitcnt vmcnt(4) (tile t+1 landed; t+2 still in flight) + s_barrier.
// Safety: b2 was read at iter t-1; those ds_reads are lgkm-drained before
// iter t-1's MFMAs, which precede its barrier -> overwrite is safe.
template<int OUT_BF16, int RELU>
__global__ __launch_bounds__(256) void gemm_bf16_kernel(
    const unsigned short* __restrict__ A, const unsigned short* __restrict__ Bt,
    const float* __restrict__ bias, void* __restrict__ C,
    int M, int N, int K)
{
    __shared__ unsigned short As[3][LBUF];
    __shared__ unsigned short Bs[3][LBUF];

    int t = threadIdx.x;
    int w = t >> 6, l = t & 63;

    // ---- block remap: XCD-contiguous chunks (bijective), N-tile fastest ----
    int nwg = gridDim.x * gridDim.y;
    int bid = blockIdx.x + blockIdx.y * gridDim.x;
    int qch = nwg >> 3, rch = nwg & 7;
    int xcd = bid & 7, lo = bid >> 3;
    int swz = (xcd < rch ? xcd * (qch + 1) : rch * (qch + 1) + (xcd - rch) * qch) + lo;
    int bm = (swz / gridDim.y) * 128;
    int bn = (swz % gridDim.y) * 128;

    int wm = (w >> 1) * 64, wn = (w & 1) * 64;

    floatx4 acc[4][4];
#pragma unroll
    for (int i = 0; i < 4; ++i)
#pragma unroll
        for (int j = 0; j < 4; ++j)
#pragma unroll
            for (int r = 0; r < 4; ++r) acc[i][j][r] = 0.f;

    int s0 = t, s1 = 256 + t;
    int ar0 = s0 >> 2, ar1 = s1 >> 2;                 // LDS tile rows
    int ak0 = ((s0 & 3) ^ ((ar0 >> 1) & 3)) * 8;      // swizzled k-chunk
    int ak1 = ((s1 & 3) ^ ((ar1 >> 1) & 3)) * 8;
    int am0 = min(bm + ar0, M - 1);
    int am1 = min(bm + ar1, M - 1);
    const unsigned short* Ap0 = A + (size_t)am0 * K + ak0;
    const unsigned short* Ap1 = A + (size_t)am1 * K + ak1;
    const unsigned short* Bp0 = Bt + (size_t)(bn + ar0) * K + ak0;
    const unsigned short* Bp1 = Bt + (size_t)(bn + ar1) * K + ak1;

    int o0 = (w * 64) * 8, o1 = (256 + w * 64) * 8;

    int fr = l & 15, fq = l >> 4;
    int sw = (fr >> 1) & 3;                           // read-side swizzle sel
    int aoff = (wm + fr) * 32 + ((fq ^ sw) * 8);
    int boff = (wn + fr) * 32 + ((fq ^ sw) * 8);

    int nt = K >> 5;   // >= 2 for all call sites (K % 64 == 0)

    // ---- prologue: stage tile 0 -> buf0, tile 1 -> buf1 ----
    async_copy16(Ap0, &As[0][o0]);
    async_copy16(Ap1, &As[0][o1]);
    async_copy16(Bp0, &Bs[0][o0]);
    async_copy16(Bp1, &Bs[0][o1]);
    async_copy16(Ap0 + 32, &As[1][o0]);
    async_copy16(Ap1 + 32, &As[1][o1]);
    async_copy16(Bp0 + 32, &Bs[1][o0]);
    async_copy16(Bp1 + 32, &Bs[1][o1]);
    asm volatile("s_waitcnt vmcnt(4)" ::: "memory");   // tile 0 landed
    __builtin_amdgcn_s_barrier();
    asm volatile("" ::: "memory");

    int b0 = 0, b1 = 1, b2 = 2;
    for (int tt = 0; tt < nt; ++tt) {
        // ---- stage tile tt+2 -> buf b2 (stays in flight across barrier) ----
        if (tt + 2 < nt) {
            int k2 = (tt + 2) << 5;
            unsigned short* Ad = &As[0][0] + b2 * LBUF;
            unsigned short* Bd = &Bs[0][0] + b2 * LBUF;
            async_copy16(Ap0 + k2, Ad + o0);
            async_copy16(Ap1 + k2, Ad + o1);
            async_copy16(Bp0 + k2, Bd + o0);
            async_copy16(Bp1 + k2, Bd + o1);
        }
        // ---- ds_read + MFMA on buf b0 (tile tt, guaranteed landed) ----
        {
            const unsigned short* Ab = &As[0][0] + b0 * LBUF;
            const unsigned short* Bb = &Bs[0][0] + b0 * LBUF;
            shortx8 af[4], bf[4];
#pragma unroll
            for (int i = 0; i < 4; ++i) af[i] = *(const shortx8*)&Ab[aoff + i * 16 * 32];
#pragma unroll
            for (int j = 0; j < 4; ++j) bf[j] = *(const shortx8*)&Bb[boff + j * 16 * 32];
#pragma unroll
            for (int i = 0; i < 4; ++i)
#pragma unroll
                for (int j = 0; j < 4; ++j)
                    acc[i][j] = __builtin_amdgcn_mfma_f32_16x16x32_bf16(bf[j], af[i], acc[i][j], 0, 0, 0);
        }
        // ---- counted wait: tile tt+1 landed; tile tt+2 still in flight ----
        if (tt + 2 < nt) {
            asm volatile("s_waitcnt vmcnt(4)" ::: "memory");
        } else {
            asm volatile("s_waitcnt vmcnt(0)" ::: "memory");
        }
        __builtin_amdgcn_s_barrier();
        asm volatile("" ::: "memory");
        int tmp = b0; b0 = b1; b1 = b2; b2 = tmp;
    }

    // ---- epilogue: lane owns rows (i*16+fr), cols (j*16+fq*4 .. +3) ----
    float4 bb[4];
#pragma unroll
    for (int j = 0; j < 4; ++j)
        bb[j] = *(const float4*)&bias[bn + wn + j * 16 + fq * 4];

#pragma unroll
    for (int i = 0; i < 4; ++i) {
        int row = bm + wm + i * 16 + fr;
        if (row >= M) continue;
#pragma unroll
        for (int j = 0; j < 4; ++j) {
            int col = bn + wn + j * 16 + fq * 4;
            float v0 = acc[i][j][0] + bb[j].x;
            float v1 = acc[i][j][1] + bb[j].y;
            float v2 = acc[i][j][2] + bb[j].z;
            float v3 = acc[i][j][3] + bb[j].w;
            if (RELU) {
                v0 = fmaxf(v0, 0.f); v1 = fmaxf(v1, 0.f);
                v2 = fmaxf(v2, 0.f); v3 = fmaxf(v3, 0.f);
            }
            if (OUT_BF16) {
                ushort4 o;
                o.x = f2b(v0); o.y = f2b(v1); o.z = f2b(v2); o.w = f2b(v3);
                *(ushort4*)&((unsigned short*)C)[(size_t)row * N + col] = o;
            } else {
                float4 o;
                o.x = v0; o.y = v1; o.z = v2; o.w = v3;
                *(float4*)&((float*)C)[(size_t)row * N + col] = o;
            }
        }
    }
}

// ---------------- fp32 -> bf16 elementwise (n % 4 == 0) --------------------
__global__ void cvt_b16_kernel(const float* __restrict__ in, unsigned short* __restrict__ out, size_t n4)
{
    size_t i = (size_t)blockIdx.x * blockDim.x + threadIdx.x;
    if (i >= n4) return;
    float4 v = ((const float4*)in)[i];
    ushort4 o;
    o.x = f2b(v.x); o.y = f2b(v.y); o.z = f2b(v.z); o.w = f2b(v.w);
    ((ushort4*)out)[i] = o;
}

// ---------------- W[K,N] fp32 -> Wt[N,K] bf16 (K,N % 32 == 0) --------------
__global__ __launch_bounds__(256) void transpose_b16_kernel(
    const float* __restrict__ W, unsigned short* __restrict__ Wt, int Kd, int Nd)
{
    __shared__ float tile[32][33];
    int bx = blockIdx.x * 32;   // N
    int by = blockIdx.y * 32;   // K
    int tx = threadIdx.x & 31, ty = threadIdx.x >> 5;  // 32 x 8
#pragma unroll
    for (int i = 0; i < 32; i += 8)
        tile[ty + i][tx] = W[(size_t)(by + ty + i) * Nd + bx + tx];
    __syncthreads();
#pragma unroll
    for (int i = 0; i < 32; i += 8)
        Wt[(size_t)(bx + ty + i) * Kd + by + tx] = f2b(tile[tx][ty + i]);
}

// ---------------- bias concat for fused projection -------------------------
__global__ void bcat_kernel(const float* __restrict__ okb, const float* __restrict__ ovb,
                            const float* __restrict__ oqb, const float* __restrict__ skb,
                            const float* __restrict__ sqb, float* __restrict__ bcat)
{
    int i = blockIdx.x * 256 + threadIdx.x;  // 0..2047
    float v;
    if      (i < 512)  v = okb[i];
    else if (i < 1024) v = ovb[i - 512];
    else if (i < 1536) v = oqb[i - 1024];
    else if (i < 1792) v = skb[i - 1536];
    else               v = sqb[i - 1792];
    bcat[i] = v;
}

// ---------------- generic tiled fp32 GEMM (o-proj only) --------------------
__global__ __launch_bounds__(256) void gemm_kernel(
    const float* __restrict__ A, const float* __restrict__ W,
    const float* __restrict__ bias, float* __restrict__ C,
    int M, int N, int K, int relu)
{
    __shared__ float As[16][68];
    __shared__ float Ws[16][68];
    int t  = threadIdx.x;
    int tx = t & 15, ty = t >> 4;
    int bm = blockIdx.x * 64, bn = blockIdx.y * 64;
    float acc[4][4] = {};

    for (int k0 = 0; k0 < K; k0 += 16) {
#pragma unroll
        for (int e = 0; e < 4; ++e) {
            int idx = t + e * 256;
            int kk = idx & 15, m = idx >> 4;
            int row = bm + m;
            As[kk][m] = (row < M) ? A[(size_t)row * K + k0 + kk] : 0.f;
        }
#pragma unroll
        for (int e = 0; e < 4; ++e) {
            int idx = t + e * 256;
            int n = idx & 63, kk = idx >> 6;
            Ws[kk][n] = W[(size_t)(k0 + kk) * N + bn + n];
        }
        __syncthreads();
#pragma unroll
        for (int kk = 0; kk < 16; ++kk) {
            float4 a4 = *(const float4*)&As[kk][ty * 4];
            float4 b4 = *(const float4*)&Ws[kk][tx * 4];
            float av[4] = {a4.x, a4.y, a4.z, a4.w};
            float bv[4] = {b4.x, b4.y, b4.z, b4.w};
#pragma unroll
            for (int i = 0; i < 4; ++i)
#pragma unroll
                for (int j = 0; j < 4; ++j)
                    acc[i][j] += av[i] * bv[j];
        }
        __syncthreads();
    }

#pragma unroll
    for (int i = 0; i < 4; ++i) {
        int row = bm + ty * 4 + i;
        if (row >= M) continue;
        int col = bn + tx * 4;
        float4 bb = *(const float4*)&bias[col];
        float4 r;
        r.x = acc[i][0] + bb.x; r.y = acc[i][1] + bb.y;
        r.z = acc[i][2] + bb.z; r.w = acc[i][3] + bb.w;
        if (relu) {
            r.x = fmaxf(r.x, 0.f); r.y = fmaxf(r.y, 0.f);
            r.z = fmaxf(r.z, 0.f); r.w = fmaxf(r.w, 0.f);
        }
        *(float4*)&C[(size_t)row * N + col] = r;
    }
}

// ---------------- s = h2(bf16) @ t2w2 + t2b2 (one wave per row) ------------
__global__ __launch_bounds__(64) void rowdot512_b16_kernel(
    const unsigned short* __restrict__ A, const float* __restrict__ w,
    const float* __restrict__ bptr, float* __restrict__ out)
{
    int row = blockIdx.x;
    int lane = threadIdx.x;
    int col = lane * 8;
    shortx8 a8 = *(const shortx8*)(A + (size_t)row * DD + col);
    float4 w0 = *(const float4*)(w + col);
    float4 w1 = *(const float4*)(w + col + 4);
    float v = b2f((unsigned short)a8[0]) * w0.x + b2f((unsigned short)a8[1]) * w0.y
            + b2f((unsigned short)a8[2]) * w0.z + b2f((unsigned short)a8[3]) * w0.w
            + b2f((unsigned short)a8[4]) * w1.x + b2f((unsigned short)a8[5]) * w1.y
            + b2f((unsigned short)a8[6]) * w1.z + b2f((unsigned short)a8[7]) * w1.w;
#pragma unroll
    for (int d = 32; d > 0; d >>= 1) v += __shfl_down(v, d, 64);
    if (lane == 0) out[row] = v + bptr[0];
}

// ---------------- segment machinery ----------------------------------------
__global__ void seg_offsets_kernel(const int* __restrict__ lens, int* __restrict__ offs, int E)
{
    if (threadIdx.x == 0 && blockIdx.x == 0) {
        int acc = 0;
        for (int g = 0; g < E; ++g) { offs[g] = acc; acc += lens[g]; }
        offs[E] = acc;
    }
}

__global__ void fill_seg_kernel(const int* __restrict__ offs, int* __restrict__ seg)
{
    int g = blockIdx.x;
    int o = offs[g], e = offs[g + 1];
    for (int i = o + threadIdx.x; i < e; i += blockDim.x) seg[i] = g;
}

__global__ __launch_bounds__(384) void seg_softmax_kernel(
    const float* __restrict__ s, const int* __restrict__ offs, float* __restrict__ wgt)
{
    __shared__ float red[8];
    int g = blockIdx.x;
    int o = offs[g], len = offs[g + 1] - o;
    int t = threadIdx.x;
    int lane = t & 63, wid = t >> 6;

    float v = (t < len) ? s[o + t] : NEG_BIG;
    float m = v;
#pragma unroll
    for (int d = 32; d > 0; d >>= 1) m = fmaxf(m, __shfl_down(m, d, 64));
    if (lane == 0) red[wid] = m;
    __syncthreads();
    if (t == 0) {
        float mm = red[0];
        for (int i = 1; i < 6; ++i) mm = fmaxf(mm, red[i]);
        red[6] = mm;
    }
    __syncthreads();
    float M = red[6];

    float p = (t < len) ? expf(v - M) : 0.f;
    float sum = p;
#pragma unroll
    for (int d = 32; d > 0; d >>= 1) sum += __shfl_down(sum, d, 64);
    if (lane == 0) red[wid] = sum;
    __syncthreads();
    if (t == 0) {
        float ss = red[0];
        for (int i = 1; i < 6; ++i) ss += red[i];
        red[7] = ss;
    }
    __syncthreads();
    if (t < len) wgt[o + t] = p / red[7];
}

// ---------------- seg weighted sum: 8-way chunk split, partials ------------
__global__ __launch_bounds__(256) void seg_wsum_part_kernel(
    const unsigned short* __restrict__ att_x, const float* __restrict__ wgt,
    const int* __restrict__ offs, float* __restrict__ part)
{
    __shared__ float sm[4][DD];
    int g = blockIdx.x, ch = blockIdx.y;
    int o = offs[g], e = offs[g + 1];
    int len = e - o;
    int per = (len + 7) >> 3;
    int s = o + ch * per;
    int en = min(s + per, e);

    int t = threadIdx.x, lane = t & 63, w = t >> 6;
    int col = lane * 8;
    float acc[8] = {};
    for (int i = s + w; i < en; i += 4) {
        float wt = wgt[i];
        shortx8 v = *(const shortx8*)(att_x + (size_t)i * DD + col);
#pragma unroll
        for (int j = 0; j < 8; ++j)
            acc[j] += b2f((unsigned short)v[j]) * wt;
    }
#pragma unroll
    for (int j = 0; j < 8; ++j) sm[w][col + j] = acc[j];
    __syncthreads();

    float* pr = part + ((size_t)g * 8 + ch) * DD;
#pragma unroll
    for (int j = 0; j < 2; ++j) {
        int c = t * 2 + j;
        pr[c] = (sm[0][c] + sm[1][c]) + (sm[2][c] + sm[3][c]);
    }
}

__global__ __launch_bounds__(256) void seg_wsum_reduce_kernel(
    const float* __restrict__ part, float* __restrict__ rep)
{
    int g = blockIdx.x;
    int t = threadIdx.x;
#pragma unroll
    for (int j = 0; j < 2; ++j) {
        int c = t * 2 + j;
        float s = 0.f;
#pragma unroll
        for (int ch = 0; ch < 8; ++ch)
            s += part[((size_t)g * 8 + ch) * DD + c];
        rep[(size_t)g * DD + c] = s;
    }
}

// ---------------- LN1 (wave-per-row): out = LN(x + att_x*wgt[row]) ---------
__global__ __launch_bounds__(256) void ln1_kernel(
    const float* __restrict__ x, const unsigned short* __restrict__ att_x,
    const float* __restrict__ wgt, const float* __restrict__ w,
    const float* __restrict__ b, float* __restrict__ out, int N)
{
    int row = blockIdx.x * 4 + (threadIdx.x >> 6);
    if (row >= N) return;
    int col = (threadIdx.x & 63) * 8;
    const float* xr = x + (size_t)row * DD + col;
    const unsigned short* ar = att_x + (size_t)row * DD + col;
    float wr = wgt[row];
    float4 x0 = *(const float4*)xr;
    float4 x1 = *(const float4*)(xr + 4);
    shortx8 a8 = *(const shortx8*)ar;
    float v[8];
    v[0] = x0.x + b2f((unsigned short)a8[0]) * wr;
    v[1] = x0.y + b2f((unsigned short)a8[1]) * wr;
    v[2] = x0.z + b2f((unsigned short)a8[2]) * wr;
    v[3] = x0.w + b2f((unsigned short)a8[3]) * wr;
    v[4] = x1.x + b2f((unsigned short)a8[4]) * wr;
    v[5] = x1.y + b2f((unsigned short)a8[5]) * wr;
    v[6] = x1.z + b2f((unsigned short)a8[6]) * wr;
    v[7] = x1.w + b2f((unsigned short)a8[7]) * wr;
    float s = (v[0] + v[1] + v[2] + v[3]) + (v[4] + v[5] + v[6] + v[7]);
    float mean = wave_sum64(s) * (1.f / 512.f);
    float q = 0.f;
#pragma unroll
    for (int j = 0; j < 8; ++j) { v[j] -= mean; q += v[j] * v[j]; }
    float rstd = rsqrtf(wave_sum64(q) * (1.f / 512.f) + 1e-5f);
    float4 w0 = *(const float4*)(w + col), w1 = *(const float4*)(w + col + 4);
    float4 b0 = *(const float4*)(b + col), b1 = *(const float4*)(b + col + 4);
    float4 o0, o1;
    o0.x = v[0] * rstd * w0.x + b0.x; o0.y = v[1] * rstd * w0.y + b0.y;
    o0.z = v[2] * rstd * w0.z + b0.z; o0.w = v[3] * rstd * w0.w + b0.w;
    o1.x = v[4] * rstd * w1.x + b1.x; o1.y = v[5] * rstd * w1.y + b1.y;
    o1.z = v[6] * rstd * w1.z + b1.z; o1.w = v[7] * rstd * w1.w + b1.w;
    *(float4*)(out + (size_t)row * DD + col) = o0;
    *(float4*)(out + (size_t)row * DD + col + 4) = o1;
}

// ---------------- LN2 (wave-per-row, in-place) + bf16 copy -----------------
__global__ __launch_bounds__(256) void ln2_kernel(
    float* __restrict__ xb, const float* __restrict__ o,
    const int* __restrict__ seg, const float* __restrict__ w,
    const float* __restrict__ b, unsigned short* __restrict__ xb16, int N)
{
    int row = blockIdx.x * 4 + (threadIdx.x >> 6);
    if (row >= N) return;
    int col = (threadIdx.x & 63) * 8;
    int g = seg[row];
    const float* xr = xb + (size_t)row * DD + col;
    const float* orow = o + (size_t)g * DD + col;
    float4 x0 = *(const float4*)xr;
    float4 x1 = *(const float4*)(xr + 4);
    float4 a0 = *(const float4*)orow;
    float4 a1 = *(const float4*)(orow + 4);
    float v[8];
    v[0] = x0.x + a0.x; v[1] = x0.y + a0.y; v[2] = x0.z + a0.z; v[3] = x0.w + a0.w;
    v[4] = x1.x + a1.x; v[5] = x1.y + a1.y; v[6] = x1.z + a1.z; v[7] = x1.w + a1.w;
    float s = (v[0] + v[1] + v[2] + v[3]) + (v[4] + v[5] + v[6] + v[7]);
    float mean = wave_sum64(s) * (1.f / 512.f);
    float q = 0.f;
#pragma unroll
    for (int j = 0; j < 8; ++j) { v[j] -= mean; q += v[j] * v[j]; }
    float rstd = rsqrtf(wave_sum64(q) * (1.f / 512.f) + 1e-5f);
    float4 w0 = *(const float4*)(w + col), w1 = *(const float4*)(w + col + 4);
    float4 b0 = *(const float4*)(b + col), b1 = *(const float4*)(b + col + 4);
    float y[8];
    y[0] = v[0] * rstd * w0.x + b0.x; y[1] = v[1] * rstd * w0.y + b0.y;
    y[2] = v[2] * rstd * w0.z + b0.z; y[3] = v[3] * rstd * w0.w + b0.w;
    y[4] = v[4] * rstd * w1.x + b1.x; y[5] = v[5] * rstd * w1.y + b1.y;
    y[6] = v[6] * rstd * w1.z + b1.z; y[7] = v[7] * rstd * w1.w + b1.w;
    float4 o0, o1;
    o0.x = y[0]; o0.y = y[1]; o0.z = y[2]; o0.w = y[3];
    o1.x = y[4]; o1.y = y[5]; o1.z = y[6]; o1.w = y[7];
    *(float4*)(xb + (size_t)row * DD + col) = o0;
    *(float4*)(xb + (size_t)row * DD + col + 4) = o1;
    ushort4 h0, h1;
    h0.x = f2b(y[0]); h0.y = f2b(y[1]); h0.z = f2b(y[2]); h0.w = f2b(y[3]);
    h1.x = f2b(y[4]); h1.y = f2b(y[5]); h1.z = f2b(y[6]); h1.w = f2b(y[7]);
    *(ushort4*)(xb16 + (size_t)row * DD + col) = h0;
    *(ushort4*)(xb16 + (size_t)row * DD + col + 4) = h1;
}

// ---------------- LN3 + FiLM (wave-per-row, ffn in bf16) -------------------
__global__ __launch_bounds__(256) void ln3_film_kernel(
    const float* __restrict__ xb, const unsigned short* __restrict__ ffn,
    const int* __restrict__ mode, const float* __restrict__ w,
    const float* __restrict__ b, const float* __restrict__ msc,
    const float* __restrict__ msh, float* __restrict__ out, int N)
{
    int row = blockIdx.x * 4 + (threadIdx.x >> 6);
    if (row >= N) return;
    int col = (threadIdx.x & 63) * 8;
    int md = mode[row];
    const float* xr = xb + (size_t)row * DD + col;
    const unsigned short* fr = ffn + (size_t)row * DD + col;
    float4 x0 = *(const float4*)xr;
    float4 x1 = *(const float4*)(xr + 4);
    shortx8 f8 = *(const shortx8*)fr;
    float v[8];
    v[0] = x0.x + b2f((unsigned short)f8[0]);
    v[1] = x0.y + b2f((unsigned short)f8[1]);
    v[2] = x0.z + b2f((unsigned short)f8[2]);
    v[3] = x0.w + b2f((unsigned short)f8[3]);
    v[4] = x1.x + b2f((unsigned short)f8[4]);
    v[5] = x1.y + b2f((unsigned short)f8[5]);
    v[6] = x1.z + b2f((unsigned short)f8[6]);
    v[7] = x1.w + b2f((unsigned short)f8[7]);
    float s = (v[0] + v[1] + v[2] + v[3]) + (v[4] + v[5] + v[6] + v[7]);
    float mean = wave_sum64(s) * (1.f / 512.f);
    float q = 0.f;
#pragma unroll
    for (int j = 0; j < 8; ++j) { v[j] -= mean; q += v[j] * v[j]; }
    float rstd = rsqrtf(wave_sum64(q) * (1.f / 512.f) + 1e-5f);
    float4 w0 = *(const float4*)(w + col), w1 = *(const float4*)(w + col + 4);
    float4 b0 = *(const float4*)(b + col), b1 = *(const float4*)(b + col + 4);
    const float* mscr = msc + (size_t)md * DD + col;
    const float* mshr = msh + (size_t)md * DD + col;
    float4 s0 = *(const float4*)mscr, s1 = *(const float4*)(mscr + 4);
    float4 t0 = *(const float4*)mshr, t1 = *(const float4*)(mshr + 4);
    float y[8], sc[8], sh[8], wv[8], bv[8];
    wv[0] = w0.x; wv[1] = w0.y; wv[2] = w0.z; wv[3] = w0.w;
    wv[4] = w1.x; wv[5] = w1.y; wv[6] = w1.z; wv[7] = w1.w;
    bv[0] = b0.x; bv[1] = b0.y; bv[2] = b0.z; bv[3] = b0.w;
    bv[4] = b1.x; bv[5] = b1.y; bv[6] = b1.z; bv[7] = b1.w;
    sc[0] = s0.x; sc[1] = s0.y; sc[2] = s0.z; sc[3] = s0.w;
    sc[4] = s1.x; sc[5] = s1.y; sc[6] = s1.z; sc[7] = s1.w;
    sh[0] = t0.x; sh[1] = t0.y; sh[2] = t0.z; sh[3] = t0.w;
    sh[4] = t1.x; sh[5] = t1.y; sh[6] = t1.z; sh[7] = t1.w;
    float r[8];
#pragma unroll
    for (int j = 0; j < 8; ++j) {
        y[j] = v[j] * rstd * wv[j] + bv[j];
        float p = y[j] * sc[j] + sh[j];
        r[j] = fmaxf(p, 0.f) + y[j];
    }
    float4 o0, o1;
    o0.x = r[0]; o0.y = r[1]; o0.z = r[2]; o0.w = r[3];
    o1.x = r[4]; o1.y = r[5]; o1.z = r[6]; o1.w = r[7];
    *(float4*)(out + (size_t)row * DD + col) = o0;
    *(float4*)(out + (size_t)row * DD + col + 4) = o1;
}

// ---------------- new_rep = concat(past_rep, sample_rep) -------------------
__global__ void newrep_kernel(const float* __restrict__ past, const float* __restrict__ rep,
                              float* __restrict__ out, int total)
{
    int i = blockIdx.x * blockDim.x + threadIdx.x;
    if (i >= total) return;
    out[i] = (i < PP * DD) ? past[i] : rep[i - PP * DD];
}

// ---------------- attention scores: S[h][q][k] = (Q·K)/8 -------------------
__global__ __launch_bounds__(256) void attn_scores_kernel(
    const float* __restrict__ proj, float* __restrict__ S, int pe)
{
    int q0 = blockIdx.x * 64;
    int k0 = blockIdx.y * 64;
    int h  = blockIdx.z;
    if (k0 > PP + q0 + 63) return;          // fully-masked causal tile

    int qcol = (h < 8) ? (1024 + h * 64) : (1792 + (h - 8) * 64);
    int kcol = (h < 8) ? (h * 64)        : (1536 + (h - 8) * 64);

    __shared__ float Qs[64][LDT];   // [d][q]
    __shared__ float Ks[64][LDT];   // [d][k]
    int t = threadIdx.x;
    int r = t >> 2, c4 = (t & 3) * 16;
    const float* qsrc = proj + (size_t)(PP + q0 + r) * 2048 + qcol + c4;
    const float* ksrc = proj + (size_t)(k0 + r) * 2048 + kcol + c4;
#pragma unroll
    for (int e = 0; e < 4; ++e) {
        float4 v = *(const float4*)(qsrc + e * 4);
        Qs[c4 + e * 4 + 0][r] = v.x; Qs[c4 + e * 4 + 1][r] = v.y;
        Qs[c4 + e * 4 + 2][r] = v.z; Qs[c4 + e * 4 + 3][r] = v.w;
        float4 u = *(const float4*)(ksrc + e * 4);
        Ks[c4 + e * 4 + 0][r] = u.x; Ks[c4 + e * 4 + 1][r] = u.y;
        Ks[c4 + e * 4 + 2][r] = u.z; Ks[c4 + e * 4 + 3][r] = u.w;
    }
    __syncthreads();

    int tx = t & 15, ty = t >> 4;           // tx -> 4 k cols, ty -> 4 q rows
    float acc[4][4] = {};
#pragma unroll 4
    for (int d = 0; d < 64; ++d) {
        float4 a = *(const float4*)&Qs[d][ty * 4];
        float4 b = *(const float4*)&Ks[d][tx * 4];
        float av[4] = {a.x, a.y, a.z, a.w};
        float bv[4] = {b.x, b.y, b.z, b.w};
#pragma unroll
        for (int i = 0; i < 4; ++i)
#pragma unroll
            for (int j = 0; j < 4; ++j)
                acc[i][j] += av[i] * bv[j];
    }

    float* Sh = S + ((size_t)h * 256 + q0) * pe + k0;
#pragma unroll
    for (int i = 0; i < 4; ++i) {
        float4 o;
        o.x = acc[i][0] * 0.125f; o.y = acc[i][1] * 0.125f;
        o.z = acc[i][2] * 0.125f; o.w = acc[i][3] * 0.125f;
        *(float4*)&Sh[(size_t)(ty * 4 + i) * pe + tx * 4] = o;
    }
}

// ---------------- attention softmax: P in place, diag u for score heads ----
__global__ __launch_bounds__(256) void attn_softmax_kernel(
    float* __restrict__ S, float* __restrict__ u4, int pe)
{
    __shared__ float red[8];
    int q = blockIdx.x;
    int h = blockIdx.y;
    int limq = PP + q;                       // inclusive
    float* row = S + ((size_t)h * 256 + q) * pe;
    int t = threadIdx.x;
    int lane = t & 63, wid = t >> 6;

    float m = NEG_BIG;
    for (int k = t; k <= limq; k += 256) m = fmaxf(m, row[k]);
#pragma unroll
    for (int d = 32; d > 0; d >>= 1) m = fmaxf(m, __shfl_xor(m, d, 64));
    if (lane == 0) red[wid] = m;
    __syncthreads();
    float M = fmaxf(fmaxf(red[0], red[1]), fmaxf(red[2], red[3]));

    float s = 0.f;
    for (int k = t; k <= limq; k += 256) s += expf(row[k] - M);
#pragma unroll
    for (int d = 32; d > 0; d >>= 1) s += __shfl_xor(s, d, 64);
    if (lane == 0) red[4 + wid] = s;
    __syncthreads();
    float SUM = (red[4] + red[5]) + (red[6] + red[7]);
    float inv = 1.f / SUM;

    if (h < 8) {
        for (int k = t; k < pe; k += 256)
            row[k] = (k <= limq) ? expf(row[k] - M) * inv : 0.f;
    } else {
        if (t == 0) u4[q * 4 + (h - 8)] = expf(row[limq] - M) * inv;
    }
}

// ---------------- attention PV: ob[q][h*64+d] = P[h][q][:] @ V[:][d] -------
__global__ __launch_bounds__(256) void attn_pv_kernel(
    const float* __restrict__ S, const float* __restrict__ proj,
    float* __restrict__ ob, int pe)
{
    __shared__ float Ps[64][36];    // [k][q] transposed, q-width 32
    __shared__ float Vs[64][LDT];   // [k][d]
    int q0 = blockIdx.x * 32;
    int h  = blockIdx.y;
    int ktiles = (PP + q0 + 31) / 64 + 1;    // covers all k <= PP+q0+31

    int t = threadIdx.x;
    int tx = t & 15, ty = t >> 4;            // tx -> 4 d cols, ty -> 2 q rows
    int rp = t >> 3, c8 = (t & 7) * 8;       // P staging: 32 rows x 8 cols
    int rv = t >> 2, c16 = (t & 3) * 16;     // V staging: 64 rows x 16 cols
    float acc[2][4] = {};

    for (int kt = 0; kt < ktiles; ++kt) {
        int k0 = kt * 64;
        const float* psrc = S + ((size_t)h * 256 + q0 + rp) * pe + k0 + c8;
        const float* vsrc = proj + (size_t)(k0 + rv) * 2048 + 512 + h * 64 + c16;
#pragma unroll
        for (int e = 0; e < 2; ++e) {
            float4 v = *(const float4*)(psrc + e * 4);
            Ps[c8 + e * 4 + 0][rp] = v.x; Ps[c8 + e * 4 + 1][rp] = v.y;
            Ps[c8 + e * 4 + 2][rp] = v.z; Ps[c8 + e * 4 + 3][rp] = v.w;
        }
#pragma unroll
        for (int e = 0; e < 4; ++e)
            *(float4*)&Vs[rv][c16 + e * 4] = *(const float4*)(vsrc + e * 4);
        __syncthreads();

#pragma unroll 8
        for (int kk = 0; kk < 64; ++kk) {
            float2 a = *(const float2*)&Ps[kk][ty * 2];
            float4 b = *(const float4*)&Vs[kk][tx * 4];
            float av[2] = {a.x, a.y};
            float bv[4] = {b.x, b.y, b.z, b.w};
#pragma unroll
            for (int i = 0; i < 2; ++i)
#pragma unroll
                for (int j = 0; j < 4; ++j)
                    acc[i][j] += av[i] * bv[j];
        }
        __syncthreads();
    }

#pragma unroll
    for (int i = 0; i < 2; ++i) {
        float4 o;
        o.x = acc[i][0]; o.y = acc[i][1]; o.z = acc[i][2]; o.w = acc[i][3];
        *(float4*)&ob[(size_t)(q0 + ty * 2 + i) * DD + h * 64 + tx * 4] = o;
    }
}

// ---------------- cumprod finalize (head-mean + reversed cumprod) ----------
__global__ void finalize_kernel(const float* __restrict__ u4, float* __restrict__ out_past,
                                float* __restrict__ out_us, int E)
{
    if (threadIdx.x == 0 && blockIdx.x == 0) {
        float uE = 0.25f * (u4[(E - 1) * 4] + u4[(E - 1) * 4 + 1] + u4[(E - 1) * 4 + 2] + u4[(E - 1) * 4 + 3]);
        out_us[E - 1] = uE;
        float pf = 1.f;
        for (int i = E - 1; i >= 0; --i) {
            float u = 0.25f * (u4[i * 4] + u4[i * 4 + 1] + u4[i * 4 + 2] + u4[i * 4 + 3]);
            if (i < E - 1) out_us[i] = u * pf;
            pf = (1.f - u) * pf;
        }
        out_past[0] = pf;
    }
}

// ---------------------------------------------------------------------------
extern "C" void kernel_launch(void* const* d_in, const int* in_sizes, int n_in,
                              void* d_out, int out_size, void* d_ws, size_t ws_size,
                              hipStream_t stream)
{
    const float* x    = (const float*)d_in[0];
    const float* past = (const float*)d_in[1];
    const int*   lens = (const int*)d_in[2];
    const int*   mode = (const int*)d_in[3];
    const float* t1w1 = (const float*)d_in[4];
    const float* t1b1 = (const float*)d_in[5];
    const float* t1w2 = (const float*)d_in[6];
    const float* t1b2 = (const float*)d_in[7];
    const float* t2w1 = (const float*)d_in[8];
    const float* t2b1 = (const float*)d_in[9];
    const float* t2w2 = (const float*)d_in[10];
    const float* t2b2 = (const float*)d_in[11];
    const float* oq_w = (const float*)d_in[12];
    const float* oq_b = (const float*)d_in[13];
    const float* ok_w = (const float*)d_in[14];
    const float* ok_b = (const float*)d_in[15];
    const float* ov_w = (const float*)d_in[16];
    const float* ov_b = (const float*)d_in[17];
    const float* oo_w = (const float*)d_in[18];
    const float* oo_b = (const float*)d_in[19];
    const float* sq_w = (const float*)d_in[20];
    const float* sq_b = (const float*)d_in[21];
    const float* sk_w = (const float*)d_in[22];
    const float* sk_b = (const float*)d_in[23];
    const float* f1w  = (const float*)d_in[24];
    const float* f1b  = (const float*)d_in[25];
    const float* f2w  = (const float*)d_in[26];
    const float* f2b_ = (const float*)d_in[27];
    const float* ln1w = (const float*)d_in[28];
    const float* ln1b = (const float*)d_in[29];
    const float* ln2w = (const float*)d_in[30];
    const float* ln2b = (const float*)d_in[31];
    const float* ln3w = (const float*)d_in[32];
    const float* ln3b = (const float*)d_in[33];
    const float* msc  = (const float*)d_in[34];
    const float* msh  = (const float*)d_in[35];

    int N  = in_sizes[0] / DD;
    int E  = in_sizes[2];
    int PE = PP + E;
    if (N <= 0) return;

    float* out        = (float*)d_out;
    float* out_x      = out;
    float* out_past   = out + (size_t)N * DD;
    float* out_us     = out_past + 1;
    float* out_newrep = out_us + E;

    // ---- workspace layout ----
    const int CH = 16384;                               // FFN row-chunk
    char* wp = (char*)d_ws;
    unsigned short* b16_a = (unsigned short*)wp;  wp += (size_t)N * DD * 2;
    unsigned short* b16_b = (unsigned short*)wp;  wp += (size_t)N * DD * 2;
    unsigned short* ffh   = (unsigned short*)wp;  wp += (size_t)CH * FF * 2;
    unsigned short* wt1   = (unsigned short*)wp;  wp += (size_t)DD * DD * 2;
    unsigned short* wt2   = (unsigned short*)wp;  wp += (size_t)DD * DD * 2;
    unsigned short* wt3   = (unsigned short*)wp;  wp += (size_t)DD * DD * 2;
    unsigned short* wtf1  = (unsigned short*)wp;  wp += (size_t)FF * DD * 2;
    unsigned short* wtf2  = (unsigned short*)wp;  wp += (size_t)DD * FF * 2;
    unsigned short* wtcat = (unsigned short*)wp;  wp += (size_t)2048 * DD * 2;  // [2048][512]
    unsigned short* nr16  = (unsigned short*)wp;  wp += (size_t)PE * DD * 2;
    float* bcat = (float*)wp;  wp += 2048 * 4;
    float* proj = (float*)wp;  wp += (size_t)PE * 2048 * 4;   // fused projections
    float* sbuf = (float*)wp;  wp += (size_t)N * 4;
    float* wgt  = (float*)wp;  wp += (size_t)N * 4;
    float* rep  = (float*)wp;  wp += (size_t)E * DD * 4;
    float* ob   = (float*)wp;  wp += (size_t)E * DD * 4;
    float* oprj = (float*)wp;  wp += (size_t)E * DD * 4;
    float* u4   = (float*)wp;  wp += (size_t)E * 4 * 4;
    int*   seg  = (int*)wp;    wp += (size_t)N * 4;
    int*   offs = (int*)wp;

    // aliases into ffh (used strictly before the FFN/attention writes them):
    // seg_wsum partials [E][8][512] f32, then S/P buffer [12][E][PE] f32.
    float* part = (float*)ffh;
    float* S    = (float*)ffh;

    int mg128 = (N + 127) / 128;
    int ln_grid = (N + 3) / 4;

    // ---- weight prep: transposes to [N,K] bf16 + fused-projection concat ----
    transpose_b16_kernel<<<dim3(DD / 32, DD / 32), 256, 0, stream>>>(t1w1, wt1, DD, DD);
    transpose_b16_kernel<<<dim3(DD / 32, DD / 32), 256, 0, stream>>>(t1w2, wt2, DD, DD);
    transpose_b16_kernel<<<dim3(DD / 32, DD / 32), 256, 0, stream>>>(t2w1, wt3, DD, DD);
    transpose_b16_kernel<<<dim3(FF / 32, DD / 32), 256, 0, stream>>>(f1w, wtf1, DD, FF);
    transpose_b16_kernel<<<dim3(DD / 32, FF / 32), 256, 0, stream>>>(f2w, wtf2, FF, DD);
    transpose_b16_kernel<<<dim3(DD / 32, DD / 32), 256, 0, stream>>>(ok_w, wtcat,              DD, DD);
    transpose_b16_kernel<<<dim3(DD / 32, DD / 32), 256, 0, stream>>>(ov_w, wtcat + 512 * DD,  DD, DD);
    transpose_b16_kernel<<<dim3(DD / 32, DD / 32), 256, 0, stream>>>(oq_w, wtcat + 1024 * DD, DD, DD);
    transpose_b16_kernel<<<dim3(256 / 32, DD / 32), 256, 0, stream>>>(sk_w, wtcat + 1536 * DD, DD, 256);
    transpose_b16_kernel<<<dim3(256 / 32, DD / 32), 256, 0, stream>>>(sq_w, wtcat + 1792 * DD, DD, 256);
    bcat_kernel<<<8, 256, 0, stream>>>(ok_b, ov_b, oq_b, sk_b, sq_b, bcat);

    // ---- x -> bf16 ----
    size_t n4 = (size_t)N * DD / 4;
    cvt_b16_kernel<<<(int)((n4 + 255) / 256), 256, 0, stream>>>(x, b16_a, n4);

    // ---- inner attention MLPs (bf16 MFMA) ----
    gemm_bf16_kernel<1, 1><<<dim3(mg128, DD / 128), 256, 0, stream>>>(b16_a, wt1, t1b1, b16_b, N, DD, DD);
    gemm_bf16_kernel<1, 0><<<dim3(mg128, DD / 128), 256, 0, stream>>>(b16_b, wt2, t1b2, b16_a, N, DD, DD);
    gemm_bf16_kernel<1, 1><<<dim3(mg128, DD / 128), 256, 0, stream>>>(b16_a, wt3, t2b1, b16_b, N, DD, DD);
    rowdot512_b16_kernel<<<N, 64, 0, stream>>>(b16_b, t2w2, t2b2, sbuf);

    // ---- segment softmax + rep + LN1 ----
    seg_offsets_kernel<<<1, 64, 0, stream>>>(lens, offs, E);
    fill_seg_kernel<<<E, 256, 0, stream>>>(offs, seg);
    seg_softmax_kernel<<<E, 384, 0, stream>>>(sbuf, offs, wgt);
    seg_wsum_part_kernel<<<dim3(E, 8), 256, 0, stream>>>(b16_a, wgt, offs, part);
    seg_wsum_reduce_kernel<<<E, 256, 0, stream>>>(part, rep);
    ln1_kernel<<<ln_grid, 256, 0, stream>>>(x, b16_a, wgt, ln1w, ln1b, out_x, N);

    // ---- new_rep output + bf16 copy ----
    int nr_total = PE * DD;
    newrep_kernel<<<(nr_total + 255) / 256, 256, 0, stream>>>(past, rep, out_newrep, nr_total);
    cvt_b16_kernel<<<(nr_total / 4 + 255) / 256, 256, 0, stream>>>(out_newrep, nr16, nr_total / 4);

    // ---- fused K|V|Q|K2|Q2 projection (one MFMA GEMM, N=2048) ----
    gemm_bf16_kernel<0, 0><<<dim3(PE / 128, 2048 / 128), 256, 0, stream>>>(nr16, wtcat, bcat, proj, PE, 2048, DD);

    // ---- outer + score attention as fp32 tiled GEMMs ----
    attn_scores_kernel<<<dim3(E / 64, PE / 64, 12), 256, 0, stream>>>(proj, S, PE);
    attn_softmax_kernel<<<dim3(E, 12), 256, 0, stream>>>(S, u4, PE);
    attn_pv_kernel<<<dim3(E / 32, 8), 256, 0, stream>>>(S, proj, ob, PE);
    gemm_kernel<<<dim3(E / 64, DD / 64), 256, 0, stream>>>(ob, oo_w, oo_b, oprj, E, DD, DD, 0);
    ln2_kernel<<<ln_grid, 256, 0, stream>>>(out_x, oprj, seg, ln2w, ln2b, b16_b, N);
    finalize_kernel<<<1, 64, 0, stream>>>(u4, out_past, out_us, E);

    // ---- FFN (bf16 MFMA, chunked) ----
    for (int r0 = 0; r0 < N; r0 += CH) {
        int mr = N - r0; if (mr > CH) mr = CH;
        int mgc = (mr + 127) / 128;
        gemm_bf16_kernel<1, 1><<<dim3(mgc, FF / 128), 256, 0, stream>>>(
            b16_b + (size_t)r0 * DD, wtf1, f1b, ffh, mr, FF, DD);
        gemm_bf16_kernel<1, 0><<<dim3(mgc, DD / 128), 256, 0, stream>>>(
            ffh, wtf2, f2b_, b16_a + (size_t)r0 * DD, mr, DD, FF);
    }
    ln3_film_kernel<<<ln_grid, 256, 0, stream>>>(out_x, b16_a, mode, ln3w, ln3b, msc, msh, out_x, N);
}